// Round 9
// baseline (696.326 us; speedup 1.0000x reference)
//
#include <hip/hip_runtime.h>
#include <math.h>

constexpr int kC   = 192;
constexpr int kNH  = 8;
constexpr int kHC  = 64;
constexpr int kHID = 512;
constexpr int kP   = 16;
constexpr int kB   = 2;
constexpr int kH   = 128;
constexpr int kW   = 128;
constexpr int kHW  = kH * kW;      // 16384
constexpr int kN   = kB * kHW;     // 32768
constexpr float kEPS = 1e-5f;

typedef __attribute__((ext_vector_type(8))) short bf16x8;
typedef __attribute__((ext_vector_type(4))) float f32x4;

__device__ inline unsigned short f2bf(float f) {
    unsigned int u = __builtin_bit_cast(unsigned int, f);
    unsigned int r = (u + 0x7FFFu + ((u >> 16) & 1u)) >> 16;   // RNE
    return (unsigned short)r;
}
__device__ inline float bf2f(unsigned short u) {
    return __builtin_bit_cast(float, (unsigned int)u << 16);
}
__device__ inline unsigned int cvtpk(float lo, float hi) {
    unsigned int r;
    asm("v_cvt_pk_bf16_f32 %0, %1, %2" : "=v"(r) : "v"(lo), "v"(hi));
    return r;
}
__device__ inline unsigned long long pk4(float a, float b, float c, float d) {
    return (unsigned long long)cvtpk(a, b) | ((unsigned long long)cvtpk(c, d) << 32);
}
__device__ inline f32x4 ubf4(unsigned long long u) {
    f32x4 r;
    r[0] = bf2f((unsigned short)u);
    r[1] = bf2f((unsigned short)(u >> 16));
    r[2] = bf2f((unsigned short)(u >> 32));
    r[3] = bf2f((unsigned short)(u >> 48));
    return r;
}
__device__ inline float gelu_f(float x) {
    return 0.5f * x * (1.0f + erff(x * 0.70710678118654752f));
}

// ---------------------------------------------------------------------------
// Prep: zero [acc0|acc1|acc2|ksum_w] + bf16 weight cvts + fused W2' weight.
// ---------------------------------------------------------------------------
__global__ void prep_kernel(float* __restrict__ zbase,
                            const float* wq, const float* wk, const float* wm,
                            const float* c1, const float* c2,
                            const float* wo, const float* mlp_b, const float* bo,
                            unsigned short* wqb, unsigned short* wkb,
                            unsigned short* mlpb1, unsigned short* c1b, unsigned short* c2b,
                            unsigned short* w2pb, float* bp2)
{
    int i = blockIdx.x * 256 + threadIdx.x;
    if (i < 133376) { zbase[i] = 0.f; return; }          // acc0..2 (2304) + ksum_w (131072)
    i -= 133376;
    if (i < 98304) { wqb[i] = f2bf(wq[i]); return; }
    i -= 98304;
    if (i < 98304) { wkb[i] = f2bf(wk[i]); return; }
    i -= 98304;
    if (i < 36864) { int o = i / 192, k = i - o * 192; mlpb1[i] = f2bf(wm[o * 384 + k]); return; }
    i -= 36864;
    if (i < 36864) { c1b[i] = f2bf(c1[i]); return; }
    i -= 36864;
    if (i < 36864) { c2b[i] = f2bf(c2[i]); return; }
    i -= 36864;
    if (i < 98304) {
        int o = i >> 9, j = i & 511;
        const float* a = wm + o * 384 + 192;
        float s = 0.f;
        for (int c = 0; c < 192; ++c) s += a[c] * wo[c * 512 + j];
        w2pb[o * 512 + j] = f2bf(s);
        if (j == 0) {
            float t = mlp_b[o];
            for (int c = 0; c < 192; ++c) t += a[c] * bo[c];
            bp2[o] = t;
        }
    }
}

// ---------------------------------------------------------------------------
// Fused transpose + ln1: x NCHW fp32 -> XPb raw bf16 [n][192] + XNb bf16.
// ---------------------------------------------------------------------------
__global__ __launch_bounds__(256) void txln_kernel(const float* __restrict__ x,
                                                   unsigned short* __restrict__ xpb,
                                                   unsigned short* __restrict__ xnb,
                                                   const float* __restrict__ g,
                                                   const float* __restrict__ bb)
{
    __shared__ float tile[192][65];
    __shared__ float red[2][4][64];
    __shared__ float pms[64], prs[64];
    int hw0 = blockIdx.x * 64;
    int b   = blockIdx.y;
    int tid = threadIdx.x;
    for (int i = tid; i < 192 * 64; i += 256) {
        int c = i >> 6, p = i & 63;
        tile[c][p] = x[(size_t)(b * kC + c) * kHW + hw0 + p];
    }
    __syncthreads();
    {
        int p = tid & 63, qt = tid >> 6;
        float s = 0.f, ss = 0.f;
        for (int c = qt * 48; c < qt * 48 + 48; ++c) {
            float v = tile[c][p]; s += v; ss += v * v;
        }
        red[0][qt][p] = s; red[1][qt][p] = ss;
    }
    __syncthreads();
    if (tid < 64) {
        float s  = red[0][0][tid] + red[0][1][tid] + red[0][2][tid] + red[0][3][tid];
        float ss = red[1][0][tid] + red[1][1][tid] + red[1][2][tid] + red[1][3][tid];
        float m = s * (1.0f / kC);
        float var = ss * (1.0f / kC) - m * m;
        pms[tid] = m;
        prs[tid] = rsqrtf(var + kEPS);
    }
    __syncthreads();
    for (int i = tid; i < 64 * 192; i += 256) {
        int p = i / 192, c = i - p * 192;
        float raw = tile[c][p];
        size_t oi = (size_t)(b * kHW + hw0 + p) * kC + c;
        xpb[oi] = f2bf(raw);
        xnb[oi] = f2bf((raw - pms[p]) * prs[p] * g[c] + bb[c]);
    }
}

// ---------------------------------------------------------------------------
// LayerNorm (ln2), bf16 -> bf16, 4 threads per pixel.
// ---------------------------------------------------------------------------
__global__ void ln_pm_bf16_kernel(const unsigned short* __restrict__ in,
                                  unsigned short* __restrict__ out,
                                  const float* __restrict__ g, const float* __restrict__ bb)
{
    int t = blockIdx.x * 256 + threadIdx.x;     // kN*4
    int n = t >> 2, q = t & 3;
    const unsigned long long* ip = (const unsigned long long*)(in + (size_t)n * kC) + q * 12;
    f32x4 v[12];
    float s = 0.f, ss = 0.f;
#pragma unroll
    for (int r = 0; r < 12; ++r) {
        v[r] = ubf4(ip[r]);
        s  += (v[r][0] + v[r][1]) + (v[r][2] + v[r][3]);
        ss += (v[r][0]*v[r][0] + v[r][1]*v[r][1]) + (v[r][2]*v[r][2] + v[r][3]*v[r][3]);
    }
    s  += __shfl_xor(s, 1);  s  += __shfl_xor(s, 2);
    ss += __shfl_xor(ss, 1); ss += __shfl_xor(ss, 2);
    float m  = s * (1.0f / kC);
    float var = ss * (1.0f / kC) - m * m;
    float rs = rsqrtf(var + kEPS);
    unsigned long long* op = (unsigned long long*)(out + (size_t)n * kC) + q * 12;
#pragma unroll
    for (int r = 0; r < 12; ++r) {
        f32x4 gg = *(const f32x4*)(g + q * 48 + r * 4);
        f32x4 bv = *(const f32x4*)(bb + q * 48 + r * 4);
        op[r] = pk4((v[r][0]-m)*rs*gg[0] + bv[0], (v[r][1]-m)*rs*gg[1] + bv[1],
                    (v[r][2]-m)*rs*gg[2] + bv[2], (v[r][3]-m)*rs*gg[3] + bv[3]);
    }
}

#define MGEMM_CORE(KVAL, APTR, BPTR)                                              \
    {                                                                             \
        const unsigned short* Ap = APTR;                                          \
        const unsigned short* Bp = BPTR;                                          \
        _Pragma("unroll 2")                                                       \
        for (int k = 0; k < KVAL; k += 32) {                                      \
            bf16x8 a0 = *(const bf16x8*)(Ap + k);                                 \
            bf16x8 a1 = *(const bf16x8*)(Ap + (size_t)16 * KVAL + k);             \
            bf16x8 b0 = *(const bf16x8*)(Bp + k);                                 \
            bf16x8 b1 = *(const bf16x8*)(Bp + (size_t)16 * KVAL + k);             \
            bf16x8 b2 = *(const bf16x8*)(Bp + (size_t)32 * KVAL + k);             \
            bf16x8 b3 = *(const bf16x8*)(Bp + (size_t)48 * KVAL + k);             \
            acc[0][0] = __builtin_amdgcn_mfma_f32_16x16x32_bf16(a0, b0, acc[0][0], 0, 0, 0); \
            acc[0][1] = __builtin_amdgcn_mfma_f32_16x16x32_bf16(a0, b1, acc[0][1], 0, 0, 0); \
            acc[0][2] = __builtin_amdgcn_mfma_f32_16x16x32_bf16(a0, b2, acc[0][2], 0, 0, 0); \
            acc[0][3] = __builtin_amdgcn_mfma_f32_16x16x32_bf16(a0, b3, acc[0][3], 0, 0, 0); \
            acc[1][0] = __builtin_amdgcn_mfma_f32_16x16x32_bf16(a1, b0, acc[1][0], 0, 0, 0); \
            acc[1][1] = __builtin_amdgcn_mfma_f32_16x16x32_bf16(a1, b1, acc[1][1], 0, 0, 0); \
            acc[1][2] = __builtin_amdgcn_mfma_f32_16x16x32_bf16(a1, b2, acc[1][2], 0, 0, 0); \
            acc[1][3] = __builtin_amdgcn_mfma_f32_16x16x32_bf16(a1, b3, acc[1][3], 0, 0, 0); \
        }                                                                         \
    }

// ---------------------------------------------------------------------------
// q/k projection GEMM + fused per-head L2 norm + fused row-sum.
// IS_K=0: dense bf16 out [n][512] + dense red_out (qpart).
// IS_K=1: NO dense out; red_out = ksum_h; atomic ksum_w.
// ---------------------------------------------------------------------------
template<int IS_K>
__device__ void mgemm_l2_body(int nblk, int head,
                              const unsigned short* __restrict__ A,
                              const unsigned short* __restrict__ B,
                              unsigned short* __restrict__ out,
                              float* __restrict__ red_out,
                              float* __restrict__ ksum_w)
{
    __shared__ float ssq[2][2][4][16];
    __shared__ float rbuf[2][2][4][2][4];
    int nB = nblk * 128, oB = head * 64;
    int w = threadIdx.x >> 6, lane = threadIdx.x & 63;
    int l15 = lane & 15, g = lane >> 4;
    int wm = w & 1, wn = w >> 1;

    f32x4 acc[2][4];
#pragma unroll
    for (int mt = 0; mt < 2; ++mt)
#pragma unroll
        for (int nt = 0; nt < 4; ++nt) acc[mt][nt] = (f32x4){0.f,0.f,0.f,0.f};

    MGEMM_CORE(192, A + (size_t)(oB + wm * 32 + l15) * 192 + 8 * g,
                    B + (size_t)(nB + wn * 64 + l15) * 192 + 8 * g);

#pragma unroll
    for (int nt = 0; nt < 4; ++nt) {
        float s = 0.f;
#pragma unroll
        for (int mt = 0; mt < 2; ++mt) {
            f32x4 a = acc[mt][nt];
            s += (a[0]*a[0] + a[1]*a[1]) + (a[2]*a[2] + a[3]*a[3]);
        }
        s += __shfl_xor(s, 16);
        s += __shfl_xor(s, 32);
        if (g == 0) ssq[wm][wn][nt][l15] = s;
    }
    __syncthreads();

    float sc[4];
#pragma unroll
    for (int nt = 0; nt < 4; ++nt) {
        float ss2 = ssq[0][wn][nt][l15] + ssq[1][wn][nt][l15];
        sc[nt] = 1.0f / fmaxf(sqrtf(ss2), 1e-12f);
    }

    int b = nB >> 14;
    int bh = b * 8 + head;
#pragma unroll
    for (int nt = 0; nt < 4; ++nt) {
        int n = nB + wn * 64 + nt * 16 + l15;
#pragma unroll
        for (int mt = 0; mt < 2; ++mt) {
            int o = oB + wm * 32 + mt * 16 + 4 * g;
            f32x4 v = acc[mt][nt];
            if (IS_K) {
                int ww = n & (kW - 1);
                float* dst = ksum_w + ((size_t)(bh * kW + ww)) * 64 + (o & 63);
                atomicAdd(dst + 0, v[0] * sc[nt]);
                atomicAdd(dst + 1, v[1] * sc[nt]);
                atomicAdd(dst + 2, v[2] * sc[nt]);
                atomicAdd(dst + 3, v[3] * sc[nt]);
            } else {
                *(unsigned long long*)(out + (size_t)n * kHID + o) =
                    pk4(v[0]*sc[nt], v[1]*sc[nt], v[2]*sc[nt], v[3]*sc[nt]);
            }
        }
    }

    float sred[2][4] = {};
#pragma unroll
    for (int nt = 0; nt < 4; ++nt)
#pragma unroll
        for (int mt = 0; mt < 2; ++mt) {
            f32x4 a = acc[mt][nt];
            sred[mt][0] += a[0] * sc[nt];
            sred[mt][1] += a[1] * sc[nt];
            sred[mt][2] += a[2] * sc[nt];
            sred[mt][3] += a[3] * sc[nt];
        }
#pragma unroll
    for (int off = 1; off < 16; off <<= 1)
#pragma unroll
        for (int mt = 0; mt < 2; ++mt)
#pragma unroll
            for (int r = 0; r < 4; ++r)
                sred[mt][r] += __shfl_xor(sred[mt][r], off);
    if (l15 == 0)
#pragma unroll
        for (int mt = 0; mt < 2; ++mt)
#pragma unroll
            for (int r = 0; r < 4; ++r)
                rbuf[wm][wn][g][mt][r] = sred[mt][r];
    __syncthreads();
    if (threadIdx.x < 64) {
        int o = threadIdx.x;
        int wm2 = o >> 5, mt2 = (o >> 4) & 1, g2 = (o >> 2) & 3, r2 = o & 3;
        float v = rbuf[wm2][0][g2][mt2][r2] + rbuf[wm2][1][g2][mt2][r2];
        int row = (nB & (kHW - 1)) >> 7;
        red_out[((size_t)(bh * 128 + row)) * 64 + o] = v;
    }
}

// dwconv body (bf16 in -> bf16 out), id over kN*48
__device__ void dwconv_body(int idx, const unsigned short* __restrict__ in,
                            unsigned short* __restrict__ out,
                            const float* __restrict__ wt, const float* __restrict__ bias)
{
    int n = idx / 48;
    int c0 = (idx - n * 48) * 4;
    int hw = n & (kHW - 1);
    int h = hw >> 7, ww = hw & 127;
    f32x4 s = *(const f32x4*)(bias + c0);
#pragma unroll
    for (int dy = -1; dy <= 1; ++dy) {
        int hh = h + dy;
        if (hh < 0 || hh >= kH) continue;
#pragma unroll
        for (int dx = -1; dx <= 1; ++dx) {
            int wx = ww + dx;
            if (wx < 0 || wx >= kW) continue;
            f32x4 v = ubf4(*(const unsigned long long*)(in + (size_t)(n + dy * kW + dx) * kC + c0));
            int t = (dy + 1) * 3 + (dx + 1);
            s[0] += v[0] * wt[(c0 + 0) * 9 + t];
            s[1] += v[1] * wt[(c0 + 1) * 9 + t];
            s[2] += v[2] * wt[(c0 + 2) * 9 + t];
            s[3] += v[3] * wt[(c0 + 3) * 9 + t];
        }
    }
    *(unsigned long long*)(out + (size_t)n * kC + c0) = pk4(s[0], s[1], s[2], s[3]);
}

// ---------------------------------------------------------------------------
// Dispatcher: blocks [0,2048) Q-gemm, [2048,4096) K-gemm, [4096,10240) dwconv.
// ---------------------------------------------------------------------------
__global__ __launch_bounds__(256) void branch_kernel(
    const unsigned short* __restrict__ wqb, const unsigned short* __restrict__ wkb,
    const unsigned short* __restrict__ xnb, const unsigned short* __restrict__ xpb,
    unsigned short* __restrict__ qpb, float* __restrict__ qpart,
    float* __restrict__ ksum_h, float* __restrict__ ksum_w,
    unsigned short* __restrict__ lb,
    const float* __restrict__ dw_w, const float* __restrict__ dw_b)
{
    int id = blockIdx.x;
    if (id < 2048) {
        mgemm_l2_body<0>(id & 255, id >> 8, wqb, xnb, qpb, qpart, nullptr);
    } else if (id < 4096) {
        id -= 2048;
        mgemm_l2_body<1>(id & 255, id >> 8, wkb, xnb, nullptr, ksum_h, ksum_w);
    } else {
        dwconv_body((id - 4096) * 256 + threadIdx.x, xpb, lb, dw_w, dw_b);
    }
}

// ---------------------------------------------------------------------------
// c1/c2 GEMM: bf16 out [n][192] + bias + fused instance-norm partial stats.
// ---------------------------------------------------------------------------
__global__ __launch_bounds__(256) void mgemm_is_kernel(
    const unsigned short* __restrict__ A, const unsigned short* __restrict__ B,
    unsigned short* __restrict__ out, const float* __restrict__ bias,
    float* __restrict__ accp)
{
    __shared__ float sa[2][64], qa[2][64];
    int nB = blockIdx.x * 128, oB = blockIdx.y * 64;
    int w = threadIdx.x >> 6, lane = threadIdx.x & 63;
    int l15 = lane & 15, g = lane >> 4;
    int wm = w & 1, wn = w >> 1;

    f32x4 acc[2][4];
#pragma unroll
    for (int mt = 0; mt < 2; ++mt)
#pragma unroll
        for (int nt = 0; nt < 4; ++nt) acc[mt][nt] = (f32x4){0.f,0.f,0.f,0.f};

    MGEMM_CORE(192, A + (size_t)(oB + wm * 32 + l15) * 192 + 8 * g,
                    B + (size_t)(nB + wn * 64 + l15) * 192 + 8 * g);

    f32x4 vv[2][4];
#pragma unroll
    for (int mt = 0; mt < 2; ++mt)
#pragma unroll
        for (int nt = 0; nt < 4; ++nt) {
            int o = oB + wm * 32 + mt * 16 + 4 * g;
            int n = nB + wn * 64 + nt * 16 + l15;
            f32x4 v = acc[mt][nt] + *(const f32x4*)(bias + o);
            vv[mt][nt] = v;
            *(unsigned long long*)(out + (size_t)n * kC + o) = pk4(v[0], v[1], v[2], v[3]);
        }
    float s2[2][4] = {}, q2[2][4] = {};
#pragma unroll
    for (int mt = 0; mt < 2; ++mt)
#pragma unroll
        for (int nt = 0; nt < 4; ++nt)
#pragma unroll
            for (int r = 0; r < 4; ++r) {
                float v = vv[mt][nt][r];
                s2[mt][r] += v; q2[mt][r] += v * v;
            }
#pragma unroll
    for (int off = 1; off < 16; off <<= 1)
#pragma unroll
        for (int mt = 0; mt < 2; ++mt)
#pragma unroll
            for (int r = 0; r < 4; ++r) {
                s2[mt][r] += __shfl_xor(s2[mt][r], off);
                q2[mt][r] += __shfl_xor(q2[mt][r], off);
            }
    if (l15 == 0)
#pragma unroll
        for (int mt = 0; mt < 2; ++mt)
#pragma unroll
            for (int r = 0; r < 4; ++r) {
                int ol = wm * 32 + mt * 16 + 4 * g + r;
                sa[wn][ol] = s2[mt][r];
                qa[wn][ol] = q2[mt][r];
            }
    __syncthreads();
    if (threadIdx.x < 128) {
        int ol = threadIdx.x & 63, st = threadIdx.x >> 6;
        float v = st ? (qa[0][ol] + qa[1][ol]) : (sa[0][ol] + sa[1][ol]);
        int b = nB >> 14;
        atomicAdd(&accp[(size_t)(b * kC + oB + ol) * 2 + st], v);
    }
}

// ---------------------------------------------------------------------------
// Fused MLP: F = mlp_w1@LB + W2'@OB + bp2 + x(bf16)   (bf16 out [n][192])
// ---------------------------------------------------------------------------
__global__ __launch_bounds__(256) void mgemm_mlp_kernel(
    const unsigned short* __restrict__ A1, const unsigned short* __restrict__ B1,
    const unsigned short* __restrict__ A2, const unsigned short* __restrict__ B2,
    unsigned short* __restrict__ out, const float* __restrict__ bp2,
    const unsigned short* __restrict__ res)
{
    int nB = blockIdx.x * 128, oB = blockIdx.y * 64;
    int w = threadIdx.x >> 6, lane = threadIdx.x & 63;
    int l15 = lane & 15, g = lane >> 4;
    int wm = w & 1, wn = w >> 1;

    f32x4 acc[2][4];
#pragma unroll
    for (int mt = 0; mt < 2; ++mt)
#pragma unroll
        for (int nt = 0; nt < 4; ++nt) acc[mt][nt] = (f32x4){0.f,0.f,0.f,0.f};

    MGEMM_CORE(192, A1 + (size_t)(oB + wm * 32 + l15) * 192 + 8 * g,
                    B1 + (size_t)(nB + wn * 64 + l15) * 192 + 8 * g);
    MGEMM_CORE(512, A2 + (size_t)(oB + wm * 32 + l15) * 512 + 8 * g,
                    B2 + (size_t)(nB + wn * 64 + l15) * 512 + 8 * g);

#pragma unroll
    for (int mt = 0; mt < 2; ++mt)
#pragma unroll
        for (int nt = 0; nt < 4; ++nt) {
            int o = oB + wm * 32 + mt * 16 + 4 * g;
            int n = nB + wn * 64 + nt * 16 + l15;
            f32x4 v = acc[mt][nt];
            v[0] += bp2[o]; v[1] += bp2[o+1]; v[2] += bp2[o+2]; v[3] += bp2[o+3];
            v += ubf4(*(const unsigned long long*)(res + (size_t)n * kC + o));
            *(unsigned long long*)(out + (size_t)n * kC + o) = pk4(v[0], v[1], v[2], v[3]);
        }
}

// ---------------------------------------------------------------------------
// Fused qs-reduce + scores + top-16 (tie -> lower index).
// ---------------------------------------------------------------------------
__global__ void score_topk_kernel(const float* __restrict__ qpart,
                                  const float* __restrict__ ksum_h,
                                  const float* __restrict__ ksum_w,
                                  int* __restrict__ hidx, int* __restrict__ widx)
{
    __shared__ float qsl[2][64];
    __shared__ float hs[128], ws[128];
    int bh = blockIdx.x;
    int tid = threadIdx.x;               // 128
    int hc = tid & 63, grp = tid >> 6;
    {
        const float* qp = qpart + ((size_t)bh * 128 + grp * 64) * 64 + hc;
        float s = 0.f;
        for (int i = 0; i < 64; ++i) s += qp[(size_t)i * 64];
        qsl[grp][hc] = s;
    }
    __syncthreads();
    if (tid < 64) qsl[0][tid] += qsl[1][tid];
    __syncthreads();
    {
        const float* kh = ksum_h + ((size_t)bh * 128 + tid) * 64;
        const float* kw = ksum_w + ((size_t)bh * 128 + tid) * 64;
        float sh = 0.f, sw = 0.f;
        for (int c = 0; c < 64; ++c) {
            float q = qsl[0][c];
            sh += q * kh[c];
            sw += q * kw[c];
        }
        hs[tid] = sh; ws[tid] = sw;
    }
    __syncthreads();
    int sel = tid >> 6;
    const float* sc = sel ? ws : hs;
    int* out = (sel ? widx : hidx) + bh * kP;
    int lane = tid & 63;
    float v0 = sc[lane], v1 = sc[lane + 64];
    int i0 = lane, i1 = lane + 64;
    for (int p = 0; p < kP; ++p) {
        float bv; int bi;
        if (v1 > v0) { bv = v1; bi = i1; } else { bv = v0; bi = i0; }
#pragma unroll
        for (int off = 1; off < 64; off <<= 1) {
            float ov = __shfl_xor(bv, off);
            int   oi = __shfl_xor(bi, off);
            if (ov > bv || (ov == bv && oi < bi)) { bv = ov; bi = oi; }
        }
        if (lane == 0) out[p] = bi;
        if (i0 == bi) v0 = -INFINITY;
        if (i1 == bi) v1 = -INFINITY;
    }
}

// ---------------------------------------------------------------------------
// Gather: lazy-project BOTH kf (wk@xn, L2-normalized per pixel) and vfT (wv@xn).
// ---------------------------------------------------------------------------
__global__ void gather_kv_kernel(const unsigned short* __restrict__ wkb,
                                 const unsigned short* __restrict__ xnb,
                                 const float* __restrict__ wv,
                                 const int* __restrict__ hidx, const int* __restrict__ widx,
                                 unsigned short* __restrict__ kf, unsigned short* __restrict__ vfT)
{
    int bh = blockIdx.y, p1 = blockIdx.x;
    int b = bh >> 3, nh = bh & 7;
    int hc = threadIdx.x & 63, pg = threadIdx.x >> 6;
    int hrow = hidx[bh * kP + p1];
    int o = nh * kHC + hc;
    const float* wvp = wv + (size_t)o * kC;
    const unsigned short* wkp = wkb + (size_t)o * kC;
    for (int p2 = pg; p2 < kP; p2 += 4) {
        int wcol = widx[bh * kP + p2];
        int n = b * kHW + hrow * kW + wcol;
        int kidx = p1 * kP + p2;
        const unsigned int* xr = (const unsigned int*)(xnb + (size_t)n * kC);
        const unsigned int* kr = (const unsigned int*)wkp;
        float sv = 0.f, sk = 0.f;
        for (int c2 = 0; c2 < kC / 2; ++c2) {
            unsigned int u = xr[c2];
            float x0 = bf2f((unsigned short)(u & 0xffff));
            float x1 = bf2f((unsigned short)(u >> 16));
            sv += wvp[c2 * 2] * x0 + wvp[c2 * 2 + 1] * x1;
            unsigned int kw2 = kr[c2];
            sk += bf2f((unsigned short)(kw2 & 0xffff)) * x0
                + bf2f((unsigned short)(kw2 >> 16)) * x1;
        }
        // L2 norm of k over the 64 head-channels (one wave = 64 hc for this pixel)
        float ss = sk * sk;
#pragma unroll
        for (int off = 1; off < 64; off <<= 1) ss += __shfl_xor(ss, off);
        float sc = 1.0f / fmaxf(sqrtf(ss), 1e-12f);
        kf[((size_t)bh * 256 + kidx) * 64 + hc] = f2bf(sk * sc);
        vfT[((size_t)bh * 64 + hc) * 256 + kidx] = f2bf(sv);
    }
}

// ---------------------------------------------------------------------------
// MFMA attention, QBLK=128: kf fragments loaded once, reused for 2 q-subtiles.
// P in LDS stride-256 + XOR swizzle (conflict-free).
// ---------------------------------------------------------------------------
__global__ __launch_bounds__(256) void attn_kernel(
    const unsigned short* __restrict__ qpb, unsigned short* __restrict__ ob,
    const unsigned short* __restrict__ kf, const unsigned short* __restrict__ vfT)
{
    __shared__ unsigned short pls[64 * 256];
    __shared__ float lred[4][4][16];

    int bh = blockIdx.y; int b = bh >> 3, nh = bh & 7;
    int nbase = b * kHW + blockIdx.x * 128;
    int tid = threadIdx.x;
    int w = tid >> 6, lane = tid & 63, l15 = lane & 15, g = lane >> 4;

    const unsigned short* kfb = kf + (size_t)bh * 256 * 64;
    bf16x8 ak[4][2];
#pragma unroll
    for (int mt = 0; mt < 4; ++mt)
#pragma unroll
        for (int kt = 0; kt < 2; ++kt)
            ak[mt][kt] = *(const bf16x8*)&kfb[(size_t)(w * 64 + mt * 16 + l15) * 64 + kt * 32 + 8 * g];

    const unsigned short* vfb = vfT + (size_t)bh * 64 * 256;

#pragma unroll
    for (int sub = 0; sub < 2; ++sub) {
        int n0 = nbase + sub * 64;
        bf16x8 bq[4][2];
#pragma unroll
        for (int nt = 0; nt < 4; ++nt)
#pragma unroll
            for (int kt = 0; kt < 2; ++kt)
                bq[nt][kt] = *(const bf16x8*)(qpb + (size_t)(n0 + nt * 16 + l15) * kHID
                                              + nh * kHC + kt * 32 + 8 * g);

        f32x4 acc[4][4];
#pragma unroll
        for (int mt = 0; mt < 4; ++mt)
#pragma unroll
            for (int nt = 0; nt < 4; ++nt) acc[mt][nt] = (f32x4){0.f,0.f,0.f,0.f};

#pragma unroll
        for (int kt = 0; kt < 2; ++kt)
#pragma unroll
            for (int mt = 0; mt < 4; ++mt)
#pragma unroll
                for (int nt = 0; nt < 4; ++nt)
                    acc[mt][nt] = __builtin_amdgcn_mfma_f32_16x16x32_bf16(
                        ak[mt][kt], bq[nt][kt], acc[mt][nt], 0, 0, 0);

        if (sub) __syncthreads();   // protect pls/lred from previous subtile readers

        float lpart[4] = {0.f, 0.f, 0.f, 0.f};
#pragma unroll
        for (int mt = 0; mt < 4; ++mt)
#pragma unroll
            for (int nt = 0; nt < 4; ++nt) {
                float e0 = __expf(acc[mt][nt][0]);
                float e1 = __expf(acc[mt][nt][1]);
                float e2 = __expf(acc[mt][nt][2]);
                float e3 = __expf(acc[mt][nt][3]);
                lpart[nt] += (e0 + e1) + (e2 + e3);
                int qq = nt * 16 + l15;
                int k0 = w * 64 + mt * 16 + 4 * g;
                int kx = k0 ^ ((qq & 7) << 3);
                *(unsigned long long*)&pls[qq * 256 + kx] = pk4(e0, e1, e2, e3);
            }
#pragma unroll
        for (int nt = 0; nt < 4; ++nt) {
            lpart[nt] += __shfl_xor(lpart[nt], 16);
            lpart[nt] += __shfl_xor(lpart[nt], 32);
        }
        if (g == 0)
#pragma unroll
            for (int nt = 0; nt < 4; ++nt) lred[w][nt][l15] = lpart[nt];
        __syncthreads();

        f32x4 oacc[4];
#pragma unroll
        for (int nt = 0; nt < 4; ++nt) oacc[nt] = (f32x4){0.f,0.f,0.f,0.f};

#pragma unroll
        for (int ks = 0; ks < 8; ++ks) {
            bf16x8 av = *(const bf16x8*)&vfb[(size_t)(w * 16 + l15) * 256 + ks * 32 + 8 * g];
#pragma unroll
            for (int nt = 0; nt < 4; ++nt) {
                int qq = nt * 16 + l15;
                int kx = (ks * 32 + 8 * g) ^ ((qq & 7) << 3);
                bf16x8 bp = *(const bf16x8*)&pls[qq * 256 + kx];
                oacc[nt] = __builtin_amdgcn_mfma_f32_16x16x32_bf16(av, bp, oacc[nt], 0, 0, 0);
            }
        }

#pragma unroll
        for (int nt = 0; nt < 4; ++nt) {
            float l = lred[0][nt][l15] + lred[1][nt][l15] + lred[2][nt][l15] + lred[3][nt][l15];
            float inv = 1.0f / l;
            int qq = nt * 16 + l15;
            int hc0 = w * 16 + 4 * g;
            *(unsigned long long*)(ob + (size_t)(n0 + qq) * kHID + nh * kHC + hc0) =
                pk4(oacc[nt][0] * inv, oacc[nt][1] * inv, oacc[nt][2] * inv, oacc[nt][3] * inv);
        }
    }
}

// ---------------------------------------------------------------------------
// Instance-norm stats (bf16 input) via per-chunk atomics.
// ---------------------------------------------------------------------------
__global__ void istats_bf16_kernel(const unsigned short* __restrict__ in, float* __restrict__ acc)
{
    int n0 = blockIdx.x * 64;
    int b = n0 >> 14;
    int c = threadIdx.x;
    float s = 0.f, ss = 0.f;
    for (int p = 0; p < 64; ++p) {
        float v = bf2f(in[(size_t)(n0 + p) * kC + c]);
        s += v; ss += v * v;
    }
    atomicAdd(&acc[(size_t)(b * kC + c) * 2],     s);
    atomicAdd(&acc[(size_t)(b * kC + c) * 2 + 1], ss);
}

__device__ inline void inorm_ms(const float* acc, int b, int c, float& m, float& rs)
{
    float s  = acc[(size_t)(b * kC + c) * 2];
    float ss = acc[(size_t)(b * kC + c) * 2 + 1];
    m = s * (1.0f / kHW);
    float var = ss * (1.0f / kHW) - m * m;
    rs = rsqrtf(var + kEPS);
}

// ---------------------------------------------------------------------------
// Fused res-dwconv: R = res_b + dwconv(gelu(inorm_acc0(T1)))  (Y2 on the fly).
// ---------------------------------------------------------------------------
__global__ void dwconv_gelu_kernel(const unsigned short* __restrict__ t1,
                                   const float* __restrict__ acc0,
                                   unsigned short* __restrict__ rout,
                                   const float* __restrict__ wt, const float* __restrict__ bias)
{
    int idx = blockIdx.x * 256 + threadIdx.x;      // kN*48
    int n = idx / 48;
    int c0 = (idx - n * 48) * 4;
    int hw = n & (kHW - 1);
    int b = n >> 14;
    int h = hw >> 7, ww = hw & 127;
    float m[4], rs[4];
#pragma unroll
    for (int j = 0; j < 4; ++j) inorm_ms(acc0, b, c0 + j, m[j], rs[j]);
    f32x4 s = *(const f32x4*)(bias + c0);
#pragma unroll
    for (int dy = -1; dy <= 1; ++dy) {
        int hh = h + dy;
        if (hh < 0 || hh >= kH) continue;
#pragma unroll
        for (int dx = -1; dx <= 1; ++dx) {
            int wx = ww + dx;
            if (wx < 0 || wx >= kW) continue;
            f32x4 v = ubf4(*(const unsigned long long*)(t1 + (size_t)(n + dy * kW + dx) * kC + c0));
            int t = (dy + 1) * 3 + (dx + 1);
#pragma unroll
            for (int j = 0; j < 4; ++j)
                s[j] += gelu_f((v[j] - m[j]) * rs[j]) * wt[(c0 + j) * 9 + t];
        }
    }
    *(unsigned long long*)(rout + (size_t)n * kC + c0) = pk4(s[0], s[1], s[2], s[3]);
}

// ---------------------------------------------------------------------------
// Y3 = gelu(inorm_acc1(R)) + gelu(inorm_acc0(T1))   (recomputes y2 inline)
// ---------------------------------------------------------------------------
__global__ void apply_res_kernel(const unsigned short* __restrict__ r,
                                 const unsigned short* __restrict__ t1,
                                 const float* __restrict__ acc1, const float* __restrict__ acc0,
                                 unsigned short* __restrict__ out)
{
    int idx = blockIdx.x * 256 + threadIdx.x;      // kN*48
    int n = idx / 48;
    int c0 = (idx - n * 48) * 4;
    int b = n >> 14;
    f32x4 vr = ubf4(*(const unsigned long long*)(r  + (size_t)n * kC + c0));
    f32x4 vt = ubf4(*(const unsigned long long*)(t1 + (size_t)n * kC + c0));
    f32x4 o;
#pragma unroll
    for (int j = 0; j < 4; ++j) {
        float m1, rs1, m0, rs0;
        inorm_ms(acc1, b, c0 + j, m1, rs1);
        inorm_ms(acc0, b, c0 + j, m0, rs0);
        o[j] = gelu_f((vr[j] - m1) * rs1) + gelu_f((vt[j] - m0) * rs0);
    }
    *(unsigned long long*)(out + (size_t)n * kC + c0) = pk4(o[0], o[1], o[2], o[3]);
}

// ---------------------------------------------------------------------------
// Final inorm via LDS transpose: bf16 pixel-major in -> NCHW fp32 d_out.
// ---------------------------------------------------------------------------
__global__ __launch_bounds__(256) void final_kernel(const unsigned short* __restrict__ in,
                                                    const float* __restrict__ acc,
                                                    float* __restrict__ out)
{
    __shared__ unsigned short tile[192][68];
    int n0 = blockIdx.x * 64;
    int b = n0 >> 14;
    int hw0 = n0 & (kHW - 1);
    int tid = threadIdx.x;
    for (int i = tid; i < 64 * 48; i += 256) {
        int p = i / 48, cq = i - p * 48;
        unsigned long long u = *(const unsigned long long*)(in + (size_t)(n0 + p) * kC + cq * 4);
        tile[cq * 4 + 0][p] = (unsigned short)u;
        tile[cq * 4 + 1][p] = (unsigned short)(u >> 16);
        tile[cq * 4 + 2][p] = (unsigned short)(u >> 32);
        tile[cq * 4 + 3][p] = (unsigned short)(u >> 48);
    }
    __syncthreads();
    for (int i = tid; i < 192 * 16; i += 256) {
        int c = i >> 4, grp = i & 15;
        float m, rs;
        inorm_ms(acc, b, c, m, rs);
        f32x4 o;
#pragma unroll
        for (int j = 0; j < 4; ++j)
            o[j] = (bf2f(tile[c][grp * 4 + j]) - m) * rs;
        *(f32x4*)(out + (size_t)(b * kC + c) * kHW + hw0 + grp * 4) = o;
    }
}

// ---------------------------------------------------------------------------
extern "C" void kernel_launch(void* const* d_in, const int* in_sizes, int n_in,
                              void* d_out, int out_size, void* d_ws, size_t ws_size,
                              hipStream_t stream)
{
    const float* x     = (const float*)d_in[0];
    const float* ln1_g = (const float*)d_in[1];
    const float* ln1_b = (const float*)d_in[2];
    const float* wq    = (const float*)d_in[3];
    const float* wk    = (const float*)d_in[4];
    const float* wv    = (const float*)d_in[5];
    const float* wo    = (const float*)d_in[6];
    const float* bo    = (const float*)d_in[7];
    const float* dw_w  = (const float*)d_in[8];
    const float* dw_b  = (const float*)d_in[9];
    const float* mlp_w = (const float*)d_in[10];
    const float* mlp_b = (const float*)d_in[11];
    const float* ln2_g = (const float*)d_in[12];
    const float* ln2_b = (const float*)d_in[13];
    const float* c1_w  = (const float*)d_in[14];
    const float* c1_b  = (const float*)d_in[15];
    const float* res_w = (const float*)d_in[16];
    const float* res_b = (const float*)d_in[17];
    const float* c2_w  = (const float*)d_in[18];
    const float* c2_b  = (const float*)d_in[19];

    char* base = (char*)d_ws;
    unsigned short* XPb = (unsigned short*)(base);               // bf16 [n][192] raw x
    unsigned short* XNb = (unsigned short*)(base + 25165824);    // bf16 [n][192] xn / Y1
    unsigned short* QPb = (unsigned short*)(base + 37748736);    // bf16 [n][512]; later F / T2
    unsigned short* F   = QPb;
    unsigned short* T2  = QPb;
    unsigned short* OB  = (unsigned short*)(base + 71303168);    // bf16 [n][512] attn out; later R
    unsigned short* R   = OB;                                    // (OB dead after mlp)
    unsigned short* LB  = (unsigned short*)(base + 104857600);   // bf16 [n][192] local; later Y3
    unsigned short* Y3  = LB;
    unsigned short* T1  = (unsigned short*)(base + 117440512);   // bf16 [n][192]
    char* sm = base + 130023424;
    float* qpart  = (float*)(sm);                 sm += 524288;   // [16][128][64]
    float* ksum_h = (float*)(sm);                 sm += 524288;
    float* acc0   = (float*)(sm);                 sm += 3072;     // zero block start
    float* acc1   = (float*)(sm);                 sm += 3072;
    float* acc2   = (float*)(sm);                 sm += 3072;
    float* ksum_w = (float*)(sm);                 sm += 524288;   // zero block end
    unsigned short* kf   = (unsigned short*)(sm); sm += 524288;
    unsigned short* vfT  = (unsigned short*)(sm); sm += 524288;
    unsigned short* wqb  = (unsigned short*)(sm); sm += 196608;
    unsigned short* wkb  = (unsigned short*)(sm); sm += 196608;
    unsigned short* mlpb1= (unsigned short*)(sm); sm += 73728;
    unsigned short* c1b  = (unsigned short*)(sm); sm += 73728;
    unsigned short* c2b  = (unsigned short*)(sm); sm += 73728;
    unsigned short* w2pb = (unsigned short*)(sm); sm += 196608;
    float* bp2 = (float*)(sm);                    sm += 1024;
    int* hidx = (int*)(sm);                       sm += 1024;
    int* widx = (int*)(sm);

    // 1. prep: zero (acc0..2 + ksum_w) + weight cvts + fused W2'
    prep_kernel<<<2111, 256, 0, stream>>>(acc0, wq, wk, mlp_w, c1_w, c2_w,
                                          wo, mlp_b, bo,
                                          wqb, wkb, mlpb1, c1b, c2b, w2pb, bp2);
    // 2. transpose + ln1
    txln_kernel<<<dim3(kHW / 64, kB), 256, 0, stream>>>(x, XPb, XNb, ln1_g, ln1_b);
    // 3. fused: Q-gemm | K-gemm (reductions only) | local dwconv
    branch_kernel<<<10240, 256, 0, stream>>>(wqb, wkb, XNb, XPb, QPb, qpart,
                                             ksum_h, ksum_w, LB, dw_w, dw_b);
    // 4. scores + top-16
    score_topk_kernel<<<16, 128, 0, stream>>>(qpart, ksum_h, ksum_w, hidx, widx);
    // 5. gather: lazy kf + vfT
    gather_kv_kernel<<<dim3(kP, 16), 256, 0, stream>>>(wkb, XNb, wv, hidx, widx, kf, vfT);
    // 6. attention (QBLK=128)
    attn_kernel<<<dim3(kHW / 128, 16), 256, 0, stream>>>(QPb, OB, kf, vfT);
    // 7. fused mlp (wo folded) + residual
    mgemm_mlp_kernel<<<dim3(kN / 128, kC / 64), 256, 0, stream>>>(mlpb1, LB, w2pb, OB, F, bp2, XPb);
    // 8. ln2
    ln_pm_bf16_kernel<<<(kN * 4) / 256, 256, 0, stream>>>(F, XNb, ln2_g, ln2_b);
    // 9. c1 GEMM + istats(acc0)
    mgemm_is_kernel<<<dim3(kN / 128, kC / 64), 256, 0, stream>>>(c1b, XNb, T1, c1_b, acc0);
    // 10. res dwconv with inline gelu(inorm(T1))  -> R
    dwconv_gelu_kernel<<<(kN * 48) / 256, 256, 0, stream>>>(T1, acc0, R, res_w, res_b);
    // 11. istats(R) -> acc1
    istats_bf16_kernel<<<kN / 64, 192, 0, stream>>>(R, acc1);
    // 12. Y3 = gelu(inorm(R)) + gelu(inorm(T1))
    apply_res_kernel<<<(kN * 48) / 256, 256, 0, stream>>>(R, T1, acc1, acc0, Y3);
    // 13. c2 GEMM + istats(acc2)
    mgemm_is_kernel<<<dim3(kN / 128, kC / 64), 256, 0, stream>>>(c2b, Y3, T2, c2_b, acc2);
    // 14. final inorm -> d_out
    final_kernel<<<kN / 64, 256, 0, stream>>>(T2, acc2, (float*)d_out);
}

// Round 10
// 484.886 us; speedup vs baseline: 1.4361x; 1.4361x over previous
//
#include <hip/hip_runtime.h>
#include <math.h>

constexpr int kC   = 192;
constexpr int kNH  = 8;
constexpr int kHC  = 64;
constexpr int kHID = 512;
constexpr int kP   = 16;
constexpr int kB   = 2;
constexpr int kH   = 128;
constexpr int kW   = 128;
constexpr int kHW  = kH * kW;      // 16384
constexpr int kN   = kB * kHW;     // 32768
constexpr float kEPS = 1e-5f;

typedef __attribute__((ext_vector_type(8))) short bf16x8;
typedef __attribute__((ext_vector_type(4))) float f32x4;

__device__ inline unsigned short f2bf(float f) {
    unsigned int u = __builtin_bit_cast(unsigned int, f);
    unsigned int r = (u + 0x7FFFu + ((u >> 16) & 1u)) >> 16;   // RNE
    return (unsigned short)r;
}
__device__ inline float bf2f(unsigned short u) {
    return __builtin_bit_cast(float, (unsigned int)u << 16);
}
__device__ inline unsigned int cvtpk(float lo, float hi) {
    unsigned int r;
    asm("v_cvt_pk_bf16_f32 %0, %1, %2" : "=v"(r) : "v"(lo), "v"(hi));
    return r;
}
__device__ inline unsigned long long pk4(float a, float b, float c, float d) {
    return (unsigned long long)cvtpk(a, b) | ((unsigned long long)cvtpk(c, d) << 32);
}
__device__ inline f32x4 ubf4(unsigned long long u) {
    f32x4 r;
    r[0] = bf2f((unsigned short)u);
    r[1] = bf2f((unsigned short)(u >> 16));
    r[2] = bf2f((unsigned short)(u >> 32));
    r[3] = bf2f((unsigned short)(u >> 48));
    return r;
}
__device__ inline float gelu_f(float x) {
    return 0.5f * x * (1.0f + erff(x * 0.70710678118654752f));
}

// ---------------------------------------------------------------------------
// Prep: zero acc0..2 + bf16 weight cvts + fused W2' weight.
// ---------------------------------------------------------------------------
__global__ void prep_kernel(float* __restrict__ zbase,
                            const float* wq, const float* wk, const float* wm,
                            const float* c1, const float* c2,
                            const float* wo, const float* mlp_b, const float* bo,
                            unsigned short* wqb, unsigned short* wkb,
                            unsigned short* mlpb1, unsigned short* c1b, unsigned short* c2b,
                            unsigned short* w2pb, float* bp2)
{
    int i = blockIdx.x * 256 + threadIdx.x;
    if (i < 2304) { zbase[i] = 0.f; return; }            // acc0..2
    i -= 2304;
    if (i < 98304) { wqb[i] = f2bf(wq[i]); return; }
    i -= 98304;
    if (i < 98304) { wkb[i] = f2bf(wk[i]); return; }
    i -= 98304;
    if (i < 36864) { int o = i / 192, k = i - o * 192; mlpb1[i] = f2bf(wm[o * 384 + k]); return; }
    i -= 36864;
    if (i < 36864) { c1b[i] = f2bf(c1[i]); return; }
    i -= 36864;
    if (i < 36864) { c2b[i] = f2bf(c2[i]); return; }
    i -= 36864;
    if (i < 98304) {
        int o = i >> 9, j = i & 511;
        const float* a = wm + o * 384 + 192;
        float s = 0.f;
        for (int c = 0; c < 192; ++c) s += a[c] * wo[c * 512 + j];
        w2pb[o * 512 + j] = f2bf(s);
        if (j == 0) {
            float t = mlp_b[o];
            for (int c = 0; c < 192; ++c) t += a[c] * bo[c];
            bp2[o] = t;
        }
    }
}

// ---------------------------------------------------------------------------
// Fused transpose + ln1: x NCHW fp32 -> XPb raw bf16 [n][192] + XNb bf16.
// ---------------------------------------------------------------------------
__global__ __launch_bounds__(256) void txln_kernel(const float* __restrict__ x,
                                                   unsigned short* __restrict__ xpb,
                                                   unsigned short* __restrict__ xnb,
                                                   const float* __restrict__ g,
                                                   const float* __restrict__ bb)
{
    __shared__ float tile[192][65];
    __shared__ float red[2][4][64];
    __shared__ float pms[64], prs[64];
    int hw0 = blockIdx.x * 64;
    int b   = blockIdx.y;
    int tid = threadIdx.x;
    for (int i = tid; i < 192 * 64; i += 256) {
        int c = i >> 6, p = i & 63;
        tile[c][p] = x[(size_t)(b * kC + c) * kHW + hw0 + p];
    }
    __syncthreads();
    {
        int p = tid & 63, qt = tid >> 6;
        float s = 0.f, ss = 0.f;
        for (int c = qt * 48; c < qt * 48 + 48; ++c) {
            float v = tile[c][p]; s += v; ss += v * v;
        }
        red[0][qt][p] = s; red[1][qt][p] = ss;
    }
    __syncthreads();
    if (tid < 64) {
        float s  = red[0][0][tid] + red[0][1][tid] + red[0][2][tid] + red[0][3][tid];
        float ss = red[1][0][tid] + red[1][1][tid] + red[1][2][tid] + red[1][3][tid];
        float m = s * (1.0f / kC);
        float var = ss * (1.0f / kC) - m * m;
        pms[tid] = m;
        prs[tid] = rsqrtf(var + kEPS);
    }
    __syncthreads();
    for (int i = tid; i < 64 * 192; i += 256) {
        int p = i / 192, c = i - p * 192;
        float raw = tile[c][p];
        size_t oi = (size_t)(b * kHW + hw0 + p) * kC + c;
        xpb[oi] = f2bf(raw);
        xnb[oi] = f2bf((raw - pms[p]) * prs[p] * g[c] + bb[c]);
    }
}

// ---------------------------------------------------------------------------
// LayerNorm (ln2), bf16 -> bf16, 4 threads per pixel.
// ---------------------------------------------------------------------------
__global__ void ln_pm_bf16_kernel(const unsigned short* __restrict__ in,
                                  unsigned short* __restrict__ out,
                                  const float* __restrict__ g, const float* __restrict__ bb)
{
    int t = blockIdx.x * 256 + threadIdx.x;     // kN*4
    int n = t >> 2, q = t & 3;
    const unsigned long long* ip = (const unsigned long long*)(in + (size_t)n * kC) + q * 12;
    f32x4 v[12];
    float s = 0.f, ss = 0.f;
#pragma unroll
    for (int r = 0; r < 12; ++r) {
        v[r] = ubf4(ip[r]);
        s  += (v[r][0] + v[r][1]) + (v[r][2] + v[r][3]);
        ss += (v[r][0]*v[r][0] + v[r][1]*v[r][1]) + (v[r][2]*v[r][2] + v[r][3]*v[r][3]);
    }
    s  += __shfl_xor(s, 1);  s  += __shfl_xor(s, 2);
    ss += __shfl_xor(ss, 1); ss += __shfl_xor(ss, 2);
    float m  = s * (1.0f / kC);
    float var = ss * (1.0f / kC) - m * m;
    float rs = rsqrtf(var + kEPS);
    unsigned long long* op = (unsigned long long*)(out + (size_t)n * kC) + q * 12;
#pragma unroll
    for (int r = 0; r < 12; ++r) {
        f32x4 gg = *(const f32x4*)(g + q * 48 + r * 4);
        f32x4 bv = *(const f32x4*)(bb + q * 48 + r * 4);
        op[r] = pk4((v[r][0]-m)*rs*gg[0] + bv[0], (v[r][1]-m)*rs*gg[1] + bv[1],
                    (v[r][2]-m)*rs*gg[2] + bv[2], (v[r][3]-m)*rs*gg[3] + bv[3]);
    }
}

#define MGEMM_CORE(KVAL, APTR, BPTR)                                              \
    {                                                                             \
        const unsigned short* Ap = APTR;                                          \
        const unsigned short* Bp = BPTR;                                          \
        _Pragma("unroll 2")                                                       \
        for (int k = 0; k < KVAL; k += 32) {                                      \
            bf16x8 a0 = *(const bf16x8*)(Ap + k);                                 \
            bf16x8 a1 = *(const bf16x8*)(Ap + (size_t)16 * KVAL + k);             \
            bf16x8 b0 = *(const bf16x8*)(Bp + k);                                 \
            bf16x8 b1 = *(const bf16x8*)(Bp + (size_t)16 * KVAL + k);             \
            bf16x8 b2 = *(const bf16x8*)(Bp + (size_t)32 * KVAL + k);             \
            bf16x8 b3 = *(const bf16x8*)(Bp + (size_t)48 * KVAL + k);             \
            acc[0][0] = __builtin_amdgcn_mfma_f32_16x16x32_bf16(a0, b0, acc[0][0], 0, 0, 0); \
            acc[0][1] = __builtin_amdgcn_mfma_f32_16x16x32_bf16(a0, b1, acc[0][1], 0, 0, 0); \
            acc[0][2] = __builtin_amdgcn_mfma_f32_16x16x32_bf16(a0, b2, acc[0][2], 0, 0, 0); \
            acc[0][3] = __builtin_amdgcn_mfma_f32_16x16x32_bf16(a0, b3, acc[0][3], 0, 0, 0); \
            acc[1][0] = __builtin_amdgcn_mfma_f32_16x16x32_bf16(a1, b0, acc[1][0], 0, 0, 0); \
            acc[1][1] = __builtin_amdgcn_mfma_f32_16x16x32_bf16(a1, b1, acc[1][1], 0, 0, 0); \
            acc[1][2] = __builtin_amdgcn_mfma_f32_16x16x32_bf16(a1, b2, acc[1][2], 0, 0, 0); \
            acc[1][3] = __builtin_amdgcn_mfma_f32_16x16x32_bf16(a1, b3, acc[1][3], 0, 0, 0); \
        }                                                                         \
    }

// ---------------------------------------------------------------------------
// q/k projection GEMM + fused per-head L2 norm + fused row-sum (dense out).
// ---------------------------------------------------------------------------
__device__ void mgemm_l2_body(int nblk, int head,
                              const unsigned short* __restrict__ A,
                              const unsigned short* __restrict__ B,
                              unsigned short* __restrict__ out,
                              float* __restrict__ red_out)
{
    __shared__ float ssq[2][2][4][16];
    __shared__ float rbuf[2][2][4][2][4];
    int nB = nblk * 128, oB = head * 64;
    int w = threadIdx.x >> 6, lane = threadIdx.x & 63;
    int l15 = lane & 15, g = lane >> 4;
    int wm = w & 1, wn = w >> 1;

    f32x4 acc[2][4];
#pragma unroll
    for (int mt = 0; mt < 2; ++mt)
#pragma unroll
        for (int nt = 0; nt < 4; ++nt) acc[mt][nt] = (f32x4){0.f,0.f,0.f,0.f};

    MGEMM_CORE(192, A + (size_t)(oB + wm * 32 + l15) * 192 + 8 * g,
                    B + (size_t)(nB + wn * 64 + l15) * 192 + 8 * g);

#pragma unroll
    for (int nt = 0; nt < 4; ++nt) {
        float s = 0.f;
#pragma unroll
        for (int mt = 0; mt < 2; ++mt) {
            f32x4 a = acc[mt][nt];
            s += (a[0]*a[0] + a[1]*a[1]) + (a[2]*a[2] + a[3]*a[3]);
        }
        s += __shfl_xor(s, 16);
        s += __shfl_xor(s, 32);
        if (g == 0) ssq[wm][wn][nt][l15] = s;
    }
    __syncthreads();

    float sc[4];
#pragma unroll
    for (int nt = 0; nt < 4; ++nt) {
        float ss2 = ssq[0][wn][nt][l15] + ssq[1][wn][nt][l15];
        sc[nt] = 1.0f / fmaxf(sqrtf(ss2), 1e-12f);
    }

#pragma unroll
    for (int nt = 0; nt < 4; ++nt) {
        int n = nB + wn * 64 + nt * 16 + l15;
#pragma unroll
        for (int mt = 0; mt < 2; ++mt) {
            int o = oB + wm * 32 + mt * 16 + 4 * g;
            f32x4 v = acc[mt][nt];
            *(unsigned long long*)(out + (size_t)n * kHID + o) =
                pk4(v[0]*sc[nt], v[1]*sc[nt], v[2]*sc[nt], v[3]*sc[nt]);
        }
    }

    float sred[2][4] = {};
#pragma unroll
    for (int nt = 0; nt < 4; ++nt)
#pragma unroll
        for (int mt = 0; mt < 2; ++mt) {
            f32x4 a = acc[mt][nt];
            sred[mt][0] += a[0] * sc[nt];
            sred[mt][1] += a[1] * sc[nt];
            sred[mt][2] += a[2] * sc[nt];
            sred[mt][3] += a[3] * sc[nt];
        }
#pragma unroll
    for (int off = 1; off < 16; off <<= 1)
#pragma unroll
        for (int mt = 0; mt < 2; ++mt)
#pragma unroll
            for (int r = 0; r < 4; ++r)
                sred[mt][r] += __shfl_xor(sred[mt][r], off);
    if (l15 == 0)
#pragma unroll
        for (int mt = 0; mt < 2; ++mt)
#pragma unroll
            for (int r = 0; r < 4; ++r)
                rbuf[wm][wn][g][mt][r] = sred[mt][r];
    __syncthreads();
    if (threadIdx.x < 64) {
        int o = threadIdx.x;
        int wm2 = o >> 5, mt2 = (o >> 4) & 1, g2 = (o >> 2) & 3, r2 = o & 3;
        float v = rbuf[wm2][0][g2][mt2][r2] + rbuf[wm2][1][g2][mt2][r2];
        int row = (nB & (kHW - 1)) >> 7;
        int b = nB >> 14;
        int bh = b * 8 + head;
        red_out[((size_t)(bh * 128 + row)) * 64 + o] = v;
    }
}

// dwconv body (bf16 in -> bf16 out), id over kN*48
__device__ void dwconv_body(int idx, const unsigned short* __restrict__ in,
                            unsigned short* __restrict__ out,
                            const float* __restrict__ wt, const float* __restrict__ bias)
{
    int n = idx / 48;
    int c0 = (idx - n * 48) * 4;
    int hw = n & (kHW - 1);
    int h = hw >> 7, ww = hw & 127;
    f32x4 s = *(const f32x4*)(bias + c0);
#pragma unroll
    for (int dy = -1; dy <= 1; ++dy) {
        int hh = h + dy;
        if (hh < 0 || hh >= kH) continue;
#pragma unroll
        for (int dx = -1; dx <= 1; ++dx) {
            int wx = ww + dx;
            if (wx < 0 || wx >= kW) continue;
            f32x4 v = ubf4(*(const unsigned long long*)(in + (size_t)(n + dy * kW + dx) * kC + c0));
            int t = (dy + 1) * 3 + (dx + 1);
            s[0] += v[0] * wt[(c0 + 0) * 9 + t];
            s[1] += v[1] * wt[(c0 + 1) * 9 + t];
            s[2] += v[2] * wt[(c0 + 2) * 9 + t];
            s[3] += v[3] * wt[(c0 + 3) * 9 + t];
        }
    }
    *(unsigned long long*)(out + (size_t)n * kC + c0) = pk4(s[0], s[1], s[2], s[3]);
}

// ---------------------------------------------------------------------------
// Dispatcher: [0,2048) Q-gemm, [2048,4096) K-gemm (dense), [4096,10240) dwconv.
// ---------------------------------------------------------------------------
__global__ __launch_bounds__(256) void branch_kernel(
    const unsigned short* __restrict__ wqb, const unsigned short* __restrict__ wkb,
    const unsigned short* __restrict__ xnb, const unsigned short* __restrict__ xpb,
    unsigned short* __restrict__ qpb, unsigned short* __restrict__ kpb,
    float* __restrict__ qpart, float* __restrict__ ksum_h,
    unsigned short* __restrict__ lb,
    const float* __restrict__ dw_w, const float* __restrict__ dw_b)
{
    int id = blockIdx.x;
    if (id < 2048) {
        mgemm_l2_body(id & 255, id >> 8, wqb, xnb, qpb, qpart);
    } else if (id < 4096) {
        id -= 2048;
        mgemm_l2_body(id & 255, id >> 8, wkb, xnb, kpb, ksum_h);
    } else {
        dwconv_body((id - 4096) * 256 + threadIdx.x, xpb, lb, dw_w, dw_b);
    }
}

// ksum_w[bh][w][hc] = sum_h k.  256 threads: 4 h-segments of 32 + LDS reduce.
__global__ void sum_h_kernel(const unsigned short* __restrict__ buf, float* __restrict__ out)
{
    __shared__ float red[4][64];
    int w = blockIdx.x, bh = blockIdx.y;
    int hc = threadIdx.x & 63, seg = threadIdx.x >> 6;
    int b = bh >> 3, nh = bh & 7;
    const unsigned short* p = buf + (size_t)(b * kHW + seg * 32 * kW + w) * kHID + nh * kHC + hc;
    float s = 0.f;
    for (int h = 0; h < 32; ++h) s += bf2f(p[(size_t)h * kW * kHID]);
    red[seg][hc] = s;
    __syncthreads();
    if (threadIdx.x < 64)
        out[((size_t)bh * kW + w) * kHC + threadIdx.x] =
            red[0][threadIdx.x] + red[1][threadIdx.x] + red[2][threadIdx.x] + red[3][threadIdx.x];
}

// ---------------------------------------------------------------------------
// c1/c2 GEMM: bf16 out [n][192] + bias + fused instance-norm partial stats.
// ---------------------------------------------------------------------------
__global__ __launch_bounds__(256) void mgemm_is_kernel(
    const unsigned short* __restrict__ A, const unsigned short* __restrict__ B,
    unsigned short* __restrict__ out, const float* __restrict__ bias,
    float* __restrict__ accp)
{
    __shared__ float sa[2][64], qa[2][64];
    int nB = blockIdx.x * 128, oB = blockIdx.y * 64;
    int w = threadIdx.x >> 6, lane = threadIdx.x & 63;
    int l15 = lane & 15, g = lane >> 4;
    int wm = w & 1, wn = w >> 1;

    f32x4 acc[2][4];
#pragma unroll
    for (int mt = 0; mt < 2; ++mt)
#pragma unroll
        for (int nt = 0; nt < 4; ++nt) acc[mt][nt] = (f32x4){0.f,0.f,0.f,0.f};

    MGEMM_CORE(192, A + (size_t)(oB + wm * 32 + l15) * 192 + 8 * g,
                    B + (size_t)(nB + wn * 64 + l15) * 192 + 8 * g);

    f32x4 vv[2][4];
#pragma unroll
    for (int mt = 0; mt < 2; ++mt)
#pragma unroll
        for (int nt = 0; nt < 4; ++nt) {
            int o = oB + wm * 32 + mt * 16 + 4 * g;
            int n = nB + wn * 64 + nt * 16 + l15;
            f32x4 v = acc[mt][nt] + *(const f32x4*)(bias + o);
            vv[mt][nt] = v;
            *(unsigned long long*)(out + (size_t)n * kC + o) = pk4(v[0], v[1], v[2], v[3]);
        }
    float s2[2][4] = {}, q2[2][4] = {};
#pragma unroll
    for (int mt = 0; mt < 2; ++mt)
#pragma unroll
        for (int nt = 0; nt < 4; ++nt)
#pragma unroll
            for (int r = 0; r < 4; ++r) {
                float v = vv[mt][nt][r];
                s2[mt][r] += v; q2[mt][r] += v * v;
            }
#pragma unroll
    for (int off = 1; off < 16; off <<= 1)
#pragma unroll
        for (int mt = 0; mt < 2; ++mt)
#pragma unroll
            for (int r = 0; r < 4; ++r) {
                s2[mt][r] += __shfl_xor(s2[mt][r], off);
                q2[mt][r] += __shfl_xor(q2[mt][r], off);
            }
    if (l15 == 0)
#pragma unroll
        for (int mt = 0; mt < 2; ++mt)
#pragma unroll
            for (int r = 0; r < 4; ++r) {
                int ol = wm * 32 + mt * 16 + 4 * g + r;
                sa[wn][ol] = s2[mt][r];
                qa[wn][ol] = q2[mt][r];
            }
    __syncthreads();
    if (threadIdx.x < 128) {
        int ol = threadIdx.x & 63, st = threadIdx.x >> 6;
        float v = st ? (qa[0][ol] + qa[1][ol]) : (sa[0][ol] + sa[1][ol]);
        int b = nB >> 14;
        atomicAdd(&accp[(size_t)(b * kC + oB + ol) * 2 + st], v);
    }
}

// ---------------------------------------------------------------------------
// Fused MLP: F = mlp_w1@LB + W2'@OB + bp2 + x(bf16)   (bf16 out [n][192])
// ---------------------------------------------------------------------------
__global__ __launch_bounds__(256) void mgemm_mlp_kernel(
    const unsigned short* __restrict__ A1, const unsigned short* __restrict__ B1,
    const unsigned short* __restrict__ A2, const unsigned short* __restrict__ B2,
    unsigned short* __restrict__ out, const float* __restrict__ bp2,
    const unsigned short* __restrict__ res)
{
    int nB = blockIdx.x * 128, oB = blockIdx.y * 64;
    int w = threadIdx.x >> 6, lane = threadIdx.x & 63;
    int l15 = lane & 15, g = lane >> 4;
    int wm = w & 1, wn = w >> 1;

    f32x4 acc[2][4];
#pragma unroll
    for (int mt = 0; mt < 2; ++mt)
#pragma unroll
        for (int nt = 0; nt < 4; ++nt) acc[mt][nt] = (f32x4){0.f,0.f,0.f,0.f};

    MGEMM_CORE(192, A1 + (size_t)(oB + wm * 32 + l15) * 192 + 8 * g,
                    B1 + (size_t)(nB + wn * 64 + l15) * 192 + 8 * g);
    MGEMM_CORE(512, A2 + (size_t)(oB + wm * 32 + l15) * 512 + 8 * g,
                    B2 + (size_t)(nB + wn * 64 + l15) * 512 + 8 * g);

#pragma unroll
    for (int mt = 0; mt < 2; ++mt)
#pragma unroll
        for (int nt = 0; nt < 4; ++nt) {
            int o = oB + wm * 32 + mt * 16 + 4 * g;
            int n = nB + wn * 64 + nt * 16 + l15;
            f32x4 v = acc[mt][nt];
            v[0] += bp2[o]; v[1] += bp2[o+1]; v[2] += bp2[o+2]; v[3] += bp2[o+3];
            v += ubf4(*(const unsigned long long*)(res + (size_t)n * kC + o));
            *(unsigned long long*)(out + (size_t)n * kC + o) = pk4(v[0], v[1], v[2], v[3]);
        }
}

// ---------------------------------------------------------------------------
// Fused qs-reduce + scores + top-16 (tie -> lower index).
// ---------------------------------------------------------------------------
__global__ void score_topk_kernel(const float* __restrict__ qpart,
                                  const float* __restrict__ ksum_h,
                                  const float* __restrict__ ksum_w,
                                  int* __restrict__ hidx, int* __restrict__ widx)
{
    __shared__ float qsl[2][64];
    __shared__ float hs[128], ws[128];
    int bh = blockIdx.x;
    int tid = threadIdx.x;               // 128
    int hc = tid & 63, grp = tid >> 6;
    {
        const float* qp = qpart + ((size_t)bh * 128 + grp * 64) * 64 + hc;
        float s = 0.f;
        for (int i = 0; i < 64; ++i) s += qp[(size_t)i * 64];
        qsl[grp][hc] = s;
    }
    __syncthreads();
    if (tid < 64) qsl[0][tid] += qsl[1][tid];
    __syncthreads();
    {
        const float* kh = ksum_h + ((size_t)bh * 128 + tid) * 64;
        const float* kw = ksum_w + ((size_t)bh * 128 + tid) * 64;
        float sh = 0.f, sw = 0.f;
        for (int c = 0; c < 64; ++c) {
            float q = qsl[0][c];
            sh += q * kh[c];
            sw += q * kw[c];
        }
        hs[tid] = sh; ws[tid] = sw;
    }
    __syncthreads();
    int sel = tid >> 6;
    const float* sc = sel ? ws : hs;
    int* out = (sel ? widx : hidx) + bh * kP;
    int lane = tid & 63;
    float v0 = sc[lane], v1 = sc[lane + 64];
    int i0 = lane, i1 = lane + 64;
    for (int p = 0; p < kP; ++p) {
        float bv; int bi;
        if (v1 > v0) { bv = v1; bi = i1; } else { bv = v0; bi = i0; }
#pragma unroll
        for (int off = 1; off < 64; off <<= 1) {
            float ov = __shfl_xor(bv, off);
            int   oi = __shfl_xor(bi, off);
            if (ov > bv || (ov == bv && oi < bi)) { bv = ov; bi = oi; }
        }
        if (lane == 0) out[p] = bi;
        if (i0 == bi) v0 = -INFINITY;
        if (i1 == bi) v1 = -INFINITY;
    }
}

// ---------------------------------------------------------------------------
// Gather kf from dense KPb; lazy-project vfT.
// ---------------------------------------------------------------------------
__global__ void gather_kv_kernel(const unsigned short* __restrict__ kpb,
                                 const unsigned short* __restrict__ xnb,
                                 const float* __restrict__ wv,
                                 const int* __restrict__ hidx, const int* __restrict__ widx,
                                 unsigned short* __restrict__ kf, unsigned short* __restrict__ vfT)
{
    int bh = blockIdx.y, p1 = blockIdx.x;
    int b = bh >> 3, nh = bh & 7;
    int hc = threadIdx.x & 63, pg = threadIdx.x >> 6;
    int hrow = hidx[bh * kP + p1];
    int o = nh * kHC + hc;
    const float* wvp = wv + (size_t)o * kC;
    for (int p2 = pg; p2 < kP; p2 += 4) {
        int wcol = widx[bh * kP + p2];
        int n = b * kHW + hrow * kW + wcol;
        int kidx = p1 * kP + p2;
        kf[((size_t)bh * 256 + kidx) * 64 + hc] = kpb[(size_t)n * kHID + nh * kHC + hc];
        const unsigned int* xr = (const unsigned int*)(xnb + (size_t)n * kC);
        float s = 0.f;
        for (int c2 = 0; c2 < kC / 2; ++c2) {
            unsigned int u = xr[c2];
            s += wvp[c2 * 2]     * bf2f((unsigned short)(u & 0xffff));
            s += wvp[c2 * 2 + 1] * bf2f((unsigned short)(u >> 16));
        }
        vfT[((size_t)bh * 64 + hc) * 256 + kidx] = f2bf(s);
    }
}

// ---------------------------------------------------------------------------
// MFMA attention, QBLK=128: kf fragments loaded once, reused for 2 q-subtiles.
// P in LDS stride-256 + XOR swizzle (conflict-free).
// ---------------------------------------------------------------------------
__global__ __launch_bounds__(256) void attn_kernel(
    const unsigned short* __restrict__ qpb, unsigned short* __restrict__ ob,
    const unsigned short* __restrict__ kf, const unsigned short* __restrict__ vfT)
{
    __shared__ unsigned short pls[64 * 256];
    __shared__ float lred[4][4][16];

    int bh = blockIdx.y; int b = bh >> 3, nh = bh & 7;
    int nbase = b * kHW + blockIdx.x * 128;
    int tid = threadIdx.x;
    int w = tid >> 6, lane = tid & 63, l15 = lane & 15, g = lane >> 4;

    const unsigned short* kfb = kf + (size_t)bh * 256 * 64;
    bf16x8 ak[4][2];
#pragma unroll
    for (int mt = 0; mt < 4; ++mt)
#pragma unroll
        for (int kt = 0; kt < 2; ++kt)
            ak[mt][kt] = *(const bf16x8*)&kfb[(size_t)(w * 64 + mt * 16 + l15) * 64 + kt * 32 + 8 * g];

    const unsigned short* vfb = vfT + (size_t)bh * 64 * 256;

#pragma unroll
    for (int sub = 0; sub < 2; ++sub) {
        int n0 = nbase + sub * 64;
        bf16x8 bq[4][2];
#pragma unroll
        for (int nt = 0; nt < 4; ++nt)
#pragma unroll
            for (int kt = 0; kt < 2; ++kt)
                bq[nt][kt] = *(const bf16x8*)(qpb + (size_t)(n0 + nt * 16 + l15) * kHID
                                              + nh * kHC + kt * 32 + 8 * g);

        f32x4 acc[4][4];
#pragma unroll
        for (int mt = 0; mt < 4; ++mt)
#pragma unroll
            for (int nt = 0; nt < 4; ++nt) acc[mt][nt] = (f32x4){0.f,0.f,0.f,0.f};

#pragma unroll
        for (int kt = 0; kt < 2; ++kt)
#pragma unroll
            for (int mt = 0; mt < 4; ++mt)
#pragma unroll
                for (int nt = 0; nt < 4; ++nt)
                    acc[mt][nt] = __builtin_amdgcn_mfma_f32_16x16x32_bf16(
                        ak[mt][kt], bq[nt][kt], acc[mt][nt], 0, 0, 0);

        if (sub) __syncthreads();   // protect pls/lred from previous subtile readers

        float lpart[4] = {0.f, 0.f, 0.f, 0.f};
#pragma unroll
        for (int mt = 0; mt < 4; ++mt)
#pragma unroll
            for (int nt = 0; nt < 4; ++nt) {
                float e0 = __expf(acc[mt][nt][0]);
                float e1 = __expf(acc[mt][nt][1]);
                float e2 = __expf(acc[mt][nt][2]);
                float e3 = __expf(acc[mt][nt][3]);
                lpart[nt] += (e0 + e1) + (e2 + e3);
                int qq = nt * 16 + l15;
                int k0 = w * 64 + mt * 16 + 4 * g;
                int kx = k0 ^ ((qq & 7) << 3);
                *(unsigned long long*)&pls[qq * 256 + kx] = pk4(e0, e1, e2, e3);
            }
#pragma unroll
        for (int nt = 0; nt < 4; ++nt) {
            lpart[nt] += __shfl_xor(lpart[nt], 16);
            lpart[nt] += __shfl_xor(lpart[nt], 32);
        }
        if (g == 0)
#pragma unroll
            for (int nt = 0; nt < 4; ++nt) lred[w][nt][l15] = lpart[nt];
        __syncthreads();

        f32x4 oacc[4];
#pragma unroll
        for (int nt = 0; nt < 4; ++nt) oacc[nt] = (f32x4){0.f,0.f,0.f,0.f};

#pragma unroll
        for (int ks = 0; ks < 8; ++ks) {
            bf16x8 av = *(const bf16x8*)&vfb[(size_t)(w * 16 + l15) * 256 + ks * 32 + 8 * g];
#pragma unroll
            for (int nt = 0; nt < 4; ++nt) {
                int qq = nt * 16 + l15;
                int kx = (ks * 32 + 8 * g) ^ ((qq & 7) << 3);
                bf16x8 bp = *(const bf16x8*)&pls[qq * 256 + kx];
                oacc[nt] = __builtin_amdgcn_mfma_f32_16x16x32_bf16(av, bp, oacc[nt], 0, 0, 0);
            }
        }

#pragma unroll
        for (int nt = 0; nt < 4; ++nt) {
            float l = lred[0][nt][l15] + lred[1][nt][l15] + lred[2][nt][l15] + lred[3][nt][l15];
            float inv = 1.0f / l;
            int qq = nt * 16 + l15;
            int hc0 = w * 16 + 4 * g;
            *(unsigned long long*)(ob + (size_t)(n0 + qq) * kHID + nh * kHC + hc0) =
                pk4(oacc[nt][0] * inv, oacc[nt][1] * inv, oacc[nt][2] * inv, oacc[nt][3] * inv);
        }
    }
}

// ---------------------------------------------------------------------------
// Instance-norm stats (bf16 input) via per-chunk atomics.
// ---------------------------------------------------------------------------
__global__ void istats_bf16_kernel(const unsigned short* __restrict__ in, float* __restrict__ acc)
{
    int n0 = blockIdx.x * 64;
    int b = n0 >> 14;
    int c = threadIdx.x;
    float s = 0.f, ss = 0.f;
    for (int p = 0; p < 64; ++p) {
        float v = bf2f(in[(size_t)(n0 + p) * kC + c]);
        s += v; ss += v * v;
    }
    atomicAdd(&acc[(size_t)(b * kC + c) * 2],     s);
    atomicAdd(&acc[(size_t)(b * kC + c) * 2 + 1], ss);
}

__device__ inline void inorm_ms(const float* acc, int b, int c, float& m, float& rs)
{
    float s  = acc[(size_t)(b * kC + c) * 2];
    float ss = acc[(size_t)(b * kC + c) * 2 + 1];
    m = s * (1.0f / kHW);
    float var = ss * (1.0f / kHW) - m * m;
    rs = rsqrtf(var + kEPS);
}

// ---------------------------------------------------------------------------
// Fused res-dwconv: R = res_b + dwconv(gelu(inorm_acc0(T1))).
// ---------------------------------------------------------------------------
__global__ void dwconv_gelu_kernel(const unsigned short* __restrict__ t1,
                                   const float* __restrict__ acc0,
                                   unsigned short* __restrict__ rout,
                                   const float* __restrict__ wt, const float* __restrict__ bias)
{
    int idx = blockIdx.x * 256 + threadIdx.x;      // kN*48
    int n = idx / 48;
    int c0 = (idx - n * 48) * 4;
    int hw = n & (kHW - 1);
    int b = n >> 14;
    int h = hw >> 7, ww = hw & 127;
    float m[4], rs[4];
#pragma unroll
    for (int j = 0; j < 4; ++j) inorm_ms(acc0, b, c0 + j, m[j], rs[j]);
    f32x4 s = *(const f32x4*)(bias + c0);
#pragma unroll
    for (int dy = -1; dy <= 1; ++dy) {
        int hh = h + dy;
        if (hh < 0 || hh >= kH) continue;
#pragma unroll
        for (int dx = -1; dx <= 1; ++dx) {
            int wx = ww + dx;
            if (wx < 0 || wx >= kW) continue;
            f32x4 v = ubf4(*(const unsigned long long*)(t1 + (size_t)(n + dy * kW + dx) * kC + c0));
            int t = (dy + 1) * 3 + (dx + 1);
#pragma unroll
            for (int j = 0; j < 4; ++j)
                s[j] += gelu_f((v[j] - m[j]) * rs[j]) * wt[(c0 + j) * 9 + t];
        }
    }
    *(unsigned long long*)(rout + (size_t)n * kC + c0) = pk4(s[0], s[1], s[2], s[3]);
}

// ---------------------------------------------------------------------------
// Y3 = gelu(inorm_acc1(R)) + gelu(inorm_acc0(T1))
// ---------------------------------------------------------------------------
__global__ void apply_res_kernel(const unsigned short* __restrict__ r,
                                 const unsigned short* __restrict__ t1,
                                 const float* __restrict__ acc1, const float* __restrict__ acc0,
                                 unsigned short* __restrict__ out)
{
    int idx = blockIdx.x * 256 + threadIdx.x;      // kN*48
    int n = idx / 48;
    int c0 = (idx - n * 48) * 4;
    int b = n >> 14;
    f32x4 vr = ubf4(*(const unsigned long long*)(r  + (size_t)n * kC + c0));
    f32x4 vt = ubf4(*(const unsigned long long*)(t1 + (size_t)n * kC + c0));
    f32x4 o;
#pragma unroll
    for (int j = 0; j < 4; ++j) {
        float m1, rs1, m0, rs0;
        inorm_ms(acc1, b, c0 + j, m1, rs1);
        inorm_ms(acc0, b, c0 + j, m0, rs0);
        o[j] = gelu_f((vr[j] - m1) * rs1) + gelu_f((vt[j] - m0) * rs0);
    }
    *(unsigned long long*)(out + (size_t)n * kC + c0) = pk4(o[0], o[1], o[2], o[3]);
}

// ---------------------------------------------------------------------------
// Final inorm via LDS transpose: bf16 pixel-major in -> NCHW fp32 d_out.
// ---------------------------------------------------------------------------
__global__ __launch_bounds__(256) void final_kernel(const unsigned short* __restrict__ in,
                                                    const float* __restrict__ acc,
                                                    float* __restrict__ out)
{
    __shared__ unsigned short tile[192][68];
    int n0 = blockIdx.x * 64;
    int b = n0 >> 14;
    int hw0 = n0 & (kHW - 1);
    int tid = threadIdx.x;
    for (int i = tid; i < 64 * 48; i += 256) {
        int p = i / 48, cq = i - p * 48;
        unsigned long long u = *(const unsigned long long*)(in + (size_t)(n0 + p) * kC + cq * 4);
        tile[cq * 4 + 0][p] = (unsigned short)u;
        tile[cq * 4 + 1][p] = (unsigned short)(u >> 16);
        tile[cq * 4 + 2][p] = (unsigned short)(u >> 32);
        tile[cq * 4 + 3][p] = (unsigned short)(u >> 48);
    }
    __syncthreads();
    for (int i = tid; i < 192 * 16; i += 256) {
        int c = i >> 4, grp = i & 15;
        float m, rs;
        inorm_ms(acc, b, c, m, rs);
        f32x4 o;
#pragma unroll
        for (int j = 0; j < 4; ++j)
            o[j] = (bf2f(tile[c][grp * 4 + j]) - m) * rs;
        *(f32x4*)(out + (size_t)(b * kC + c) * kHW + hw0 + grp * 4) = o;
    }
}

// ---------------------------------------------------------------------------
extern "C" void kernel_launch(void* const* d_in, const int* in_sizes, int n_in,
                              void* d_out, int out_size, void* d_ws, size_t ws_size,
                              hipStream_t stream)
{
    const float* x     = (const float*)d_in[0];
    const float* ln1_g = (const float*)d_in[1];
    const float* ln1_b = (const float*)d_in[2];
    const float* wq    = (const float*)d_in[3];
    const float* wk    = (const float*)d_in[4];
    const float* wv    = (const float*)d_in[5];
    const float* wo    = (const float*)d_in[6];
    const float* bo    = (const float*)d_in[7];
    const float* dw_w  = (const float*)d_in[8];
    const float* dw_b  = (const float*)d_in[9];
    const float* mlp_w = (const float*)d_in[10];
    const float* mlp_b = (const float*)d_in[11];
    const float* ln2_g = (const float*)d_in[12];
    const float* ln2_b = (const float*)d_in[13];
    const float* c1_w  = (const float*)d_in[14];
    const float* c1_b  = (const float*)d_in[15];
    const float* res_w = (const float*)d_in[16];
    const float* res_b = (const float*)d_in[17];
    const float* c2_w  = (const float*)d_in[18];
    const float* c2_b  = (const float*)d_in[19];

    char* base = (char*)d_ws;
    unsigned short* XPb = (unsigned short*)(base);               // bf16 [n][192] raw x
    unsigned short* XNb = (unsigned short*)(base + 25165824);    // bf16 [n][192] xn / Y1
    unsigned short* QPb = (unsigned short*)(base + 37748736);    // bf16 [n][512]; later F / T2
    unsigned short* F   = QPb;
    unsigned short* T2  = QPb;
    unsigned short* KPb = (unsigned short*)(base + 71303168);    // bf16 [n][512]; OB/R alias
    unsigned short* OB  = KPb;
    unsigned short* R   = KPb;
    unsigned short* LB  = (unsigned short*)(base + 104857600);   // bf16 [n][192] local; later Y3
    unsigned short* Y3  = LB;
    unsigned short* T1  = (unsigned short*)(base + 117440512);   // bf16 [n][192]
    char* sm = base + 130023424;
    float* qpart  = (float*)(sm);                 sm += 524288;   // [16][128][64]
    float* ksum_h = (float*)(sm);                 sm += 524288;
    float* ksum_w = (float*)(sm);                 sm += 524288;
    float* acc0   = (float*)(sm);                 sm += 3072;     // zero block (2304 floats)
    float* acc1   = (float*)(sm);                 sm += 3072;
    float* acc2   = (float*)(sm);                 sm += 3072;
    unsigned short* kf   = (unsigned short*)(sm); sm += 524288;
    unsigned short* vfT  = (unsigned short*)(sm); sm += 524288;
    unsigned short* wqb  = (unsigned short*)(sm); sm += 196608;
    unsigned short* wkb  = (unsigned short*)(sm); sm += 196608;
    unsigned short* mlpb1= (unsigned short*)(sm); sm += 73728;
    unsigned short* c1b  = (unsigned short*)(sm); sm += 73728;
    unsigned short* c2b  = (unsigned short*)(sm); sm += 73728;
    unsigned short* w2pb = (unsigned short*)(sm); sm += 196608;
    float* bp2 = (float*)(sm);                    sm += 1024;
    int* hidx = (int*)(sm);                       sm += 1024;
    int* widx = (int*)(sm);

    // 1. prep: zero acc0..2 + weight cvts + fused W2'
    prep_kernel<<<1593, 256, 0, stream>>>(acc0, wq, wk, mlp_w, c1_w, c2_w,
                                          wo, mlp_b, bo,
                                          wqb, wkb, mlpb1, c1b, c2b, w2pb, bp2);
    // 2. transpose + ln1
    txln_kernel<<<dim3(kHW / 64, kB), 256, 0, stream>>>(x, XPb, XNb, ln1_g, ln1_b);
    // 3. fused: Q-gemm | K-gemm (dense + ksum_h) | local dwconv
    branch_kernel<<<10240, 256, 0, stream>>>(wqb, wkb, XNb, XPb, QPb, KPb,
                                             qpart, ksum_h, LB, dw_w, dw_b);
    // 4. ksum_w
    sum_h_kernel<<<dim3(kW, 16), 256, 0, stream>>>(KPb, ksum_w);
    // 5. scores + top-16
    score_topk_kernel<<<16, 128, 0, stream>>>(qpart, ksum_h, ksum_w, hidx, widx);
    // 6. gather: kf copy + lazy vfT
    gather_kv_kernel<<<dim3(kP, 16), 256, 0, stream>>>(KPb, XNb, wv, hidx, widx, kf, vfT);
    // 7. attention (QBLK=128; writes OB over KPb, kf/vfT already extracted)
    attn_kernel<<<dim3(kHW / 128, 16), 256, 0, stream>>>(QPb, OB, kf, vfT);
    // 8. fused mlp (wo folded) + residual
    mgemm_mlp_kernel<<<dim3(kN / 128, kC / 64), 256, 0, stream>>>(mlpb1, LB, w2pb, OB, F, bp2, XPb);
    // 9. ln2
    ln_pm_bf16_kernel<<<(kN * 4) / 256, 256, 0, stream>>>(F, XNb, ln2_g, ln2_b);
    // 10. c1 GEMM + istats(acc0)
    mgemm_is_kernel<<<dim3(kN / 128, kC / 64), 256, 0, stream>>>(c1b, XNb, T1, c1_b, acc0);
    // 11. res dwconv with inline gelu(inorm(T1))  -> R
    dwconv_gelu_kernel<<<(kN * 48) / 256, 256, 0, stream>>>(T1, acc0, R, res_w, res_b);
    // 12. istats(R) -> acc1
    istats_bf16_kernel<<<kN / 64, 192, 0, stream>>>(R, acc1);
    // 13. Y3 = gelu(inorm(R)) + gelu(inorm(T1))
    apply_res_kernel<<<(kN * 48) / 256, 256, 0, stream>>>(R, T1, acc1, acc0, Y3);
    // 14. c2 GEMM + istats(acc2)
    mgemm_is_kernel<<<dim3(kN / 128, kC / 64), 256, 0, stream>>>(c2b, Y3, T2, c2_b, acc2);
    // 15. final inorm -> d_out
    final_kernel<<<kN / 64, 256, 0, stream>>>(T2, acc2, (float*)d_out);
}

// Round 11
// 467.043 us; speedup vs baseline: 1.4909x; 1.0382x over previous
//
#include <hip/hip_runtime.h>
#include <math.h>

constexpr int kC   = 192;
constexpr int kNH  = 8;
constexpr int kHC  = 64;
constexpr int kHID = 512;
constexpr int kP   = 16;
constexpr int kB   = 2;
constexpr int kH   = 128;
constexpr int kW   = 128;
constexpr int kHW  = kH * kW;      // 16384
constexpr int kN   = kB * kHW;     // 32768
constexpr float kEPS = 1e-5f;

typedef __attribute__((ext_vector_type(8))) short bf16x8;
typedef __attribute__((ext_vector_type(4))) float f32x4;

__device__ inline unsigned short f2bf(float f) {
    unsigned int u = __builtin_bit_cast(unsigned int, f);
    unsigned int r = (u + 0x7FFFu + ((u >> 16) & 1u)) >> 16;   // RNE
    return (unsigned short)r;
}
__device__ inline float bf2f(unsigned short u) {
    return __builtin_bit_cast(float, (unsigned int)u << 16);
}
__device__ inline unsigned int cvtpk(float lo, float hi) {
    unsigned int r;
    asm("v_cvt_pk_bf16_f32 %0, %1, %2" : "=v"(r) : "v"(lo), "v"(hi));
    return r;
}
__device__ inline unsigned long long pk4(float a, float b, float c, float d) {
    return (unsigned long long)cvtpk(a, b) | ((unsigned long long)cvtpk(c, d) << 32);
}
__device__ inline f32x4 ubf4(unsigned long long u) {
    f32x4 r;
    r[0] = bf2f((unsigned short)u);
    r[1] = bf2f((unsigned short)(u >> 16));
    r[2] = bf2f((unsigned short)(u >> 32));
    r[3] = bf2f((unsigned short)(u >> 48));
    return r;
}
__device__ inline float gelu_f(float x) {
    return 0.5f * x * (1.0f + erff(x * 0.70710678118654752f));
}

// ---------------------------------------------------------------------------
// Prep: zero acc0..2 + bf16 weight cvts + fused W2' weight.
// ---------------------------------------------------------------------------
__global__ void prep_kernel(float* __restrict__ zbase,
                            const float* wq, const float* wk, const float* wm,
                            const float* c1, const float* c2,
                            const float* wo, const float* mlp_b, const float* bo,
                            unsigned short* wqb, unsigned short* wkb,
                            unsigned short* mlpb1, unsigned short* c1b, unsigned short* c2b,
                            unsigned short* w2pb, float* bp2)
{
    int i = blockIdx.x * 256 + threadIdx.x;
    if (i < 2304) { zbase[i] = 0.f; return; }            // acc0..2
    i -= 2304;
    if (i < 98304) { wqb[i] = f2bf(wq[i]); return; }
    i -= 98304;
    if (i < 98304) { wkb[i] = f2bf(wk[i]); return; }
    i -= 98304;
    if (i < 36864) { int o = i / 192, k = i - o * 192; mlpb1[i] = f2bf(wm[o * 384 + k]); return; }
    i -= 36864;
    if (i < 36864) { c1b[i] = f2bf(c1[i]); return; }
    i -= 36864;
    if (i < 36864) { c2b[i] = f2bf(c2[i]); return; }
    i -= 36864;
    if (i < 98304) {
        int o = i >> 9, j = i & 511;
        const float* a = wm + o * 384 + 192;
        float s = 0.f;
        for (int c = 0; c < 192; ++c) s += a[c] * wo[c * 512 + j];
        w2pb[o * 512 + j] = f2bf(s);
        if (j == 0) {
            float t = mlp_b[o];
            for (int c = 0; c < 192; ++c) t += a[c] * bo[c];
            bp2[o] = t;
        }
    }
}

// ---------------------------------------------------------------------------
// Fused transpose + ln1: x NCHW fp32 -> XPb raw bf16 [n][192] + XNb bf16.
// ---------------------------------------------------------------------------
__global__ __launch_bounds__(256) void txln_kernel(const float* __restrict__ x,
                                                   unsigned short* __restrict__ xpb,
                                                   unsigned short* __restrict__ xnb,
                                                   const float* __restrict__ g,
                                                   const float* __restrict__ bb)
{
    __shared__ float tile[192][65];
    __shared__ float red[2][4][64];
    __shared__ float pms[64], prs[64];
    int hw0 = blockIdx.x * 64;
    int b   = blockIdx.y;
    int tid = threadIdx.x;
    for (int i = tid; i < 192 * 64; i += 256) {
        int c = i >> 6, p = i & 63;
        tile[c][p] = x[(size_t)(b * kC + c) * kHW + hw0 + p];
    }
    __syncthreads();
    {
        int p = tid & 63, qt = tid >> 6;
        float s = 0.f, ss = 0.f;
        for (int c = qt * 48; c < qt * 48 + 48; ++c) {
            float v = tile[c][p]; s += v; ss += v * v;
        }
        red[0][qt][p] = s; red[1][qt][p] = ss;
    }
    __syncthreads();
    if (tid < 64) {
        float s  = red[0][0][tid] + red[0][1][tid] + red[0][2][tid] + red[0][3][tid];
        float ss = red[1][0][tid] + red[1][1][tid] + red[1][2][tid] + red[1][3][tid];
        float m = s * (1.0f / kC);
        float var = ss * (1.0f / kC) - m * m;
        pms[tid] = m;
        prs[tid] = rsqrtf(var + kEPS);
    }
    __syncthreads();
    for (int i = tid; i < 64 * 192; i += 256) {
        int p = i / 192, c = i - p * 192;
        float raw = tile[c][p];
        size_t oi = (size_t)(b * kHW + hw0 + p) * kC + c;
        xpb[oi] = f2bf(raw);
        xnb[oi] = f2bf((raw - pms[p]) * prs[p] * g[c] + bb[c]);
    }
}

// ---------------------------------------------------------------------------
// LayerNorm (ln2), bf16 -> bf16, 4 threads per pixel.
// ---------------------------------------------------------------------------
__global__ void ln_pm_bf16_kernel(const unsigned short* __restrict__ in,
                                  unsigned short* __restrict__ out,
                                  const float* __restrict__ g, const float* __restrict__ bb)
{
    int t = blockIdx.x * 256 + threadIdx.x;     // kN*4
    int n = t >> 2, q = t & 3;
    const unsigned long long* ip = (const unsigned long long*)(in + (size_t)n * kC) + q * 12;
    f32x4 v[12];
    float s = 0.f, ss = 0.f;
#pragma unroll
    for (int r = 0; r < 12; ++r) {
        v[r] = ubf4(ip[r]);
        s  += (v[r][0] + v[r][1]) + (v[r][2] + v[r][3]);
        ss += (v[r][0]*v[r][0] + v[r][1]*v[r][1]) + (v[r][2]*v[r][2] + v[r][3]*v[r][3]);
    }
    s  += __shfl_xor(s, 1);  s  += __shfl_xor(s, 2);
    ss += __shfl_xor(ss, 1); ss += __shfl_xor(ss, 2);
    float m  = s * (1.0f / kC);
    float var = ss * (1.0f / kC) - m * m;
    float rs = rsqrtf(var + kEPS);
    unsigned long long* op = (unsigned long long*)(out + (size_t)n * kC) + q * 12;
#pragma unroll
    for (int r = 0; r < 12; ++r) {
        f32x4 gg = *(const f32x4*)(g + q * 48 + r * 4);
        f32x4 bv = *(const f32x4*)(bb + q * 48 + r * 4);
        op[r] = pk4((v[r][0]-m)*rs*gg[0] + bv[0], (v[r][1]-m)*rs*gg[1] + bv[1],
                    (v[r][2]-m)*rs*gg[2] + bv[2], (v[r][3]-m)*rs*gg[3] + bv[3]);
    }
}

#define MGEMM_CORE(KVAL, APTR, BPTR)                                              \
    {                                                                             \
        const unsigned short* Ap = APTR;                                          \
        const unsigned short* Bp = BPTR;                                          \
        _Pragma("unroll 2")                                                       \
        for (int k = 0; k < KVAL; k += 32) {                                      \
            bf16x8 a0 = *(const bf16x8*)(Ap + k);                                 \
            bf16x8 a1 = *(const bf16x8*)(Ap + (size_t)16 * KVAL + k);             \
            bf16x8 b0 = *(const bf16x8*)(Bp + k);                                 \
            bf16x8 b1 = *(const bf16x8*)(Bp + (size_t)16 * KVAL + k);             \
            bf16x8 b2 = *(const bf16x8*)(Bp + (size_t)32 * KVAL + k);             \
            bf16x8 b3 = *(const bf16x8*)(Bp + (size_t)48 * KVAL + k);             \
            acc[0][0] = __builtin_amdgcn_mfma_f32_16x16x32_bf16(a0, b0, acc[0][0], 0, 0, 0); \
            acc[0][1] = __builtin_amdgcn_mfma_f32_16x16x32_bf16(a0, b1, acc[0][1], 0, 0, 0); \
            acc[0][2] = __builtin_amdgcn_mfma_f32_16x16x32_bf16(a0, b2, acc[0][2], 0, 0, 0); \
            acc[0][3] = __builtin_amdgcn_mfma_f32_16x16x32_bf16(a0, b3, acc[0][3], 0, 0, 0); \
            acc[1][0] = __builtin_amdgcn_mfma_f32_16x16x32_bf16(a1, b0, acc[1][0], 0, 0, 0); \
            acc[1][1] = __builtin_amdgcn_mfma_f32_16x16x32_bf16(a1, b1, acc[1][1], 0, 0, 0); \
            acc[1][2] = __builtin_amdgcn_mfma_f32_16x16x32_bf16(a1, b2, acc[1][2], 0, 0, 0); \
            acc[1][3] = __builtin_amdgcn_mfma_f32_16x16x32_bf16(a1, b3, acc[1][3], 0, 0, 0); \
        }                                                                         \
    }

// ---------------------------------------------------------------------------
// q/k projection GEMM, BM=128 (2 heads), 4 waves each owning one full
// (head x 64n) tile. Per-head L2 norm is intra-wave (no LDS). Fused row-sum.
// Grid: (256 nblk, 4 headpair, 2 q/k).
// ---------------------------------------------------------------------------
__global__ __launch_bounds__(256) void qk_proj_kernel(
    const unsigned short* __restrict__ wqb, const unsigned short* __restrict__ wkb,
    const unsigned short* __restrict__ xnb,
    unsigned short* __restrict__ qpb, unsigned short* __restrict__ kpb,
    float* __restrict__ qpart, float* __restrict__ ksum_h)
{
    __shared__ float rbuf[2][2][4][4][4];   // [wm][wn][g][mt][r]
    int nB = blockIdx.x * 128;
    int hp = blockIdx.y;
    const unsigned short* A = blockIdx.z ? wkb : wqb;
    unsigned short* out = blockIdx.z ? kpb : qpb;
    float* red_out = blockIdx.z ? ksum_h : qpart;

    int w = threadIdx.x >> 6, lane = threadIdx.x & 63;
    int l15 = lane & 15, g = lane >> 4;
    int wm = w & 1, wn = w >> 1;            // wm = head within pair, wn = n-half
    int oB = hp * 128;

    const unsigned short* Ap = A + (size_t)(oB + wm * 64 + l15) * 192 + 8 * g;
    const unsigned short* Bp = xnb + (size_t)(nB + wn * 64 + l15) * 192 + 8 * g;

    f32x4 acc[4][4];
#pragma unroll
    for (int mt = 0; mt < 4; ++mt)
#pragma unroll
        for (int nt = 0; nt < 4; ++nt) acc[mt][nt] = (f32x4){0.f,0.f,0.f,0.f};

#pragma unroll 2
    for (int k = 0; k < 192; k += 32) {
        bf16x8 a[4], bb[4];
#pragma unroll
        for (int mt = 0; mt < 4; ++mt) a[mt] = *(const bf16x8*)(Ap + (size_t)mt * 16 * 192 + k);
#pragma unroll
        for (int nt = 0; nt < 4; ++nt) bb[nt] = *(const bf16x8*)(Bp + (size_t)nt * 16 * 192 + k);
#pragma unroll
        for (int mt = 0; mt < 4; ++mt)
#pragma unroll
            for (int nt = 0; nt < 4; ++nt)
                acc[mt][nt] = __builtin_amdgcn_mfma_f32_16x16x32_bf16(a[mt], bb[nt], acc[mt][nt], 0, 0, 0);
    }

    // per-pixel L2 norm over this wave's head (all 64 o live in-wave)
    float sc[4];
#pragma unroll
    for (int nt = 0; nt < 4; ++nt) {
        float s = 0.f;
#pragma unroll
        for (int mt = 0; mt < 4; ++mt) {
            f32x4 a = acc[mt][nt];
            s += (a[0]*a[0] + a[1]*a[1]) + (a[2]*a[2] + a[3]*a[3]);
        }
        s += __shfl_xor(s, 16);
        s += __shfl_xor(s, 32);
        sc[nt] = 1.0f / fmaxf(sqrtf(s), 1e-12f);
    }

    // normalized bf16 stores
#pragma unroll
    for (int nt = 0; nt < 4; ++nt) {
        int n = nB + wn * 64 + nt * 16 + l15;
#pragma unroll
        for (int mt = 0; mt < 4; ++mt) {
            int o = oB + wm * 64 + mt * 16 + 4 * g;
            f32x4 v = acc[mt][nt];
            *(unsigned long long*)(out + (size_t)n * kHID + o) =
                pk4(v[0]*sc[nt], v[1]*sc[nt], v[2]*sc[nt], v[3]*sc[nt]);
        }
    }

    // fused row-sum of normalized values (per head)
    float sred[4][4] = {};
#pragma unroll
    for (int nt = 0; nt < 4; ++nt)
#pragma unroll
        for (int mt = 0; mt < 4; ++mt) {
            f32x4 a = acc[mt][nt];
            sred[mt][0] += a[0] * sc[nt];
            sred[mt][1] += a[1] * sc[nt];
            sred[mt][2] += a[2] * sc[nt];
            sred[mt][3] += a[3] * sc[nt];
        }
#pragma unroll
    for (int off = 1; off < 16; off <<= 1)
#pragma unroll
        for (int mt = 0; mt < 4; ++mt)
#pragma unroll
            for (int r = 0; r < 4; ++r)
                sred[mt][r] += __shfl_xor(sred[mt][r], off);
    if (l15 == 0)
#pragma unroll
        for (int mt = 0; mt < 4; ++mt)
#pragma unroll
            for (int r = 0; r < 4; ++r)
                rbuf[wm][wn][g][mt][r] = sred[mt][r];
    __syncthreads();
    if (threadIdx.x < 128) {
        int wm2 = threadIdx.x >> 6;
        int o = threadIdx.x & 63;
        int mt2 = o >> 4, g2 = (o >> 2) & 3, r2 = o & 3;
        float v = rbuf[wm2][0][g2][mt2][r2] + rbuf[wm2][1][g2][mt2][r2];
        int row = (nB & (kHW - 1)) >> 7;
        int b = nB >> 14;
        int bh = b * 8 + hp * 2 + wm2;
        red_out[((size_t)(bh * 128 + row)) * 64 + o] = v;
    }
}

// ---------------------------------------------------------------------------
// Depthwise 3x3 SAME conv, pixel-major bf16 in -> bf16 out [n][192].
// ---------------------------------------------------------------------------
__global__ void dwconv_pm_kernel(const unsigned short* __restrict__ in,
                                 unsigned short* __restrict__ out,
                                 const float* __restrict__ wt, const float* __restrict__ bias)
{
    int idx = blockIdx.x * 256 + threadIdx.x;      // kN*48
    int n = idx / 48;
    int c0 = (idx - n * 48) * 4;
    int hw = n & (kHW - 1);
    int h = hw >> 7, ww = hw & 127;
    f32x4 s = *(const f32x4*)(bias + c0);
#pragma unroll
    for (int dy = -1; dy <= 1; ++dy) {
        int hh = h + dy;
        if (hh < 0 || hh >= kH) continue;
#pragma unroll
        for (int dx = -1; dx <= 1; ++dx) {
            int wx = ww + dx;
            if (wx < 0 || wx >= kW) continue;
            f32x4 v = ubf4(*(const unsigned long long*)(in + (size_t)(n + dy * kW + dx) * kC + c0));
            int t = (dy + 1) * 3 + (dx + 1);
            s[0] += v[0] * wt[(c0 + 0) * 9 + t];
            s[1] += v[1] * wt[(c0 + 1) * 9 + t];
            s[2] += v[2] * wt[(c0 + 2) * 9 + t];
            s[3] += v[3] * wt[(c0 + 3) * 9 + t];
        }
    }
    *(unsigned long long*)(out + (size_t)n * kC + c0) = pk4(s[0], s[1], s[2], s[3]);
}

// ksum_w[bh][w][hc] = sum_h k.  256 threads: 4 h-segments of 32 + LDS reduce.
__global__ void sum_h_kernel(const unsigned short* __restrict__ buf, float* __restrict__ out)
{
    __shared__ float red[4][64];
    int w = blockIdx.x, bh = blockIdx.y;
    int hc = threadIdx.x & 63, seg = threadIdx.x >> 6;
    int b = bh >> 3, nh = bh & 7;
    const unsigned short* p = buf + (size_t)(b * kHW + seg * 32 * kW + w) * kHID + nh * kHC + hc;
    float s = 0.f;
    for (int h = 0; h < 32; ++h) s += bf2f(p[(size_t)h * kW * kHID]);
    red[seg][hc] = s;
    __syncthreads();
    if (threadIdx.x < 64)
        out[((size_t)bh * kW + w) * kHC + threadIdx.x] =
            red[0][threadIdx.x] + red[1][threadIdx.x] + red[2][threadIdx.x] + red[3][threadIdx.x];
}

// ---------------------------------------------------------------------------
// c1/c2 GEMM: bf16 out [n][192] + bias + fused instance-norm partial stats.
// ---------------------------------------------------------------------------
__global__ __launch_bounds__(256) void mgemm_is_kernel(
    const unsigned short* __restrict__ A, const unsigned short* __restrict__ B,
    unsigned short* __restrict__ out, const float* __restrict__ bias,
    float* __restrict__ accp)
{
    __shared__ float sa[2][64], qa[2][64];
    int nB = blockIdx.x * 128, oB = blockIdx.y * 64;
    int w = threadIdx.x >> 6, lane = threadIdx.x & 63;
    int l15 = lane & 15, g = lane >> 4;
    int wm = w & 1, wn = w >> 1;

    f32x4 acc[2][4];
#pragma unroll
    for (int mt = 0; mt < 2; ++mt)
#pragma unroll
        for (int nt = 0; nt < 4; ++nt) acc[mt][nt] = (f32x4){0.f,0.f,0.f,0.f};

    MGEMM_CORE(192, A + (size_t)(oB + wm * 32 + l15) * 192 + 8 * g,
                    B + (size_t)(nB + wn * 64 + l15) * 192 + 8 * g);

    f32x4 vv[2][4];
#pragma unroll
    for (int mt = 0; mt < 2; ++mt)
#pragma unroll
        for (int nt = 0; nt < 4; ++nt) {
            int o = oB + wm * 32 + mt * 16 + 4 * g;
            int n = nB + wn * 64 + nt * 16 + l15;
            f32x4 v = acc[mt][nt] + *(const f32x4*)(bias + o);
            vv[mt][nt] = v;
            *(unsigned long long*)(out + (size_t)n * kC + o) = pk4(v[0], v[1], v[2], v[3]);
        }
    float s2[2][4] = {}, q2[2][4] = {};
#pragma unroll
    for (int mt = 0; mt < 2; ++mt)
#pragma unroll
        for (int nt = 0; nt < 4; ++nt)
#pragma unroll
            for (int r = 0; r < 4; ++r) {
                float v = vv[mt][nt][r];
                s2[mt][r] += v; q2[mt][r] += v * v;
            }
#pragma unroll
    for (int off = 1; off < 16; off <<= 1)
#pragma unroll
        for (int mt = 0; mt < 2; ++mt)
#pragma unroll
            for (int r = 0; r < 4; ++r) {
                s2[mt][r] += __shfl_xor(s2[mt][r], off);
                q2[mt][r] += __shfl_xor(q2[mt][r], off);
            }
    if (l15 == 0)
#pragma unroll
        for (int mt = 0; mt < 2; ++mt)
#pragma unroll
            for (int r = 0; r < 4; ++r) {
                int ol = wm * 32 + mt * 16 + 4 * g + r;
                sa[wn][ol] = s2[mt][r];
                qa[wn][ol] = q2[mt][r];
            }
    __syncthreads();
    if (threadIdx.x < 128) {
        int ol = threadIdx.x & 63, st = threadIdx.x >> 6;
        float v = st ? (qa[0][ol] + qa[1][ol]) : (sa[0][ol] + sa[1][ol]);
        int b = nB >> 14;
        atomicAdd(&accp[(size_t)(b * kC + oB + ol) * 2 + st], v);
    }
}

// ---------------------------------------------------------------------------
// Fused MLP: F = mlp_w1@LB + W2'@OB + bp2 + x(bf16)   (bf16 out [n][192])
// ---------------------------------------------------------------------------
__global__ __launch_bounds__(256) void mgemm_mlp_kernel(
    const unsigned short* __restrict__ A1, const unsigned short* __restrict__ B1,
    const unsigned short* __restrict__ A2, const unsigned short* __restrict__ B2,
    unsigned short* __restrict__ out, const float* __restrict__ bp2,
    const unsigned short* __restrict__ res)
{
    int nB = blockIdx.x * 128, oB = blockIdx.y * 64;
    int w = threadIdx.x >> 6, lane = threadIdx.x & 63;
    int l15 = lane & 15, g = lane >> 4;
    int wm = w & 1, wn = w >> 1;

    f32x4 acc[2][4];
#pragma unroll
    for (int mt = 0; mt < 2; ++mt)
#pragma unroll
        for (int nt = 0; nt < 4; ++nt) acc[mt][nt] = (f32x4){0.f,0.f,0.f,0.f};

    MGEMM_CORE(192, A1 + (size_t)(oB + wm * 32 + l15) * 192 + 8 * g,
                    B1 + (size_t)(nB + wn * 64 + l15) * 192 + 8 * g);
    MGEMM_CORE(512, A2 + (size_t)(oB + wm * 32 + l15) * 512 + 8 * g,
                    B2 + (size_t)(nB + wn * 64 + l15) * 512 + 8 * g);

#pragma unroll
    for (int mt = 0; mt < 2; ++mt)
#pragma unroll
        for (int nt = 0; nt < 4; ++nt) {
            int o = oB + wm * 32 + mt * 16 + 4 * g;
            int n = nB + wn * 64 + nt * 16 + l15;
            f32x4 v = acc[mt][nt];
            v[0] += bp2[o]; v[1] += bp2[o+1]; v[2] += bp2[o+2]; v[3] += bp2[o+3];
            v += ubf4(*(const unsigned long long*)(res + (size_t)n * kC + o));
            *(unsigned long long*)(out + (size_t)n * kC + o) = pk4(v[0], v[1], v[2], v[3]);
        }
}

// ---------------------------------------------------------------------------
// Fused qs-reduce + scores + top-16 (tie -> lower index).
// ---------------------------------------------------------------------------
__global__ void score_topk_kernel(const float* __restrict__ qpart,
                                  const float* __restrict__ ksum_h,
                                  const float* __restrict__ ksum_w,
                                  int* __restrict__ hidx, int* __restrict__ widx)
{
    __shared__ float qsl[2][64];
    __shared__ float hs[128], ws[128];
    int bh = blockIdx.x;
    int tid = threadIdx.x;               // 128
    int hc = tid & 63, grp = tid >> 6;
    {
        const float* qp = qpart + ((size_t)bh * 128 + grp * 64) * 64 + hc;
        float s = 0.f;
        for (int i = 0; i < 64; ++i) s += qp[(size_t)i * 64];
        qsl[grp][hc] = s;
    }
    __syncthreads();
    if (tid < 64) qsl[0][tid] += qsl[1][tid];
    __syncthreads();
    {
        const float* kh = ksum_h + ((size_t)bh * 128 + tid) * 64;
        const float* kw = ksum_w + ((size_t)bh * 128 + tid) * 64;
        float sh = 0.f, sw = 0.f;
        for (int c = 0; c < 64; ++c) {
            float q = qsl[0][c];
            sh += q * kh[c];
            sw += q * kw[c];
        }
        hs[tid] = sh; ws[tid] = sw;
    }
    __syncthreads();
    int sel = tid >> 6;
    const float* sc = sel ? ws : hs;
    int* out = (sel ? widx : hidx) + bh * kP;
    int lane = tid & 63;
    float v0 = sc[lane], v1 = sc[lane + 64];
    int i0 = lane, i1 = lane + 64;
    for (int p = 0; p < kP; ++p) {
        float bv; int bi;
        if (v1 > v0) { bv = v1; bi = i1; } else { bv = v0; bi = i0; }
#pragma unroll
        for (int off = 1; off < 64; off <<= 1) {
            float ov = __shfl_xor(bv, off);
            int   oi = __shfl_xor(bi, off);
            if (ov > bv || (ov == bv && oi < bi)) { bv = ov; bi = oi; }
        }
        if (lane == 0) out[p] = bi;
        if (i0 == bi) v0 = -INFINITY;
        if (i1 == bi) v1 = -INFINITY;
    }
}

// ---------------------------------------------------------------------------
// Gather kf from dense KPb; lazy-project vfT.
// ---------------------------------------------------------------------------
__global__ void gather_kv_kernel(const unsigned short* __restrict__ kpb,
                                 const unsigned short* __restrict__ xnb,
                                 const float* __restrict__ wv,
                                 const int* __restrict__ hidx, const int* __restrict__ widx,
                                 unsigned short* __restrict__ kf, unsigned short* __restrict__ vfT)
{
    int bh = blockIdx.y, p1 = blockIdx.x;
    int b = bh >> 3, nh = bh & 7;
    int hc = threadIdx.x & 63, pg = threadIdx.x >> 6;
    int hrow = hidx[bh * kP + p1];
    int o = nh * kHC + hc;
    const float* wvp = wv + (size_t)o * kC;
    for (int p2 = pg; p2 < kP; p2 += 4) {
        int wcol = widx[bh * kP + p2];
        int n = b * kHW + hrow * kW + wcol;
        int kidx = p1 * kP + p2;
        kf[((size_t)bh * 256 + kidx) * 64 + hc] = kpb[(size_t)n * kHID + nh * kHC + hc];
        const unsigned int* xr = (const unsigned int*)(xnb + (size_t)n * kC);
        float s = 0.f;
        for (int c2 = 0; c2 < kC / 2; ++c2) {
            unsigned int u = xr[c2];
            s += wvp[c2 * 2]     * bf2f((unsigned short)(u & 0xffff));
            s += wvp[c2 * 2 + 1] * bf2f((unsigned short)(u >> 16));
        }
        vfT[((size_t)bh * 64 + hc) * 256 + kidx] = f2bf(s);
    }
}

// ---------------------------------------------------------------------------
// MFMA attention, QBLK=128: kf fragments loaded once, reused for 2 q-subtiles.
// P in LDS stride-256 + XOR swizzle (conflict-free).
// ---------------------------------------------------------------------------
__global__ __launch_bounds__(256) void attn_kernel(
    const unsigned short* __restrict__ qpb, unsigned short* __restrict__ ob,
    const unsigned short* __restrict__ kf, const unsigned short* __restrict__ vfT)
{
    __shared__ unsigned short pls[64 * 256];
    __shared__ float lred[4][4][16];

    int bh = blockIdx.y; int b = bh >> 3, nh = bh & 7;
    int nbase = b * kHW + blockIdx.x * 128;
    int tid = threadIdx.x;
    int w = tid >> 6, lane = tid & 63, l15 = lane & 15, g = lane >> 4;

    const unsigned short* kfb = kf + (size_t)bh * 256 * 64;
    bf16x8 ak[4][2];
#pragma unroll
    for (int mt = 0; mt < 4; ++mt)
#pragma unroll
        for (int kt = 0; kt < 2; ++kt)
            ak[mt][kt] = *(const bf16x8*)&kfb[(size_t)(w * 64 + mt * 16 + l15) * 64 + kt * 32 + 8 * g];

    const unsigned short* vfb = vfT + (size_t)bh * 64 * 256;

#pragma unroll
    for (int sub = 0; sub < 2; ++sub) {
        int n0 = nbase + sub * 64;
        bf16x8 bq[4][2];
#pragma unroll
        for (int nt = 0; nt < 4; ++nt)
#pragma unroll
            for (int kt = 0; kt < 2; ++kt)
                bq[nt][kt] = *(const bf16x8*)(qpb + (size_t)(n0 + nt * 16 + l15) * kHID
                                              + nh * kHC + kt * 32 + 8 * g);

        f32x4 acc[4][4];
#pragma unroll
        for (int mt = 0; mt < 4; ++mt)
#pragma unroll
            for (int nt = 0; nt < 4; ++nt) acc[mt][nt] = (f32x4){0.f,0.f,0.f,0.f};

#pragma unroll
        for (int kt = 0; kt < 2; ++kt)
#pragma unroll
            for (int mt = 0; mt < 4; ++mt)
#pragma unroll
                for (int nt = 0; nt < 4; ++nt)
                    acc[mt][nt] = __builtin_amdgcn_mfma_f32_16x16x32_bf16(
                        ak[mt][kt], bq[nt][kt], acc[mt][nt], 0, 0, 0);

        if (sub) __syncthreads();

        float lpart[4] = {0.f, 0.f, 0.f, 0.f};
#pragma unroll
        for (int mt = 0; mt < 4; ++mt)
#pragma unroll
            for (int nt = 0; nt < 4; ++nt) {
                float e0 = __expf(acc[mt][nt][0]);
                float e1 = __expf(acc[mt][nt][1]);
                float e2 = __expf(acc[mt][nt][2]);
                float e3 = __expf(acc[mt][nt][3]);
                lpart[nt] += (e0 + e1) + (e2 + e3);
                int qq = nt * 16 + l15;
                int k0 = w * 64 + mt * 16 + 4 * g;
                int kx = k0 ^ ((qq & 7) << 3);
                *(unsigned long long*)&pls[qq * 256 + kx] = pk4(e0, e1, e2, e3);
            }
#pragma unroll
        for (int nt = 0; nt < 4; ++nt) {
            lpart[nt] += __shfl_xor(lpart[nt], 16);
            lpart[nt] += __shfl_xor(lpart[nt], 32);
        }
        if (g == 0)
#pragma unroll
            for (int nt = 0; nt < 4; ++nt) lred[w][nt][l15] = lpart[nt];
        __syncthreads();

        f32x4 oacc[4];
#pragma unroll
        for (int nt = 0; nt < 4; ++nt) oacc[nt] = (f32x4){0.f,0.f,0.f,0.f};

#pragma unroll
        for (int ks = 0; ks < 8; ++ks) {
            bf16x8 av = *(const bf16x8*)&vfb[(size_t)(w * 16 + l15) * 256 + ks * 32 + 8 * g];
#pragma unroll
            for (int nt = 0; nt < 4; ++nt) {
                int qq = nt * 16 + l15;
                int kx = (ks * 32 + 8 * g) ^ ((qq & 7) << 3);
                bf16x8 bp = *(const bf16x8*)&pls[qq * 256 + kx];
                oacc[nt] = __builtin_amdgcn_mfma_f32_16x16x32_bf16(av, bp, oacc[nt], 0, 0, 0);
            }
        }

#pragma unroll
        for (int nt = 0; nt < 4; ++nt) {
            float l = lred[0][nt][l15] + lred[1][nt][l15] + lred[2][nt][l15] + lred[3][nt][l15];
            float inv = 1.0f / l;
            int qq = nt * 16 + l15;
            int hc0 = w * 16 + 4 * g;
            *(unsigned long long*)(ob + (size_t)(n0 + qq) * kHID + nh * kHC + hc0) =
                pk4(oacc[nt][0] * inv, oacc[nt][1] * inv, oacc[nt][2] * inv, oacc[nt][3] * inv);
        }
    }
}

// ---------------------------------------------------------------------------
// Instance-norm stats (bf16 input) via per-chunk atomics.
// ---------------------------------------------------------------------------
__global__ void istats_bf16_kernel(const unsigned short* __restrict__ in, float* __restrict__ acc)
{
    int n0 = blockIdx.x * 64;
    int b = n0 >> 14;
    int c = threadIdx.x;
    float s = 0.f, ss = 0.f;
    for (int p = 0; p < 64; ++p) {
        float v = bf2f(in[(size_t)(n0 + p) * kC + c]);
        s += v; ss += v * v;
    }
    atomicAdd(&acc[(size_t)(b * kC + c) * 2],     s);
    atomicAdd(&acc[(size_t)(b * kC + c) * 2 + 1], ss);
}

__device__ inline void inorm_ms(const float* acc, int b, int c, float& m, float& rs)
{
    float s  = acc[(size_t)(b * kC + c) * 2];
    float ss = acc[(size_t)(b * kC + c) * 2 + 1];
    m = s * (1.0f / kHW);
    float var = ss * (1.0f / kHW) - m * m;
    rs = rsqrtf(var + kEPS);
}

// ---------------------------------------------------------------------------
// Fused res-dwconv: R = res_b + dwconv(gelu(inorm_acc0(T1))).
// ---------------------------------------------------------------------------
__global__ void dwconv_gelu_kernel(const unsigned short* __restrict__ t1,
                                   const float* __restrict__ acc0,
                                   unsigned short* __restrict__ rout,
                                   const float* __restrict__ wt, const float* __restrict__ bias)
{
    int idx = blockIdx.x * 256 + threadIdx.x;      // kN*48
    int n = idx / 48;
    int c0 = (idx - n * 48) * 4;
    int hw = n & (kHW - 1);
    int b = n >> 14;
    int h = hw >> 7, ww = hw & 127;
    float m[4], rs[4];
#pragma unroll
    for (int j = 0; j < 4; ++j) inorm_ms(acc0, b, c0 + j, m[j], rs[j]);
    f32x4 s = *(const f32x4*)(bias + c0);
#pragma unroll
    for (int dy = -1; dy <= 1; ++dy) {
        int hh = h + dy;
        if (hh < 0 || hh >= kH) continue;
#pragma unroll
        for (int dx = -1; dx <= 1; ++dx) {
            int wx = ww + dx;
            if (wx < 0 || wx >= kW) continue;
            f32x4 v = ubf4(*(const unsigned long long*)(t1 + (size_t)(n + dy * kW + dx) * kC + c0));
            int t = (dy + 1) * 3 + (dx + 1);
#pragma unroll
            for (int j = 0; j < 4; ++j)
                s[j] += gelu_f((v[j] - m[j]) * rs[j]) * wt[(c0 + j) * 9 + t];
        }
    }
    *(unsigned long long*)(rout + (size_t)n * kC + c0) = pk4(s[0], s[1], s[2], s[3]);
}

// ---------------------------------------------------------------------------
// Y3 = gelu(inorm_acc1(R)) + gelu(inorm_acc0(T1))
// ---------------------------------------------------------------------------
__global__ void apply_res_kernel(const unsigned short* __restrict__ r,
                                 const unsigned short* __restrict__ t1,
                                 const float* __restrict__ acc1, const float* __restrict__ acc0,
                                 unsigned short* __restrict__ out)
{
    int idx = blockIdx.x * 256 + threadIdx.x;      // kN*48
    int n = idx / 48;
    int c0 = (idx - n * 48) * 4;
    int b = n >> 14;
    f32x4 vr = ubf4(*(const unsigned long long*)(r  + (size_t)n * kC + c0));
    f32x4 vt = ubf4(*(const unsigned long long*)(t1 + (size_t)n * kC + c0));
    f32x4 o;
#pragma unroll
    for (int j = 0; j < 4; ++j) {
        float m1, rs1, m0, rs0;
        inorm_ms(acc1, b, c0 + j, m1, rs1);
        inorm_ms(acc0, b, c0 + j, m0, rs0);
        o[j] = gelu_f((vr[j] - m1) * rs1) + gelu_f((vt[j] - m0) * rs0);
    }
    *(unsigned long long*)(out + (size_t)n * kC + c0) = pk4(o[0], o[1], o[2], o[3]);
}

// ---------------------------------------------------------------------------
// Final inorm via LDS transpose: bf16 pixel-major in -> NCHW fp32 d_out.
// ---------------------------------------------------------------------------
__global__ __launch_bounds__(256) void final_kernel(const unsigned short* __restrict__ in,
                                                    const float* __restrict__ acc,
                                                    float* __restrict__ out)
{
    __shared__ unsigned short tile[192][68];
    int n0 = blockIdx.x * 64;
    int b = n0 >> 14;
    int hw0 = n0 & (kHW - 1);
    int tid = threadIdx.x;
    for (int i = tid; i < 64 * 48; i += 256) {
        int p = i / 48, cq = i - p * 48;
        unsigned long long u = *(const unsigned long long*)(in + (size_t)(n0 + p) * kC + cq * 4);
        tile[cq * 4 + 0][p] = (unsigned short)u;
        tile[cq * 4 + 1][p] = (unsigned short)(u >> 16);
        tile[cq * 4 + 2][p] = (unsigned short)(u >> 32);
        tile[cq * 4 + 3][p] = (unsigned short)(u >> 48);
    }
    __syncthreads();
    for (int i = tid; i < 192 * 16; i += 256) {
        int c = i >> 4, grp = i & 15;
        float m, rs;
        inorm_ms(acc, b, c, m, rs);
        f32x4 o;
#pragma unroll
        for (int j = 0; j < 4; ++j)
            o[j] = (bf2f(tile[c][grp * 4 + j]) - m) * rs;
        *(f32x4*)(out + (size_t)(b * kC + c) * kHW + hw0 + grp * 4) = o;
    }
}

// ---------------------------------------------------------------------------
extern "C" void kernel_launch(void* const* d_in, const int* in_sizes, int n_in,
                              void* d_out, int out_size, void* d_ws, size_t ws_size,
                              hipStream_t stream)
{
    const float* x     = (const float*)d_in[0];
    const float* ln1_g = (const float*)d_in[1];
    const float* ln1_b = (const float*)d_in[2];
    const float* wq    = (const float*)d_in[3];
    const float* wk    = (const float*)d_in[4];
    const float* wv    = (const float*)d_in[5];
    const float* wo    = (const float*)d_in[6];
    const float* bo    = (const float*)d_in[7];
    const float* dw_w  = (const float*)d_in[8];
    const float* dw_b  = (const float*)d_in[9];
    const float* mlp_w = (const float*)d_in[10];
    const float* mlp_b = (const float*)d_in[11];
    const float* ln2_g = (const float*)d_in[12];
    const float* ln2_b = (const float*)d_in[13];
    const float* c1_w  = (const float*)d_in[14];
    const float* c1_b  = (const float*)d_in[15];
    const float* res_w = (const float*)d_in[16];
    const float* res_b = (const float*)d_in[17];
    const float* c2_w  = (const float*)d_in[18];
    const float* c2_b  = (const float*)d_in[19];

    char* base = (char*)d_ws;
    unsigned short* XPb = (unsigned short*)(base);               // bf16 [n][192] raw x
    unsigned short* XNb = (unsigned short*)(base + 25165824);    // bf16 [n][192] xn / Y1
    unsigned short* QPb = (unsigned short*)(base + 37748736);    // bf16 [n][512]; later F / T2
    unsigned short* F   = QPb;
    unsigned short* T2  = QPb;
    unsigned short* KPb = (unsigned short*)(base + 71303168);    // bf16 [n][512]; OB/R alias
    unsigned short* OB  = KPb;
    unsigned short* R   = KPb;
    unsigned short* LB  = (unsigned short*)(base + 104857600);   // bf16 [n][192] local; later Y3
    unsigned short* Y3  = LB;
    unsigned short* T1  = (unsigned short*)(base + 117440512);   // bf16 [n][192]
    char* sm = base + 130023424;
    float* qpart  = (float*)(sm);                 sm += 524288;   // [16][128][64]
    float* ksum_h = (float*)(sm);                 sm += 524288;
    float* ksum_w = (float*)(sm);                 sm += 524288;
    float* acc0   = (float*)(sm);                 sm += 3072;     // zero block (2304 floats)
    float* acc1   = (float*)(sm);                 sm += 3072;
    float* acc2   = (float*)(sm);                 sm += 3072;
    unsigned short* kf   = (unsigned short*)(sm); sm += 524288;
    unsigned short* vfT  = (unsigned short*)(sm); sm += 524288;
    unsigned short* wqb  = (unsigned short*)(sm); sm += 196608;
    unsigned short* wkb  = (unsigned short*)(sm); sm += 196608;
    unsigned short* mlpb1= (unsigned short*)(sm); sm += 73728;
    unsigned short* c1b  = (unsigned short*)(sm); sm += 73728;
    unsigned short* c2b  = (unsigned short*)(sm); sm += 73728;
    unsigned short* w2pb = (unsigned short*)(sm); sm += 196608;
    float* bp2 = (float*)(sm);                    sm += 1024;
    int* hidx = (int*)(sm);                       sm += 1024;
    int* widx = (int*)(sm);

    // 1. prep
    prep_kernel<<<1593, 256, 0, stream>>>(acc0, wq, wk, mlp_w, c1_w, c2_w,
                                          wo, mlp_b, bo,
                                          wqb, wkb, mlpb1, c1b, c2b, w2pb, bp2);
    // 2. transpose + ln1
    txln_kernel<<<dim3(kHW / 64, kB), 256, 0, stream>>>(x, XPb, XNb, ln1_g, ln1_b);
    // 3. q/k projections (BM=128, intra-wave norm)
    qk_proj_kernel<<<dim3(kN / 128, 4, 2), 256, 0, stream>>>(wqb, wkb, XNb, QPb, KPb,
                                                             qpart, ksum_h);
    // 4. local dwconv
    dwconv_pm_kernel<<<(kN * 48) / 256, 256, 0, stream>>>(XPb, LB, dw_w, dw_b);
    // 5. ksum_w
    sum_h_kernel<<<dim3(kW, 16), 256, 0, stream>>>(KPb, ksum_w);
    // 6. scores + top-16
    score_topk_kernel<<<16, 128, 0, stream>>>(qpart, ksum_h, ksum_w, hidx, widx);
    // 7. gather: kf copy + lazy vfT
    gather_kv_kernel<<<dim3(kP, 16), 256, 0, stream>>>(KPb, XNb, wv, hidx, widx, kf, vfT);
    // 8. attention (QBLK=128)
    attn_kernel<<<dim3(kHW / 128, 16), 256, 0, stream>>>(QPb, OB, kf, vfT);
    // 9. fused mlp (wo folded) + residual
    mgemm_mlp_kernel<<<dim3(kN / 128, kC / 64), 256, 0, stream>>>(mlpb1, LB, w2pb, OB, F, bp2, XPb);
    // 10. ln2
    ln_pm_bf16_kernel<<<(kN * 4) / 256, 256, 0, stream>>>(F, XNb, ln2_g, ln2_b);
    // 11. c1 GEMM + istats(acc0)
    mgemm_is_kernel<<<dim3(kN / 128, kC / 64), 256, 0, stream>>>(c1b, XNb, T1, c1_b, acc0);
    // 12. res dwconv with inline gelu(inorm(T1))  -> R
    dwconv_gelu_kernel<<<(kN * 48) / 256, 256, 0, stream>>>(T1, acc0, R, res_w, res_b);
    // 13. istats(R) -> acc1
    istats_bf16_kernel<<<kN / 64, 192, 0, stream>>>(R, acc1);
    // 14. Y3 = gelu(inorm(R)) + gelu(inorm(T1))
    apply_res_kernel<<<(kN * 48) / 256, 256, 0, stream>>>(R, T1, acc1, acc0, Y3);
    // 15. c2 GEMM + istats(acc2)
    mgemm_is_kernel<<<dim3(kN / 128, kC / 64), 256, 0, stream>>>(c2b, Y3, T2, c2_b, acc2);
    // 16. final inorm -> d_out
    final_kernel<<<kN / 64, 256, 0, stream>>>(T2, acc2, (float*)d_out);
}

// Round 12
// 462.595 us; speedup vs baseline: 1.5053x; 1.0096x over previous
//
#include <hip/hip_runtime.h>
#include <math.h>

constexpr int kC   = 192;
constexpr int kNH  = 8;
constexpr int kHC  = 64;
constexpr int kHID = 512;
constexpr int kP   = 16;
constexpr int kB   = 2;
constexpr int kH   = 128;
constexpr int kW   = 128;
constexpr int kHW  = kH * kW;      // 16384
constexpr int kN   = kB * kHW;     // 32768
constexpr float kEPS = 1e-5f;

typedef __attribute__((ext_vector_type(8))) short bf16x8;
typedef __attribute__((ext_vector_type(4))) float f32x4;

__device__ inline unsigned short f2bf(float f) {
    unsigned int u = __builtin_bit_cast(unsigned int, f);
    unsigned int r = (u + 0x7FFFu + ((u >> 16) & 1u)) >> 16;   // RNE
    return (unsigned short)r;
}
__device__ inline float bf2f(unsigned short u) {
    return __builtin_bit_cast(float, (unsigned int)u << 16);
}
__device__ inline unsigned int cvtpk(float lo, float hi) {
    unsigned int r;
    asm("v_cvt_pk_bf16_f32 %0, %1, %2" : "=v"(r) : "v"(lo), "v"(hi));
    return r;
}
__device__ inline unsigned long long pk4(float a, float b, float c, float d) {
    return (unsigned long long)cvtpk(a, b) | ((unsigned long long)cvtpk(c, d) << 32);
}
__device__ inline f32x4 ubf4(unsigned long long u) {
    f32x4 r;
    r[0] = bf2f((unsigned short)u);
    r[1] = bf2f((unsigned short)(u >> 16));
    r[2] = bf2f((unsigned short)(u >> 32));
    r[3] = bf2f((unsigned short)(u >> 48));
    return r;
}
__device__ inline float gelu_f(float x) {
    return 0.5f * x * (1.0f + erff(x * 0.70710678118654752f));
}

// ---------------------------------------------------------------------------
// Prep: zero acc0..2 + bf16 weight cvts + fused W2' weight.
// ---------------------------------------------------------------------------
__global__ void prep_kernel(float* __restrict__ zbase,
                            const float* wq, const float* wk, const float* wm,
                            const float* c1, const float* c2,
                            const float* wo, const float* mlp_b, const float* bo,
                            unsigned short* wqb, unsigned short* wkb,
                            unsigned short* mlpb1, unsigned short* c1b, unsigned short* c2b,
                            unsigned short* w2pb, float* bp2)
{
    int i = blockIdx.x * 256 + threadIdx.x;
    if (i < 2304) { zbase[i] = 0.f; return; }            // acc0..2
    i -= 2304;
    if (i < 98304) { wqb[i] = f2bf(wq[i]); return; }
    i -= 98304;
    if (i < 98304) { wkb[i] = f2bf(wk[i]); return; }
    i -= 98304;
    if (i < 36864) { int o = i / 192, k = i - o * 192; mlpb1[i] = f2bf(wm[o * 384 + k]); return; }
    i -= 36864;
    if (i < 36864) { c1b[i] = f2bf(c1[i]); return; }
    i -= 36864;
    if (i < 36864) { c2b[i] = f2bf(c2[i]); return; }
    i -= 36864;
    if (i < 98304) {
        int o = i >> 9, j = i & 511;
        const float* a = wm + o * 384 + 192;
        float s = 0.f;
        for (int c = 0; c < 192; ++c) s += a[c] * wo[c * 512 + j];
        w2pb[o * 512 + j] = f2bf(s);
        if (j == 0) {
            float t = mlp_b[o];
            for (int c = 0; c < 192; ++c) t += a[c] * bo[c];
            bp2[o] = t;
        }
    }
}

// ---------------------------------------------------------------------------
// Fused transpose + ln1: x NCHW fp32 -> XPb raw bf16 [n][192] + XNb bf16.
// ---------------------------------------------------------------------------
__global__ __launch_bounds__(256) void txln_kernel(const float* __restrict__ x,
                                                   unsigned short* __restrict__ xpb,
                                                   unsigned short* __restrict__ xnb,
                                                   const float* __restrict__ g,
                                                   const float* __restrict__ bb)
{
    __shared__ float tile[192][65];
    __shared__ float red[2][4][64];
    __shared__ float pms[64], prs[64];
    int hw0 = blockIdx.x * 64;
    int b   = blockIdx.y;
    int tid = threadIdx.x;
    for (int i = tid; i < 192 * 64; i += 256) {
        int c = i >> 6, p = i & 63;
        tile[c][p] = x[(size_t)(b * kC + c) * kHW + hw0 + p];
    }
    __syncthreads();
    {
        int p = tid & 63, qt = tid >> 6;
        float s = 0.f, ss = 0.f;
        for (int c = qt * 48; c < qt * 48 + 48; ++c) {
            float v = tile[c][p]; s += v; ss += v * v;
        }
        red[0][qt][p] = s; red[1][qt][p] = ss;
    }
    __syncthreads();
    if (tid < 64) {
        float s  = red[0][0][tid] + red[0][1][tid] + red[0][2][tid] + red[0][3][tid];
        float ss = red[1][0][tid] + red[1][1][tid] + red[1][2][tid] + red[1][3][tid];
        float m = s * (1.0f / kC);
        float var = ss * (1.0f / kC) - m * m;
        pms[tid] = m;
        prs[tid] = rsqrtf(var + kEPS);
    }
    __syncthreads();
    for (int i = tid; i < 64 * 192; i += 256) {
        int p = i / 192, c = i - p * 192;
        float raw = tile[c][p];
        size_t oi = (size_t)(b * kHW + hw0 + p) * kC + c;
        xpb[oi] = f2bf(raw);
        xnb[oi] = f2bf((raw - pms[p]) * prs[p] * g[c] + bb[c]);
    }
}

// ---------------------------------------------------------------------------
// LayerNorm (ln2), bf16 -> bf16, 4 threads per pixel.
// ---------------------------------------------------------------------------
__global__ void ln_pm_bf16_kernel(const unsigned short* __restrict__ in,
                                  unsigned short* __restrict__ out,
                                  const float* __restrict__ g, const float* __restrict__ bb)
{
    int t = blockIdx.x * 256 + threadIdx.x;     // kN*4
    int n = t >> 2, q = t & 3;
    const unsigned long long* ip = (const unsigned long long*)(in + (size_t)n * kC) + q * 12;
    f32x4 v[12];
    float s = 0.f, ss = 0.f;
#pragma unroll
    for (int r = 0; r < 12; ++r) {
        v[r] = ubf4(ip[r]);
        s  += (v[r][0] + v[r][1]) + (v[r][2] + v[r][3]);
        ss += (v[r][0]*v[r][0] + v[r][1]*v[r][1]) + (v[r][2]*v[r][2] + v[r][3]*v[r][3]);
    }
    s  += __shfl_xor(s, 1);  s  += __shfl_xor(s, 2);
    ss += __shfl_xor(ss, 1); ss += __shfl_xor(ss, 2);
    float m  = s * (1.0f / kC);
    float var = ss * (1.0f / kC) - m * m;
    float rs = rsqrtf(var + kEPS);
    unsigned long long* op = (unsigned long long*)(out + (size_t)n * kC) + q * 12;
#pragma unroll
    for (int r = 0; r < 12; ++r) {
        f32x4 gg = *(const f32x4*)(g + q * 48 + r * 4);
        f32x4 bv = *(const f32x4*)(bb + q * 48 + r * 4);
        op[r] = pk4((v[r][0]-m)*rs*gg[0] + bv[0], (v[r][1]-m)*rs*gg[1] + bv[1],
                    (v[r][2]-m)*rs*gg[2] + bv[2], (v[r][3]-m)*rs*gg[3] + bv[3]);
    }
}

#define MGEMM_CORE(KVAL, APTR, BPTR)                                              \
    {                                                                             \
        const unsigned short* Ap = APTR;                                          \
        const unsigned short* Bp = BPTR;                                          \
        _Pragma("unroll 2")                                                       \
        for (int k = 0; k < KVAL; k += 32) {                                      \
            bf16x8 a0 = *(const bf16x8*)(Ap + k);                                 \
            bf16x8 a1 = *(const bf16x8*)(Ap + (size_t)16 * KVAL + k);             \
            bf16x8 b0 = *(const bf16x8*)(Bp + k);                                 \
            bf16x8 b1 = *(const bf16x8*)(Bp + (size_t)16 * KVAL + k);             \
            bf16x8 b2 = *(const bf16x8*)(Bp + (size_t)32 * KVAL + k);             \
            bf16x8 b3 = *(const bf16x8*)(Bp + (size_t)48 * KVAL + k);             \
            acc[0][0] = __builtin_amdgcn_mfma_f32_16x16x32_bf16(a0, b0, acc[0][0], 0, 0, 0); \
            acc[0][1] = __builtin_amdgcn_mfma_f32_16x16x32_bf16(a0, b1, acc[0][1], 0, 0, 0); \
            acc[0][2] = __builtin_amdgcn_mfma_f32_16x16x32_bf16(a0, b2, acc[0][2], 0, 0, 0); \
            acc[0][3] = __builtin_amdgcn_mfma_f32_16x16x32_bf16(a0, b3, acc[0][3], 0, 0, 0); \
            acc[1][0] = __builtin_amdgcn_mfma_f32_16x16x32_bf16(a1, b0, acc[1][0], 0, 0, 0); \
            acc[1][1] = __builtin_amdgcn_mfma_f32_16x16x32_bf16(a1, b1, acc[1][1], 0, 0, 0); \
            acc[1][2] = __builtin_amdgcn_mfma_f32_16x16x32_bf16(a1, b2, acc[1][2], 0, 0, 0); \
            acc[1][3] = __builtin_amdgcn_mfma_f32_16x16x32_bf16(a1, b3, acc[1][3], 0, 0, 0); \
        }                                                                         \
    }

// ---------------------------------------------------------------------------
// q/k projection GEMM, BM=128 (2 heads), 4 waves each owning one full
// (head x 64n) tile. Per-head L2 norm intra-wave. Fused row-sum.
// ---------------------------------------------------------------------------
__global__ __launch_bounds__(256) void qk_proj_kernel(
    const unsigned short* __restrict__ wqb, const unsigned short* __restrict__ wkb,
    const unsigned short* __restrict__ xnb,
    unsigned short* __restrict__ qpb, unsigned short* __restrict__ kpb,
    float* __restrict__ qpart, float* __restrict__ ksum_h)
{
    __shared__ float rbuf[2][2][4][4][4];   // [wm][wn][g][mt][r]
    int nB = blockIdx.x * 128;
    int hp = blockIdx.y;
    const unsigned short* A = blockIdx.z ? wkb : wqb;
    unsigned short* out = blockIdx.z ? kpb : qpb;
    float* red_out = blockIdx.z ? ksum_h : qpart;

    int w = threadIdx.x >> 6, lane = threadIdx.x & 63;
    int l15 = lane & 15, g = lane >> 4;
    int wm = w & 1, wn = w >> 1;
    int oB = hp * 128;

    const unsigned short* Ap = A + (size_t)(oB + wm * 64 + l15) * 192 + 8 * g;
    const unsigned short* Bp = xnb + (size_t)(nB + wn * 64 + l15) * 192 + 8 * g;

    f32x4 acc[4][4];
#pragma unroll
    for (int mt = 0; mt < 4; ++mt)
#pragma unroll
        for (int nt = 0; nt < 4; ++nt) acc[mt][nt] = (f32x4){0.f,0.f,0.f,0.f};

#pragma unroll 2
    for (int k = 0; k < 192; k += 32) {
        bf16x8 a[4], bb[4];
#pragma unroll
        for (int mt = 0; mt < 4; ++mt) a[mt] = *(const bf16x8*)(Ap + (size_t)mt * 16 * 192 + k);
#pragma unroll
        for (int nt = 0; nt < 4; ++nt) bb[nt] = *(const bf16x8*)(Bp + (size_t)nt * 16 * 192 + k);
#pragma unroll
        for (int mt = 0; mt < 4; ++mt)
#pragma unroll
            for (int nt = 0; nt < 4; ++nt)
                acc[mt][nt] = __builtin_amdgcn_mfma_f32_16x16x32_bf16(a[mt], bb[nt], acc[mt][nt], 0, 0, 0);
    }

    float sc[4];
#pragma unroll
    for (int nt = 0; nt < 4; ++nt) {
        float s = 0.f;
#pragma unroll
        for (int mt = 0; mt < 4; ++mt) {
            f32x4 a = acc[mt][nt];
            s += (a[0]*a[0] + a[1]*a[1]) + (a[2]*a[2] + a[3]*a[3]);
        }
        s += __shfl_xor(s, 16);
        s += __shfl_xor(s, 32);
        sc[nt] = 1.0f / fmaxf(sqrtf(s), 1e-12f);
    }

#pragma unroll
    for (int nt = 0; nt < 4; ++nt) {
        int n = nB + wn * 64 + nt * 16 + l15;
#pragma unroll
        for (int mt = 0; mt < 4; ++mt) {
            int o = oB + wm * 64 + mt * 16 + 4 * g;
            f32x4 v = acc[mt][nt];
            *(unsigned long long*)(out + (size_t)n * kHID + o) =
                pk4(v[0]*sc[nt], v[1]*sc[nt], v[2]*sc[nt], v[3]*sc[nt]);
        }
    }

    float sred[4][4] = {};
#pragma unroll
    for (int nt = 0; nt < 4; ++nt)
#pragma unroll
        for (int mt = 0; mt < 4; ++mt) {
            f32x4 a = acc[mt][nt];
            sred[mt][0] += a[0] * sc[nt];
            sred[mt][1] += a[1] * sc[nt];
            sred[mt][2] += a[2] * sc[nt];
            sred[mt][3] += a[3] * sc[nt];
        }
#pragma unroll
    for (int off = 1; off < 16; off <<= 1)
#pragma unroll
        for (int mt = 0; mt < 4; ++mt)
#pragma unroll
            for (int r = 0; r < 4; ++r)
                sred[mt][r] += __shfl_xor(sred[mt][r], off);
    if (l15 == 0)
#pragma unroll
        for (int mt = 0; mt < 4; ++mt)
#pragma unroll
            for (int r = 0; r < 4; ++r)
                rbuf[wm][wn][g][mt][r] = sred[mt][r];
    __syncthreads();
    if (threadIdx.x < 128) {
        int wm2 = threadIdx.x >> 6;
        int o = threadIdx.x & 63;
        int mt2 = o >> 4, g2 = (o >> 2) & 3, r2 = o & 3;
        float v = rbuf[wm2][0][g2][mt2][r2] + rbuf[wm2][1][g2][mt2][r2];
        int row = (nB & (kHW - 1)) >> 7;
        int b = nB >> 14;
        int bh = b * 8 + hp * 2 + wm2;
        red_out[((size_t)(bh * 128 + row)) * 64 + o] = v;
    }
}

// ---------------------------------------------------------------------------
// Depthwise 3x3 SAME conv, pixel-major bf16 in -> bf16 out [n][192].
// ---------------------------------------------------------------------------
__global__ void dwconv_pm_kernel(const unsigned short* __restrict__ in,
                                 unsigned short* __restrict__ out,
                                 const float* __restrict__ wt, const float* __restrict__ bias)
{
    int idx = blockIdx.x * 256 + threadIdx.x;      // kN*48
    int n = idx / 48;
    int c0 = (idx - n * 48) * 4;
    int hw = n & (kHW - 1);
    int h = hw >> 7, ww = hw & 127;
    f32x4 s = *(const f32x4*)(bias + c0);
#pragma unroll
    for (int dy = -1; dy <= 1; ++dy) {
        int hh = h + dy;
        if (hh < 0 || hh >= kH) continue;
#pragma unroll
        for (int dx = -1; dx <= 1; ++dx) {
            int wx = ww + dx;
            if (wx < 0 || wx >= kW) continue;
            f32x4 v = ubf4(*(const unsigned long long*)(in + (size_t)(n + dy * kW + dx) * kC + c0));
            int t = (dy + 1) * 3 + (dx + 1);
            s[0] += v[0] * wt[(c0 + 0) * 9 + t];
            s[1] += v[1] * wt[(c0 + 1) * 9 + t];
            s[2] += v[2] * wt[(c0 + 2) * 9 + t];
            s[3] += v[3] * wt[(c0 + 3) * 9 + t];
        }
    }
    *(unsigned long long*)(out + (size_t)n * kC + c0) = pk4(s[0], s[1], s[2], s[3]);
}

// ksum_w[bh][w][hc] = sum_h k.  256 threads: 4 h-segments of 32 + LDS reduce.
__global__ void sum_h_kernel(const unsigned short* __restrict__ buf, float* __restrict__ out)
{
    __shared__ float red[4][64];
    int w = blockIdx.x, bh = blockIdx.y;
    int hc = threadIdx.x & 63, seg = threadIdx.x >> 6;
    int b = bh >> 3, nh = bh & 7;
    const unsigned short* p = buf + (size_t)(b * kHW + seg * 32 * kW + w) * kHID + nh * kHC + hc;
    float s = 0.f;
    for (int h = 0; h < 32; ++h) s += bf2f(p[(size_t)h * kW * kHID]);
    red[seg][hc] = s;
    __syncthreads();
    if (threadIdx.x < 64)
        out[((size_t)bh * kW + w) * kHC + threadIdx.x] =
            red[0][threadIdx.x] + red[1][threadIdx.x] + red[2][threadIdx.x] + red[3][threadIdx.x];
}

// ---------------------------------------------------------------------------
// c1/c2 GEMM: bf16 out [n][192] + bias + fused instance-norm partial stats.
// ---------------------------------------------------------------------------
__global__ __launch_bounds__(256) void mgemm_is_kernel(
    const unsigned short* __restrict__ A, const unsigned short* __restrict__ B,
    unsigned short* __restrict__ out, const float* __restrict__ bias,
    float* __restrict__ accp)
{
    __shared__ float sa[2][64], qa[2][64];
    int nB = blockIdx.x * 128, oB = blockIdx.y * 64;
    int w = threadIdx.x >> 6, lane = threadIdx.x & 63;
    int l15 = lane & 15, g = lane >> 4;
    int wm = w & 1, wn = w >> 1;

    f32x4 acc[2][4];
#pragma unroll
    for (int mt = 0; mt < 2; ++mt)
#pragma unroll
        for (int nt = 0; nt < 4; ++nt) acc[mt][nt] = (f32x4){0.f,0.f,0.f,0.f};

    MGEMM_CORE(192, A + (size_t)(oB + wm * 32 + l15) * 192 + 8 * g,
                    B + (size_t)(nB + wn * 64 + l15) * 192 + 8 * g);

    f32x4 vv[2][4];
#pragma unroll
    for (int mt = 0; mt < 2; ++mt)
#pragma unroll
        for (int nt = 0; nt < 4; ++nt) {
            int o = oB + wm * 32 + mt * 16 + 4 * g;
            int n = nB + wn * 64 + nt * 16 + l15;
            f32x4 v = acc[mt][nt] + *(const f32x4*)(bias + o);
            vv[mt][nt] = v;
            *(unsigned long long*)(out + (size_t)n * kC + o) = pk4(v[0], v[1], v[2], v[3]);
        }
    float s2[2][4] = {}, q2[2][4] = {};
#pragma unroll
    for (int mt = 0; mt < 2; ++mt)
#pragma unroll
        for (int nt = 0; nt < 4; ++nt)
#pragma unroll
            for (int r = 0; r < 4; ++r) {
                float v = vv[mt][nt][r];
                s2[mt][r] += v; q2[mt][r] += v * v;
            }
#pragma unroll
    for (int off = 1; off < 16; off <<= 1)
#pragma unroll
        for (int mt = 0; mt < 2; ++mt)
#pragma unroll
            for (int r = 0; r < 4; ++r) {
                s2[mt][r] += __shfl_xor(s2[mt][r], off);
                q2[mt][r] += __shfl_xor(q2[mt][r], off);
            }
    if (l15 == 0)
#pragma unroll
        for (int mt = 0; mt < 2; ++mt)
#pragma unroll
            for (int r = 0; r < 4; ++r) {
                int ol = wm * 32 + mt * 16 + 4 * g + r;
                sa[wn][ol] = s2[mt][r];
                qa[wn][ol] = q2[mt][r];
            }
    __syncthreads();
    if (threadIdx.x < 128) {
        int ol = threadIdx.x & 63, st = threadIdx.x >> 6;
        float v = st ? (qa[0][ol] + qa[1][ol]) : (sa[0][ol] + sa[1][ol]);
        int b = nB >> 14;
        atomicAdd(&accp[(size_t)(b * kC + oB + ol) * 2 + st], v);
    }
}

// ---------------------------------------------------------------------------
// Fused MLP: F = mlp_w1@LB + W2'@OB + bp2 + x(bf16)   (bf16 out [n][192])
// ---------------------------------------------------------------------------
__global__ __launch_bounds__(256) void mgemm_mlp_kernel(
    const unsigned short* __restrict__ A1, const unsigned short* __restrict__ B1,
    const unsigned short* __restrict__ A2, const unsigned short* __restrict__ B2,
    unsigned short* __restrict__ out, const float* __restrict__ bp2,
    const unsigned short* __restrict__ res)
{
    int nB = blockIdx.x * 128, oB = blockIdx.y * 64;
    int w = threadIdx.x >> 6, lane = threadIdx.x & 63;
    int l15 = lane & 15, g = lane >> 4;
    int wm = w & 1, wn = w >> 1;

    f32x4 acc[2][4];
#pragma unroll
    for (int mt = 0; mt < 2; ++mt)
#pragma unroll
        for (int nt = 0; nt < 4; ++nt) acc[mt][nt] = (f32x4){0.f,0.f,0.f,0.f};

    MGEMM_CORE(192, A1 + (size_t)(oB + wm * 32 + l15) * 192 + 8 * g,
                    B1 + (size_t)(nB + wn * 64 + l15) * 192 + 8 * g);
    MGEMM_CORE(512, A2 + (size_t)(oB + wm * 32 + l15) * 512 + 8 * g,
                    B2 + (size_t)(nB + wn * 64 + l15) * 512 + 8 * g);

#pragma unroll
    for (int mt = 0; mt < 2; ++mt)
#pragma unroll
        for (int nt = 0; nt < 4; ++nt) {
            int o = oB + wm * 32 + mt * 16 + 4 * g;
            int n = nB + wn * 64 + nt * 16 + l15;
            f32x4 v = acc[mt][nt];
            v[0] += bp2[o]; v[1] += bp2[o+1]; v[2] += bp2[o+2]; v[3] += bp2[o+3];
            v += ubf4(*(const unsigned long long*)(res + (size_t)n * kC + o));
            *(unsigned long long*)(out + (size_t)n * kC + o) = pk4(v[0], v[1], v[2], v[3]);
        }
}

// ---------------------------------------------------------------------------
// Fused qs-reduce + scores + top-16 (tie -> lower index).
// ---------------------------------------------------------------------------
__global__ void score_topk_kernel(const float* __restrict__ qpart,
                                  const float* __restrict__ ksum_h,
                                  const float* __restrict__ ksum_w,
                                  int* __restrict__ hidx, int* __restrict__ widx)
{
    __shared__ float qsl[2][64];
    __shared__ float hs[128], ws[128];
    int bh = blockIdx.x;
    int tid = threadIdx.x;               // 128
    int hc = tid & 63, grp = tid >> 6;
    {
        const float* qp = qpart + ((size_t)bh * 128 + grp * 64) * 64 + hc;
        float s = 0.f;
        for (int i = 0; i < 64; ++i) s += qp[(size_t)i * 64];
        qsl[grp][hc] = s;
    }
    __syncthreads();
    if (tid < 64) qsl[0][tid] += qsl[1][tid];
    __syncthreads();
    {
        const float* kh = ksum_h + ((size_t)bh * 128 + tid) * 64;
        const float* kw = ksum_w + ((size_t)bh * 128 + tid) * 64;
        float sh = 0.f, sw = 0.f;
        for (int c = 0; c < 64; ++c) {
            float q = qsl[0][c];
            sh += q * kh[c];
            sw += q * kw[c];
        }
        hs[tid] = sh; ws[tid] = sw;
    }
    __syncthreads();
    int sel = tid >> 6;
    const float* sc = sel ? ws : hs;
    int* out = (sel ? widx : hidx) + bh * kP;
    int lane = tid & 63;
    float v0 = sc[lane], v1 = sc[lane + 64];
    int i0 = lane, i1 = lane + 64;
    for (int p = 0; p < kP; ++p) {
        float bv; int bi;
        if (v1 > v0) { bv = v1; bi = i1; } else { bv = v0; bi = i0; }
#pragma unroll
        for (int off = 1; off < 64; off <<= 1) {
            float ov = __shfl_xor(bv, off);
            int   oi = __shfl_xor(bi, off);
            if (ov > bv || (ov == bv && oi < bi)) { bv = ov; bi = oi; }
        }
        if (lane == 0) out[p] = bi;
        if (i0 == bi) v0 = -INFINITY;
        if (i1 == bi) v1 = -INFINITY;
    }
}

// ---------------------------------------------------------------------------
// Gather kf from dense KPb; lazy-project vfT.
// ---------------------------------------------------------------------------
__global__ void gather_kv_kernel(const unsigned short* __restrict__ kpb,
                                 const unsigned short* __restrict__ xnb,
                                 const float* __restrict__ wv,
                                 const int* __restrict__ hidx, const int* __restrict__ widx,
                                 unsigned short* __restrict__ kf, unsigned short* __restrict__ vfT)
{
    int bh = blockIdx.y, p1 = blockIdx.x;
    int b = bh >> 3, nh = bh & 7;
    int hc = threadIdx.x & 63, pg = threadIdx.x >> 6;
    int hrow = hidx[bh * kP + p1];
    int o = nh * kHC + hc;
    const float* wvp = wv + (size_t)o * kC;
    for (int p2 = pg; p2 < kP; p2 += 4) {
        int wcol = widx[bh * kP + p2];
        int n = b * kHW + hrow * kW + wcol;
        int kidx = p1 * kP + p2;
        kf[((size_t)bh * 256 + kidx) * 64 + hc] = kpb[(size_t)n * kHID + nh * kHC + hc];
        const unsigned int* xr = (const unsigned int*)(xnb + (size_t)n * kC);
        float s = 0.f;
        for (int c2 = 0; c2 < kC / 2; ++c2) {
            unsigned int u = xr[c2];
            s += wvp[c2 * 2]     * bf2f((unsigned short)(u & 0xffff));
            s += wvp[c2 * 2 + 1] * bf2f((unsigned short)(u >> 16));
        }
        vfT[((size_t)bh * 64 + hc) * 256 + kidx] = f2bf(s);
    }
}

// ---------------------------------------------------------------------------
// MFMA attention, QBLK=128: kf fragments loaded once, reused for 2 q-subtiles.
// P in LDS stride-256 + XOR swizzle (conflict-free).
// ---------------------------------------------------------------------------
__global__ __launch_bounds__(256) void attn_kernel(
    const unsigned short* __restrict__ qpb, unsigned short* __restrict__ ob,
    const unsigned short* __restrict__ kf, const unsigned short* __restrict__ vfT)
{
    __shared__ unsigned short pls[64 * 256];
    __shared__ float lred[4][4][16];

    int bh = blockIdx.y; int b = bh >> 3, nh = bh & 7;
    int nbase = b * kHW + blockIdx.x * 128;
    int tid = threadIdx.x;
    int w = tid >> 6, lane = tid & 63, l15 = lane & 15, g = lane >> 4;

    const unsigned short* kfb = kf + (size_t)bh * 256 * 64;
    bf16x8 ak[4][2];
#pragma unroll
    for (int mt = 0; mt < 4; ++mt)
#pragma unroll
        for (int kt = 0; kt < 2; ++kt)
            ak[mt][kt] = *(const bf16x8*)&kfb[(size_t)(w * 64 + mt * 16 + l15) * 64 + kt * 32 + 8 * g];

    const unsigned short* vfb = vfT + (size_t)bh * 64 * 256;

#pragma unroll
    for (int sub = 0; sub < 2; ++sub) {
        int n0 = nbase + sub * 64;
        bf16x8 bq[4][2];
#pragma unroll
        for (int nt = 0; nt < 4; ++nt)
#pragma unroll
            for (int kt = 0; kt < 2; ++kt)
                bq[nt][kt] = *(const bf16x8*)(qpb + (size_t)(n0 + nt * 16 + l15) * kHID
                                              + nh * kHC + kt * 32 + 8 * g);

        f32x4 acc[4][4];
#pragma unroll
        for (int mt = 0; mt < 4; ++mt)
#pragma unroll
            for (int nt = 0; nt < 4; ++nt) acc[mt][nt] = (f32x4){0.f,0.f,0.f,0.f};

#pragma unroll
        for (int kt = 0; kt < 2; ++kt)
#pragma unroll
            for (int mt = 0; mt < 4; ++mt)
#pragma unroll
                for (int nt = 0; nt < 4; ++nt)
                    acc[mt][nt] = __builtin_amdgcn_mfma_f32_16x16x32_bf16(
                        ak[mt][kt], bq[nt][kt], acc[mt][nt], 0, 0, 0);

        if (sub) __syncthreads();

        float lpart[4] = {0.f, 0.f, 0.f, 0.f};
#pragma unroll
        for (int mt = 0; mt < 4; ++mt)
#pragma unroll
            for (int nt = 0; nt < 4; ++nt) {
                float e0 = __expf(acc[mt][nt][0]);
                float e1 = __expf(acc[mt][nt][1]);
                float e2 = __expf(acc[mt][nt][2]);
                float e3 = __expf(acc[mt][nt][3]);
                lpart[nt] += (e0 + e1) + (e2 + e3);
                int qq = nt * 16 + l15;
                int k0 = w * 64 + mt * 16 + 4 * g;
                int kx = k0 ^ ((qq & 7) << 3);
                *(unsigned long long*)&pls[qq * 256 + kx] = pk4(e0, e1, e2, e3);
            }
#pragma unroll
        for (int nt = 0; nt < 4; ++nt) {
            lpart[nt] += __shfl_xor(lpart[nt], 16);
            lpart[nt] += __shfl_xor(lpart[nt], 32);
        }
        if (g == 0)
#pragma unroll
            for (int nt = 0; nt < 4; ++nt) lred[w][nt][l15] = lpart[nt];
        __syncthreads();

        f32x4 oacc[4];
#pragma unroll
        for (int nt = 0; nt < 4; ++nt) oacc[nt] = (f32x4){0.f,0.f,0.f,0.f};

#pragma unroll
        for (int ks = 0; ks < 8; ++ks) {
            bf16x8 av = *(const bf16x8*)&vfb[(size_t)(w * 16 + l15) * 256 + ks * 32 + 8 * g];
#pragma unroll
            for (int nt = 0; nt < 4; ++nt) {
                int qq = nt * 16 + l15;
                int kx = (ks * 32 + 8 * g) ^ ((qq & 7) << 3);
                bf16x8 bp = *(const bf16x8*)&pls[qq * 256 + kx];
                oacc[nt] = __builtin_amdgcn_mfma_f32_16x16x32_bf16(av, bp, oacc[nt], 0, 0, 0);
            }
        }

#pragma unroll
        for (int nt = 0; nt < 4; ++nt) {
            float l = lred[0][nt][l15] + lred[1][nt][l15] + lred[2][nt][l15] + lred[3][nt][l15];
            float inv = 1.0f / l;
            int qq = nt * 16 + l15;
            int hc0 = w * 16 + 4 * g;
            *(unsigned long long*)(ob + (size_t)(n0 + qq) * kHID + nh * kHC + hc0) =
                pk4(oacc[nt][0] * inv, oacc[nt][1] * inv, oacc[nt][2] * inv, oacc[nt][3] * inv);
        }
    }
}

// ---------------------------------------------------------------------------
// Instance-norm stats (bf16 input) via per-chunk atomics.
// ---------------------------------------------------------------------------
__global__ void istats_bf16_kernel(const unsigned short* __restrict__ in, float* __restrict__ acc)
{
    int n0 = blockIdx.x * 64;
    int b = n0 >> 14;
    int c = threadIdx.x;
    float s = 0.f, ss = 0.f;
    for (int p = 0; p < 64; ++p) {
        float v = bf2f(in[(size_t)(n0 + p) * kC + c]);
        s += v; ss += v * v;
    }
    atomicAdd(&acc[(size_t)(b * kC + c) * 2],     s);
    atomicAdd(&acc[(size_t)(b * kC + c) * 2 + 1], ss);
}

__device__ inline void inorm_ms(const float* acc, int b, int c, float& m, float& rs)
{
    float s  = acc[(size_t)(b * kC + c) * 2];
    float ss = acc[(size_t)(b * kC + c) * 2 + 1];
    m = s * (1.0f / kHW);
    float var = ss * (1.0f / kHW) - m * m;
    rs = rsqrtf(var + kEPS);
}

// MODE 0: gelu(inorm(in)) -> bf16.  MODE 1: gelu(inorm(in)) + add -> bf16.
template<int MODE>
__global__ void apply_pm_kernel(const unsigned short* __restrict__ in, const float* __restrict__ acc,
                                unsigned short* __restrict__ out, const unsigned short* __restrict__ addsrc)
{
    int idx = blockIdx.x * 256 + threadIdx.x;      // kN*48
    int n = idx / 48;
    int c0 = (idx - n * 48) * 4;
    int b = n >> 14;
    f32x4 v = ubf4(*(const unsigned long long*)(in + (size_t)n * kC + c0));
    f32x4 r;
#pragma unroll
    for (int j = 0; j < 4; ++j) {
        float m, rs;
        inorm_ms(acc, b, c0 + j, m, rs);
        float x = (v[j] - m) * rs;
        r[j] = gelu_f(x);
    }
    if (MODE == 1)
        r += ubf4(*(const unsigned long long*)(addsrc + (size_t)n * kC + c0));
    *(unsigned long long*)(out + (size_t)n * kC + c0) = pk4(r[0], r[1], r[2], r[3]);
}

// ---------------------------------------------------------------------------
// Final inorm via LDS transpose: bf16 pixel-major in -> NCHW fp32 d_out.
// ---------------------------------------------------------------------------
__global__ __launch_bounds__(256) void final_kernel(const unsigned short* __restrict__ in,
                                                    const float* __restrict__ acc,
                                                    float* __restrict__ out)
{
    __shared__ unsigned short tile[192][68];
    int n0 = blockIdx.x * 64;
    int b = n0 >> 14;
    int hw0 = n0 & (kHW - 1);
    int tid = threadIdx.x;
    for (int i = tid; i < 64 * 48; i += 256) {
        int p = i / 48, cq = i - p * 48;
        unsigned long long u = *(const unsigned long long*)(in + (size_t)(n0 + p) * kC + cq * 4);
        tile[cq * 4 + 0][p] = (unsigned short)u;
        tile[cq * 4 + 1][p] = (unsigned short)(u >> 16);
        tile[cq * 4 + 2][p] = (unsigned short)(u >> 32);
        tile[cq * 4 + 3][p] = (unsigned short)(u >> 48);
    }
    __syncthreads();
    for (int i = tid; i < 192 * 16; i += 256) {
        int c = i >> 4, grp = i & 15;
        float m, rs;
        inorm_ms(acc, b, c, m, rs);
        f32x4 o;
#pragma unroll
        for (int j = 0; j < 4; ++j)
            o[j] = (bf2f(tile[c][grp * 4 + j]) - m) * rs;
        *(f32x4*)(out + (size_t)(b * kC + c) * kHW + hw0 + grp * 4) = o;
    }
}

// ---------------------------------------------------------------------------
extern "C" void kernel_launch(void* const* d_in, const int* in_sizes, int n_in,
                              void* d_out, int out_size, void* d_ws, size_t ws_size,
                              hipStream_t stream)
{
    const float* x     = (const float*)d_in[0];
    const float* ln1_g = (const float*)d_in[1];
    const float* ln1_b = (const float*)d_in[2];
    const float* wq    = (const float*)d_in[3];
    const float* wk    = (const float*)d_in[4];
    const float* wv    = (const float*)d_in[5];
    const float* wo    = (const float*)d_in[6];
    const float* bo    = (const float*)d_in[7];
    const float* dw_w  = (const float*)d_in[8];
    const float* dw_b  = (const float*)d_in[9];
    const float* mlp_w = (const float*)d_in[10];
    const float* mlp_b = (const float*)d_in[11];
    const float* ln2_g = (const float*)d_in[12];
    const float* ln2_b = (const float*)d_in[13];
    const float* c1_w  = (const float*)d_in[14];
    const float* c1_b  = (const float*)d_in[15];
    const float* res_w = (const float*)d_in[16];
    const float* res_b = (const float*)d_in[17];
    const float* c2_w  = (const float*)d_in[18];
    const float* c2_b  = (const float*)d_in[19];

    char* base = (char*)d_ws;
    unsigned short* XPb = (unsigned short*)(base);               // bf16 [n][192] raw x
    unsigned short* XNb = (unsigned short*)(base + 25165824);    // bf16 [n][192] xn / Y1
    unsigned short* QPb = (unsigned short*)(base + 37748736);    // bf16 [n][512]; later F / T2
    unsigned short* F   = QPb;
    unsigned short* T2  = QPb;
    unsigned short* KPb = (unsigned short*)(base + 71303168);    // bf16 [n][512]; OB alias; later Y2
    unsigned short* OB  = KPb;
    unsigned short* Y2  = KPb;
    unsigned short* LB  = (unsigned short*)(base + 104857600);   // bf16 [n][192] local; later Y3
    unsigned short* Y3  = LB;
    unsigned short* T1  = (unsigned short*)(base + 117440512);   // bf16 [n][192]; later R
    unsigned short* R   = T1;
    char* sm = base + 130023424;
    float* qpart  = (float*)(sm);                 sm += 524288;   // [16][128][64]
    float* ksum_h = (float*)(sm);                 sm += 524288;
    float* ksum_w = (float*)(sm);                 sm += 524288;
    float* acc0   = (float*)(sm);                 sm += 3072;     // zero block (2304 floats)
    float* acc1   = (float*)(sm);                 sm += 3072;
    float* acc2   = (float*)(sm);                 sm += 3072;
    unsigned short* kf   = (unsigned short*)(sm); sm += 524288;
    unsigned short* vfT  = (unsigned short*)(sm); sm += 524288;
    unsigned short* wqb  = (unsigned short*)(sm); sm += 196608;
    unsigned short* wkb  = (unsigned short*)(sm); sm += 196608;
    unsigned short* mlpb1= (unsigned short*)(sm); sm += 73728;
    unsigned short* c1b  = (unsigned short*)(sm); sm += 73728;
    unsigned short* c2b  = (unsigned short*)(sm); sm += 73728;
    unsigned short* w2pb = (unsigned short*)(sm); sm += 196608;
    float* bp2 = (float*)(sm);                    sm += 1024;
    int* hidx = (int*)(sm);                       sm += 1024;
    int* widx = (int*)(sm);

    // 1. prep
    prep_kernel<<<1593, 256, 0, stream>>>(acc0, wq, wk, mlp_w, c1_w, c2_w,
                                          wo, mlp_b, bo,
                                          wqb, wkb, mlpb1, c1b, c2b, w2pb, bp2);
    // 2. transpose + ln1
    txln_kernel<<<dim3(kHW / 64, kB), 256, 0, stream>>>(x, XPb, XNb, ln1_g, ln1_b);
    // 3. q/k projections (BM=128, intra-wave norm)
    qk_proj_kernel<<<dim3(kN / 128, 4, 2), 256, 0, stream>>>(wqb, wkb, XNb, QPb, KPb,
                                                             qpart, ksum_h);
    // 4. local dwconv
    dwconv_pm_kernel<<<(kN * 48) / 256, 256, 0, stream>>>(XPb, LB, dw_w, dw_b);
    // 5. ksum_w
    sum_h_kernel<<<dim3(kW, 16), 256, 0, stream>>>(KPb, ksum_w);
    // 6. scores + top-16
    score_topk_kernel<<<16, 128, 0, stream>>>(qpart, ksum_h, ksum_w, hidx, widx);
    // 7. gather: kf copy + lazy vfT
    gather_kv_kernel<<<dim3(kP, 16), 256, 0, stream>>>(KPb, XNb, wv, hidx, widx, kf, vfT);
    // 8. attention (QBLK=128; OB overwrites KPb, kf/vfT already extracted)
    attn_kernel<<<dim3(kHW / 128, 16), 256, 0, stream>>>(QPb, OB, kf, vfT);
    // 9. fused mlp (wo folded) + residual
    mgemm_mlp_kernel<<<dim3(kN / 128, kC / 64), 256, 0, stream>>>(mlpb1, LB, w2pb, OB, F, bp2, XPb);
    // 10. ln2
    ln_pm_bf16_kernel<<<(kN * 4) / 256, 256, 0, stream>>>(F, XNb, ln2_g, ln2_b);
    // 11. c1 GEMM + istats(acc0)
    mgemm_is_kernel<<<dim3(kN / 128, kC / 64), 256, 0, stream>>>(c1b, XNb, T1, c1_b, acc0);
    // 12. Y2 = gelu(inorm(T1))   (gelu ONCE per element; OB region is dead)
    apply_pm_kernel<0><<<(kN * 48) / 256, 256, 0, stream>>>(T1, acc0, Y2, nullptr);
    // 13. res dwconv: R = dwconv(Y2)   (R overwrites T1, which is dead)
    dwconv_pm_kernel<<<(kN * 48) / 256, 256, 0, stream>>>(Y2, R, res_w, res_b);
    // 14. istats(R) -> acc1
    istats_bf16_kernel<<<kN / 64, 192, 0, stream>>>(R, acc1);
    // 15. Y3 = gelu(inorm(R)) + Y2
    apply_pm_kernel<1><<<(kN * 48) / 256, 256, 0, stream>>>(R, acc1, Y3, Y2);
    // 16. c2 GEMM + istats(acc2)
    mgemm_is_kernel<<<dim3(kN / 128, kC / 64), 256, 0, stream>>>(c2b, Y3, T2, c2_b, acc2);
    // 17. final inorm -> d_out
    final_kernel<<<kN / 64, 256, 0, stream>>>(T2, acc2, (float*)d_out);
}

// Round 13
// 451.751 us; speedup vs baseline: 1.5414x; 1.0240x over previous
//
#include <hip/hip_runtime.h>
#include <math.h>

constexpr int kC   = 192;
constexpr int kNH  = 8;
constexpr int kHC  = 64;
constexpr int kHID = 512;
constexpr int kP   = 16;
constexpr int kB   = 2;
constexpr int kH   = 128;
constexpr int kW   = 128;
constexpr int kHW  = kH * kW;      // 16384
constexpr int kN   = kB * kHW;     // 32768
constexpr float kEPS = 1e-5f;

typedef __attribute__((ext_vector_type(8))) short bf16x8;
typedef __attribute__((ext_vector_type(4))) float f32x4;

__device__ inline unsigned short f2bf(float f) {
    unsigned int u = __builtin_bit_cast(unsigned int, f);
    unsigned int r = (u + 0x7FFFu + ((u >> 16) & 1u)) >> 16;   // RNE
    return (unsigned short)r;
}
__device__ inline float bf2f(unsigned short u) {
    return __builtin_bit_cast(float, (unsigned int)u << 16);
}
__device__ inline unsigned int cvtpk(float lo, float hi) {
    unsigned int r;
    asm("v_cvt_pk_bf16_f32 %0, %1, %2" : "=v"(r) : "v"(lo), "v"(hi));
    return r;
}
__device__ inline unsigned long long pk4(float a, float b, float c, float d) {
    return (unsigned long long)cvtpk(a, b) | ((unsigned long long)cvtpk(c, d) << 32);
}
__device__ inline f32x4 ubf4(unsigned long long u) {
    f32x4 r;
    r[0] = bf2f((unsigned short)u);
    r[1] = bf2f((unsigned short)(u >> 16));
    r[2] = bf2f((unsigned short)(u >> 32));
    r[3] = bf2f((unsigned short)(u >> 48));
    return r;
}
__device__ inline float gelu_f(float x) {
    return 0.5f * x * (1.0f + erff(x * 0.70710678118654752f));
}

// ---------------------------------------------------------------------------
// Prep: zero acc0..2 + bf16 weight cvts + fused W2' weight.
// ---------------------------------------------------------------------------
__global__ void prep_kernel(float* __restrict__ zbase,
                            const float* wq, const float* wk, const float* wm,
                            const float* c1, const float* c2,
                            const float* wo, const float* mlp_b, const float* bo,
                            unsigned short* wqb, unsigned short* wkb,
                            unsigned short* mlpb1, unsigned short* c1b, unsigned short* c2b,
                            unsigned short* w2pb, float* bp2)
{
    int i = blockIdx.x * 256 + threadIdx.x;
    if (i < 2304) { zbase[i] = 0.f; return; }            // acc0..2
    i -= 2304;
    if (i < 98304) { wqb[i] = f2bf(wq[i]); return; }
    i -= 98304;
    if (i < 98304) { wkb[i] = f2bf(wk[i]); return; }
    i -= 98304;
    if (i < 36864) { int o = i / 192, k = i - o * 192; mlpb1[i] = f2bf(wm[o * 384 + k]); return; }
    i -= 36864;
    if (i < 36864) { c1b[i] = f2bf(c1[i]); return; }
    i -= 36864;
    if (i < 36864) { c2b[i] = f2bf(c2[i]); return; }
    i -= 36864;
    if (i < 98304) {
        int o = i >> 9, j = i & 511;
        const float* a = wm + o * 384 + 192;
        float s = 0.f;
        for (int c = 0; c < 192; ++c) s += a[c] * wo[c * 512 + j];
        w2pb[o * 512 + j] = f2bf(s);
        if (j == 0) {
            float t = mlp_b[o];
            for (int c = 0; c < 192; ++c) t += a[c] * bo[c];
            bp2[o] = t;
        }
    }
}

// ---------------------------------------------------------------------------
// Fused transpose + ln1: x NCHW fp32 -> XPb raw bf16 [n][192] + XNb bf16.
// ---------------------------------------------------------------------------
__global__ __launch_bounds__(256) void txln_kernel(const float* __restrict__ x,
                                                   unsigned short* __restrict__ xpb,
                                                   unsigned short* __restrict__ xnb,
                                                   const float* __restrict__ g,
                                                   const float* __restrict__ bb)
{
    __shared__ float tile[192][65];
    __shared__ float red[2][4][64];
    __shared__ float pms[64], prs[64];
    int hw0 = blockIdx.x * 64;
    int b   = blockIdx.y;
    int tid = threadIdx.x;
    for (int i = tid; i < 192 * 64; i += 256) {
        int c = i >> 6, p = i & 63;
        tile[c][p] = x[(size_t)(b * kC + c) * kHW + hw0 + p];
    }
    __syncthreads();
    {
        int p = tid & 63, qt = tid >> 6;
        float s = 0.f, ss = 0.f;
        for (int c = qt * 48; c < qt * 48 + 48; ++c) {
            float v = tile[c][p]; s += v; ss += v * v;
        }
        red[0][qt][p] = s; red[1][qt][p] = ss;
    }
    __syncthreads();
    if (tid < 64) {
        float s  = red[0][0][tid] + red[0][1][tid] + red[0][2][tid] + red[0][3][tid];
        float ss = red[1][0][tid] + red[1][1][tid] + red[1][2][tid] + red[1][3][tid];
        float m = s * (1.0f / kC);
        float var = ss * (1.0f / kC) - m * m;
        pms[tid] = m;
        prs[tid] = rsqrtf(var + kEPS);
    }
    __syncthreads();
    for (int i = tid; i < 64 * 192; i += 256) {
        int p = i / 192, c = i - p * 192;
        float raw = tile[c][p];
        size_t oi = (size_t)(b * kHW + hw0 + p) * kC + c;
        xpb[oi] = f2bf(raw);
        xnb[oi] = f2bf((raw - pms[p]) * prs[p] * g[c] + bb[c]);
    }
}

#define MGEMM_CORE(KVAL, APTR, BPTR)                                              \
    {                                                                             \
        const unsigned short* Ap = APTR;                                          \
        const unsigned short* Bp = BPTR;                                          \
        _Pragma("unroll 2")                                                       \
        for (int k = 0; k < KVAL; k += 32) {                                      \
            bf16x8 a0 = *(const bf16x8*)(Ap + k);                                 \
            bf16x8 a1 = *(const bf16x8*)(Ap + (size_t)16 * KVAL + k);             \
            bf16x8 b0 = *(const bf16x8*)(Bp + k);                                 \
            bf16x8 b1 = *(const bf16x8*)(Bp + (size_t)16 * KVAL + k);             \
            bf16x8 b2 = *(const bf16x8*)(Bp + (size_t)32 * KVAL + k);             \
            bf16x8 b3 = *(const bf16x8*)(Bp + (size_t)48 * KVAL + k);             \
            acc[0][0] = __builtin_amdgcn_mfma_f32_16x16x32_bf16(a0, b0, acc[0][0], 0, 0, 0); \
            acc[0][1] = __builtin_amdgcn_mfma_f32_16x16x32_bf16(a0, b1, acc[0][1], 0, 0, 0); \
            acc[0][2] = __builtin_amdgcn_mfma_f32_16x16x32_bf16(a0, b2, acc[0][2], 0, 0, 0); \
            acc[0][3] = __builtin_amdgcn_mfma_f32_16x16x32_bf16(a0, b3, acc[0][3], 0, 0, 0); \
            acc[1][0] = __builtin_amdgcn_mfma_f32_16x16x32_bf16(a1, b0, acc[1][0], 0, 0, 0); \
            acc[1][1] = __builtin_amdgcn_mfma_f32_16x16x32_bf16(a1, b1, acc[1][1], 0, 0, 0); \
            acc[1][2] = __builtin_amdgcn_mfma_f32_16x16x32_bf16(a1, b2, acc[1][2], 0, 0, 0); \
            acc[1][3] = __builtin_amdgcn_mfma_f32_16x16x32_bf16(a1, b3, acc[1][3], 0, 0, 0); \
        }                                                                         \
    }

// ---------------------------------------------------------------------------
// q/k projection body, BM=128 (2 heads), 4 waves each a full (head x 64n)
// tile. Per-head L2 norm intra-wave. Fused row-sum.
// ---------------------------------------------------------------------------
__device__ void qk_proj_body(int nblk, int hp, int isK,
                             const unsigned short* __restrict__ wqb,
                             const unsigned short* __restrict__ wkb,
                             const unsigned short* __restrict__ xnb,
                             unsigned short* __restrict__ qpb,
                             unsigned short* __restrict__ kpb,
                             float* __restrict__ qpart, float* __restrict__ ksum_h)
{
    __shared__ float rbuf[2][2][4][4][4];   // [wm][wn][g][mt][r]
    int nB = nblk * 128;
    const unsigned short* A = isK ? wkb : wqb;
    unsigned short* out = isK ? kpb : qpb;
    float* red_out = isK ? ksum_h : qpart;

    int w = threadIdx.x >> 6, lane = threadIdx.x & 63;
    int l15 = lane & 15, g = lane >> 4;
    int wm = w & 1, wn = w >> 1;
    int oB = hp * 128;

    const unsigned short* Ap = A + (size_t)(oB + wm * 64 + l15) * 192 + 8 * g;
    const unsigned short* Bp = xnb + (size_t)(nB + wn * 64 + l15) * 192 + 8 * g;

    f32x4 acc[4][4];
#pragma unroll
    for (int mt = 0; mt < 4; ++mt)
#pragma unroll
        for (int nt = 0; nt < 4; ++nt) acc[mt][nt] = (f32x4){0.f,0.f,0.f,0.f};

#pragma unroll 2
    for (int k = 0; k < 192; k += 32) {
        bf16x8 a[4], bb[4];
#pragma unroll
        for (int mt = 0; mt < 4; ++mt) a[mt] = *(const bf16x8*)(Ap + (size_t)mt * 16 * 192 + k);
#pragma unroll
        for (int nt = 0; nt < 4; ++nt) bb[nt] = *(const bf16x8*)(Bp + (size_t)nt * 16 * 192 + k);
#pragma unroll
        for (int mt = 0; mt < 4; ++mt)
#pragma unroll
            for (int nt = 0; nt < 4; ++nt)
                acc[mt][nt] = __builtin_amdgcn_mfma_f32_16x16x32_bf16(a[mt], bb[nt], acc[mt][nt], 0, 0, 0);
    }

    float sc[4];
#pragma unroll
    for (int nt = 0; nt < 4; ++nt) {
        float s = 0.f;
#pragma unroll
        for (int mt = 0; mt < 4; ++mt) {
            f32x4 a = acc[mt][nt];
            s += (a[0]*a[0] + a[1]*a[1]) + (a[2]*a[2] + a[3]*a[3]);
        }
        s += __shfl_xor(s, 16);
        s += __shfl_xor(s, 32);
        sc[nt] = 1.0f / fmaxf(sqrtf(s), 1e-12f);
    }

#pragma unroll
    for (int nt = 0; nt < 4; ++nt) {
        int n = nB + wn * 64 + nt * 16 + l15;
#pragma unroll
        for (int mt = 0; mt < 4; ++mt) {
            int o = oB + wm * 64 + mt * 16 + 4 * g;
            f32x4 v = acc[mt][nt];
            *(unsigned long long*)(out + (size_t)n * kHID + o) =
                pk4(v[0]*sc[nt], v[1]*sc[nt], v[2]*sc[nt], v[3]*sc[nt]);
        }
    }

    float sred[4][4] = {};
#pragma unroll
    for (int nt = 0; nt < 4; ++nt)
#pragma unroll
        for (int mt = 0; mt < 4; ++mt) {
            f32x4 a = acc[mt][nt];
            sred[mt][0] += a[0] * sc[nt];
            sred[mt][1] += a[1] * sc[nt];
            sred[mt][2] += a[2] * sc[nt];
            sred[mt][3] += a[3] * sc[nt];
        }
#pragma unroll
    for (int off = 1; off < 16; off <<= 1)
#pragma unroll
        for (int mt = 0; mt < 4; ++mt)
#pragma unroll
            for (int r = 0; r < 4; ++r)
                sred[mt][r] += __shfl_xor(sred[mt][r], off);
    if (l15 == 0)
#pragma unroll
        for (int mt = 0; mt < 4; ++mt)
#pragma unroll
            for (int r = 0; r < 4; ++r)
                rbuf[wm][wn][g][mt][r] = sred[mt][r];
    __syncthreads();
    if (threadIdx.x < 128) {
        int wm2 = threadIdx.x >> 6;
        int o = threadIdx.x & 63;
        int mt2 = o >> 4, g2 = (o >> 2) & 3, r2 = o & 3;
        float v = rbuf[wm2][0][g2][mt2][r2] + rbuf[wm2][1][g2][mt2][r2];
        int row = (nB & (kHW - 1)) >> 7;
        int b = nB >> 14;
        int bh = b * 8 + hp * 2 + wm2;
        red_out[((size_t)(bh * 128 + row)) * 64 + o] = v;
    }
}

// dwconv body (bf16 in -> bf16 out), id over kN*48
__device__ void dwconv_body(int idx, const unsigned short* __restrict__ in,
                            unsigned short* __restrict__ out,
                            const float* __restrict__ wt, const float* __restrict__ bias)
{
    int n = idx / 48;
    int c0 = (idx - n * 48) * 4;
    int hw = n & (kHW - 1);
    int h = hw >> 7, ww = hw & 127;
    f32x4 s = *(const f32x4*)(bias + c0);
#pragma unroll
    for (int dy = -1; dy <= 1; ++dy) {
        int hh = h + dy;
        if (hh < 0 || hh >= kH) continue;
#pragma unroll
        for (int dx = -1; dx <= 1; ++dx) {
            int wx = ww + dx;
            if (wx < 0 || wx >= kW) continue;
            f32x4 v = ubf4(*(const unsigned long long*)(in + (size_t)(n + dy * kW + dx) * kC + c0));
            int t = (dy + 1) * 3 + (dx + 1);
            s[0] += v[0] * wt[(c0 + 0) * 9 + t];
            s[1] += v[1] * wt[(c0 + 1) * 9 + t];
            s[2] += v[2] * wt[(c0 + 2) * 9 + t];
            s[3] += v[3] * wt[(c0 + 3) * 9 + t];
        }
    }
    *(unsigned long long*)(out + (size_t)n * kC + c0) = pk4(s[0], s[1], s[2], s[3]);
}

// ---------------------------------------------------------------------------
// Merged launch: [0,2048) q/k projections; [2048,8192) local dwconv.
// dwconv blocks (memory-bound, low VGPR need) fill qk latency gaps.
// ---------------------------------------------------------------------------
__global__ __launch_bounds__(256) void qkdw_kernel(
    const unsigned short* __restrict__ wqb, const unsigned short* __restrict__ wkb,
    const unsigned short* __restrict__ xnb, const unsigned short* __restrict__ xpb,
    unsigned short* __restrict__ qpb, unsigned short* __restrict__ kpb,
    float* __restrict__ qpart, float* __restrict__ ksum_h,
    unsigned short* __restrict__ lb,
    const float* __restrict__ dw_w, const float* __restrict__ dw_b)
{
    int id = blockIdx.x;
    if (id < 2048) {
        qk_proj_body(id & 255, (id >> 8) & 3, id >> 10, wqb, wkb, xnb,
                     qpb, kpb, qpart, ksum_h);
    } else {
        dwconv_body((id - 2048) * 256 + threadIdx.x, xpb, lb, dw_w, dw_b);
    }
}

// ksum_w[bh][w][hc] = sum_h k.  256 threads: 4 h-segments of 32 + LDS reduce.
__global__ void sum_h_kernel(const unsigned short* __restrict__ buf, float* __restrict__ out)
{
    __shared__ float red[4][64];
    int w = blockIdx.x, bh = blockIdx.y;
    int hc = threadIdx.x & 63, seg = threadIdx.x >> 6;
    int b = bh >> 3, nh = bh & 7;
    const unsigned short* p = buf + (size_t)(b * kHW + seg * 32 * kW + w) * kHID + nh * kHC + hc;
    float s = 0.f;
    for (int h = 0; h < 32; ++h) s += bf2f(p[(size_t)h * kW * kHID]);
    red[seg][hc] = s;
    __syncthreads();
    if (threadIdx.x < 64)
        out[((size_t)bh * kW + w) * kHC + threadIdx.x] =
            red[0][threadIdx.x] + red[1][threadIdx.x] + red[2][threadIdx.x] + red[3][threadIdx.x];
}

// ---------------------------------------------------------------------------
// c1/c2 GEMM: bf16 out [n][192] + bias + fused instance-norm partial stats.
// ---------------------------------------------------------------------------
__global__ __launch_bounds__(256) void mgemm_is_kernel(
    const unsigned short* __restrict__ A, const unsigned short* __restrict__ B,
    unsigned short* __restrict__ out, const float* __restrict__ bias,
    float* __restrict__ accp)
{
    __shared__ float sa[2][64], qa[2][64];
    int nB = blockIdx.x * 128, oB = blockIdx.y * 64;
    int w = threadIdx.x >> 6, lane = threadIdx.x & 63;
    int l15 = lane & 15, g = lane >> 4;
    int wm = w & 1, wn = w >> 1;

    f32x4 acc[2][4];
#pragma unroll
    for (int mt = 0; mt < 2; ++mt)
#pragma unroll
        for (int nt = 0; nt < 4; ++nt) acc[mt][nt] = (f32x4){0.f,0.f,0.f,0.f};

    MGEMM_CORE(192, A + (size_t)(oB + wm * 32 + l15) * 192 + 8 * g,
                    B + (size_t)(nB + wn * 64 + l15) * 192 + 8 * g);

    f32x4 vv[2][4];
#pragma unroll
    for (int mt = 0; mt < 2; ++mt)
#pragma unroll
        for (int nt = 0; nt < 4; ++nt) {
            int o = oB + wm * 32 + mt * 16 + 4 * g;
            int n = nB + wn * 64 + nt * 16 + l15;
            f32x4 v = acc[mt][nt] + *(const f32x4*)(bias + o);
            vv[mt][nt] = v;
            *(unsigned long long*)(out + (size_t)n * kC + o) = pk4(v[0], v[1], v[2], v[3]);
        }
    float s2[2][4] = {}, q2[2][4] = {};
#pragma unroll
    for (int mt = 0; mt < 2; ++mt)
#pragma unroll
        for (int nt = 0; nt < 4; ++nt)
#pragma unroll
            for (int r = 0; r < 4; ++r) {
                float v = vv[mt][nt][r];
                s2[mt][r] += v; q2[mt][r] += v * v;
            }
#pragma unroll
    for (int off = 1; off < 16; off <<= 1)
#pragma unroll
        for (int mt = 0; mt < 2; ++mt)
#pragma unroll
            for (int r = 0; r < 4; ++r) {
                s2[mt][r] += __shfl_xor(s2[mt][r], off);
                q2[mt][r] += __shfl_xor(q2[mt][r], off);
            }
    if (l15 == 0)
#pragma unroll
        for (int mt = 0; mt < 2; ++mt)
#pragma unroll
            for (int r = 0; r < 4; ++r) {
                int ol = wm * 32 + mt * 16 + 4 * g + r;
                sa[wn][ol] = s2[mt][r];
                qa[wn][ol] = q2[mt][r];
            }
    __syncthreads();
    if (threadIdx.x < 128) {
        int ol = threadIdx.x & 63, st = threadIdx.x >> 6;
        float v = st ? (qa[0][ol] + qa[1][ol]) : (sa[0][ol] + sa[1][ol]);
        int b = nB >> 14;
        atomicAdd(&accp[(size_t)(b * kC + oB + ol) * 2 + st], v);
    }
}

// ---------------------------------------------------------------------------
// Fused MLP + ln2: per-block BM=192 (ALL output channels) x BN=128 pixels,
// 6 waves (3 o-tiles x 2 n-halves). F = w1@LB + W2'@OB + bp2 + x is never
// materialized; per-pixel LN over 192 channels via intra-wave reduce + LDS
// over the 3 o-waves; writes Y1 (bf16 [n][192]) directly.
// ---------------------------------------------------------------------------
__global__ __launch_bounds__(384) void mgemm_mlp_ln_kernel(
    const unsigned short* __restrict__ A1, const unsigned short* __restrict__ B1,
    const unsigned short* __restrict__ A2, const unsigned short* __restrict__ B2,
    unsigned short* __restrict__ out, const float* __restrict__ bp2,
    const unsigned short* __restrict__ res,
    const float* __restrict__ lng, const float* __restrict__ lnb)
{
    __shared__ float lnS[3][2][4][16], lnQ[3][2][4][16];
    int nB = blockIdx.x * 128;
    int w = threadIdx.x >> 6, lane = threadIdx.x & 63;
    int l15 = lane & 15, g = lane >> 4;
    int om = w >> 1, on = w & 1;            // om: o-tile 0..2, on: n-half 0..1
    int oB = om * 64;

    f32x4 acc[4][4];
#pragma unroll
    for (int mt = 0; mt < 4; ++mt)
#pragma unroll
        for (int nt = 0; nt < 4; ++nt) acc[mt][nt] = (f32x4){0.f,0.f,0.f,0.f};

    {
        const unsigned short* Ap = A1 + (size_t)(oB + l15) * 192 + 8 * g;
        const unsigned short* Bp = B1 + (size_t)(nB + on * 64 + l15) * 192 + 8 * g;
#pragma unroll 2
        for (int k = 0; k < 192; k += 32) {
            bf16x8 a[4], bb[4];
#pragma unroll
            for (int mt = 0; mt < 4; ++mt) a[mt] = *(const bf16x8*)(Ap + (size_t)mt * 16 * 192 + k);
#pragma unroll
            for (int nt = 0; nt < 4; ++nt) bb[nt] = *(const bf16x8*)(Bp + (size_t)nt * 16 * 192 + k);
#pragma unroll
            for (int mt = 0; mt < 4; ++mt)
#pragma unroll
                for (int nt = 0; nt < 4; ++nt)
                    acc[mt][nt] = __builtin_amdgcn_mfma_f32_16x16x32_bf16(a[mt], bb[nt], acc[mt][nt], 0, 0, 0);
        }
    }
    {
        const unsigned short* Ap = A2 + (size_t)(oB + l15) * 512 + 8 * g;
        const unsigned short* Bp = B2 + (size_t)(nB + on * 64 + l15) * 512 + 8 * g;
#pragma unroll 2
        for (int k = 0; k < 512; k += 32) {
            bf16x8 a[4], bb[4];
#pragma unroll
            for (int mt = 0; mt < 4; ++mt) a[mt] = *(const bf16x8*)(Ap + (size_t)mt * 16 * 512 + k);
#pragma unroll
            for (int nt = 0; nt < 4; ++nt) bb[nt] = *(const bf16x8*)(Bp + (size_t)nt * 16 * 512 + k);
#pragma unroll
            for (int mt = 0; mt < 4; ++mt)
#pragma unroll
                for (int nt = 0; nt < 4; ++nt)
                    acc[mt][nt] = __builtin_amdgcn_mfma_f32_16x16x32_bf16(a[mt], bb[nt], acc[mt][nt], 0, 0, 0);
        }
    }

    // finalize f = acc + bp2 + res (keep in acc); per-pixel partial LN sums
    float sp[4] = {}, sq[4] = {};
#pragma unroll
    for (int nt = 0; nt < 4; ++nt) {
        int n = nB + on * 64 + nt * 16 + l15;
#pragma unroll
        for (int mt = 0; mt < 4; ++mt) {
            int o = oB + mt * 16 + 4 * g;
            f32x4 v = acc[mt][nt];
            v[0] += bp2[o]; v[1] += bp2[o+1]; v[2] += bp2[o+2]; v[3] += bp2[o+3];
            v += ubf4(*(const unsigned long long*)(res + (size_t)n * kC + o));
            acc[mt][nt] = v;
            sp[nt] += (v[0] + v[1]) + (v[2] + v[3]);
            sq[nt] += (v[0]*v[0] + v[1]*v[1]) + (v[2]*v[2] + v[3]*v[3]);
        }
    }
#pragma unroll
    for (int nt = 0; nt < 4; ++nt) {
        sp[nt] += __shfl_xor(sp[nt], 16);
        sp[nt] += __shfl_xor(sp[nt], 32);
        sq[nt] += __shfl_xor(sq[nt], 16);
        sq[nt] += __shfl_xor(sq[nt], 32);
    }
    if (g == 0)
#pragma unroll
        for (int nt = 0; nt < 4; ++nt) {
            lnS[om][on][nt][l15] = sp[nt];
            lnQ[om][on][nt][l15] = sq[nt];
        }
    __syncthreads();

#pragma unroll
    for (int nt = 0; nt < 4; ++nt) {
        float S = lnS[0][on][nt][l15] + lnS[1][on][nt][l15] + lnS[2][on][nt][l15];
        float Q = lnQ[0][on][nt][l15] + lnQ[1][on][nt][l15] + lnQ[2][on][nt][l15];
        float m = S * (1.0f / kC);
        float var = Q * (1.0f / kC) - m * m;
        float rs = rsqrtf(var + kEPS);
        int n = nB + on * 64 + nt * 16 + l15;
#pragma unroll
        for (int mt = 0; mt < 4; ++mt) {
            int o = oB + mt * 16 + 4 * g;
            f32x4 v = acc[mt][nt];
            f32x4 gg = *(const f32x4*)(lng + o);
            f32x4 bv = *(const f32x4*)(lnb + o);
            *(unsigned long long*)(out + (size_t)n * kC + o) =
                pk4((v[0]-m)*rs*gg[0] + bv[0], (v[1]-m)*rs*gg[1] + bv[1],
                    (v[2]-m)*rs*gg[2] + bv[2], (v[3]-m)*rs*gg[3] + bv[3]);
        }
    }
}

// ---------------------------------------------------------------------------
// Fused qs-reduce + scores + top-16 (tie -> lower index).
// ---------------------------------------------------------------------------
__global__ void score_topk_kernel(const float* __restrict__ qpart,
                                  const float* __restrict__ ksum_h,
                                  const float* __restrict__ ksum_w,
                                  int* __restrict__ hidx, int* __restrict__ widx)
{
    __shared__ float qsl[2][64];
    __shared__ float hs[128], ws[128];
    int bh = blockIdx.x;
    int tid = threadIdx.x;               // 128
    int hc = tid & 63, grp = tid >> 6;
    {
        const float* qp = qpart + ((size_t)bh * 128 + grp * 64) * 64 + hc;
        float s = 0.f;
        for (int i = 0; i < 64; ++i) s += qp[(size_t)i * 64];
        qsl[grp][hc] = s;
    }
    __syncthreads();
    if (tid < 64) qsl[0][tid] += qsl[1][tid];
    __syncthreads();
    {
        const float* kh = ksum_h + ((size_t)bh * 128 + tid) * 64;
        const float* kw = ksum_w + ((size_t)bh * 128 + tid) * 64;
        float sh = 0.f, sw = 0.f;
        for (int c = 0; c < 64; ++c) {
            float q = qsl[0][c];
            sh += q * kh[c];
            sw += q * kw[c];
        }
        hs[tid] = sh; ws[tid] = sw;
    }
    __syncthreads();
    int sel = tid >> 6;
    const float* sc = sel ? ws : hs;
    int* out = (sel ? widx : hidx) + bh * kP;
    int lane = tid & 63;
    float v0 = sc[lane], v1 = sc[lane + 64];
    int i0 = lane, i1 = lane + 64;
    for (int p = 0; p < kP; ++p) {
        float bv; int bi;
        if (v1 > v0) { bv = v1; bi = i1; } else { bv = v0; bi = i0; }
#pragma unroll
        for (int off = 1; off < 64; off <<= 1) {
            float ov = __shfl_xor(bv, off);
            int   oi = __shfl_xor(bi, off);
            if (ov > bv || (ov == bv && oi < bi)) { bv = ov; bi = oi; }
        }
        if (lane == 0) out[p] = bi;
        if (i0 == bi) v0 = -INFINITY;
        if (i1 == bi) v1 = -INFINITY;
    }
}

// ---------------------------------------------------------------------------
// Gather kf from dense KPb; lazy-project vfT.
// ---------------------------------------------------------------------------
__global__ void gather_kv_kernel(const unsigned short* __restrict__ kpb,
                                 const unsigned short* __restrict__ xnb,
                                 const float* __restrict__ wv,
                                 const int* __restrict__ hidx, const int* __restrict__ widx,
                                 unsigned short* __restrict__ kf, unsigned short* __restrict__ vfT)
{
    int bh = blockIdx.y, p1 = blockIdx.x;
    int b = bh >> 3, nh = bh & 7;
    int hc = threadIdx.x & 63, pg = threadIdx.x >> 6;
    int hrow = hidx[bh * kP + p1];
    int o = nh * kHC + hc;
    const float* wvp = wv + (size_t)o * kC;
    for (int p2 = pg; p2 < kP; p2 += 4) {
        int wcol = widx[bh * kP + p2];
        int n = b * kHW + hrow * kW + wcol;
        int kidx = p1 * kP + p2;
        kf[((size_t)bh * 256 + kidx) * 64 + hc] = kpb[(size_t)n * kHID + nh * kHC + hc];
        const unsigned int* xr = (const unsigned int*)(xnb + (size_t)n * kC);
        float s = 0.f;
        for (int c2 = 0; c2 < kC / 2; ++c2) {
            unsigned int u = xr[c2];
            s += wvp[c2 * 2]     * bf2f((unsigned short)(u & 0xffff));
            s += wvp[c2 * 2 + 1] * bf2f((unsigned short)(u >> 16));
        }
        vfT[((size_t)bh * 64 + hc) * 256 + kidx] = f2bf(s);
    }
}

// ---------------------------------------------------------------------------
// MFMA attention, QBLK=128: kf fragments loaded once, reused for 2 q-subtiles.
// P in LDS stride-256 + XOR swizzle (conflict-free).
// ---------------------------------------------------------------------------
__global__ __launch_bounds__(256) void attn_kernel(
    const unsigned short* __restrict__ qpb, unsigned short* __restrict__ ob,
    const unsigned short* __restrict__ kf, const unsigned short* __restrict__ vfT)
{
    __shared__ unsigned short pls[64 * 256];
    __shared__ float lred[4][4][16];

    int bh = blockIdx.y; int b = bh >> 3, nh = bh & 7;
    int nbase = b * kHW + blockIdx.x * 128;
    int tid = threadIdx.x;
    int w = tid >> 6, lane = tid & 63, l15 = lane & 15, g = lane >> 4;

    const unsigned short* kfb = kf + (size_t)bh * 256 * 64;
    bf16x8 ak[4][2];
#pragma unroll
    for (int mt = 0; mt < 4; ++mt)
#pragma unroll
        for (int kt = 0; kt < 2; ++kt)
            ak[mt][kt] = *(const bf16x8*)&kfb[(size_t)(w * 64 + mt * 16 + l15) * 64 + kt * 32 + 8 * g];

    const unsigned short* vfb = vfT + (size_t)bh * 64 * 256;

#pragma unroll
    for (int sub = 0; sub < 2; ++sub) {
        int n0 = nbase + sub * 64;
        bf16x8 bq[4][2];
#pragma unroll
        for (int nt = 0; nt < 4; ++nt)
#pragma unroll
            for (int kt = 0; kt < 2; ++kt)
                bq[nt][kt] = *(const bf16x8*)(qpb + (size_t)(n0 + nt * 16 + l15) * kHID
                                              + nh * kHC + kt * 32 + 8 * g);

        f32x4 acc[4][4];
#pragma unroll
        for (int mt = 0; mt < 4; ++mt)
#pragma unroll
            for (int nt = 0; nt < 4; ++nt) acc[mt][nt] = (f32x4){0.f,0.f,0.f,0.f};

#pragma unroll
        for (int kt = 0; kt < 2; ++kt)
#pragma unroll
            for (int mt = 0; mt < 4; ++mt)
#pragma unroll
                for (int nt = 0; nt < 4; ++nt)
                    acc[mt][nt] = __builtin_amdgcn_mfma_f32_16x16x32_bf16(
                        ak[mt][kt], bq[nt][kt], acc[mt][nt], 0, 0, 0);

        if (sub) __syncthreads();

        float lpart[4] = {0.f, 0.f, 0.f, 0.f};
#pragma unroll
        for (int mt = 0; mt < 4; ++mt)
#pragma unroll
            for (int nt = 0; nt < 4; ++nt) {
                float e0 = __expf(acc[mt][nt][0]);
                float e1 = __expf(acc[mt][nt][1]);
                float e2 = __expf(acc[mt][nt][2]);
                float e3 = __expf(acc[mt][nt][3]);
                lpart[nt] += (e0 + e1) + (e2 + e3);
                int qq = nt * 16 + l15;
                int k0 = w * 64 + mt * 16 + 4 * g;
                int kx = k0 ^ ((qq & 7) << 3);
                *(unsigned long long*)&pls[qq * 256 + kx] = pk4(e0, e1, e2, e3);
            }
#pragma unroll
        for (int nt = 0; nt < 4; ++nt) {
            lpart[nt] += __shfl_xor(lpart[nt], 16);
            lpart[nt] += __shfl_xor(lpart[nt], 32);
        }
        if (g == 0)
#pragma unroll
            for (int nt = 0; nt < 4; ++nt) lred[w][nt][l15] = lpart[nt];
        __syncthreads();

        f32x4 oacc[4];
#pragma unroll
        for (int nt = 0; nt < 4; ++nt) oacc[nt] = (f32x4){0.f,0.f,0.f,0.f};

#pragma unroll
        for (int ks = 0; ks < 8; ++ks) {
            bf16x8 av = *(const bf16x8*)&vfb[(size_t)(w * 16 + l15) * 256 + ks * 32 + 8 * g];
#pragma unroll
            for (int nt = 0; nt < 4; ++nt) {
                int qq = nt * 16 + l15;
                int kx = (ks * 32 + 8 * g) ^ ((qq & 7) << 3);
                bf16x8 bp = *(const bf16x8*)&pls[qq * 256 + kx];
                oacc[nt] = __builtin_amdgcn_mfma_f32_16x16x32_bf16(av, bp, oacc[nt], 0, 0, 0);
            }
        }

#pragma unroll
        for (int nt = 0; nt < 4; ++nt) {
            float l = lred[0][nt][l15] + lred[1][nt][l15] + lred[2][nt][l15] + lred[3][nt][l15];
            float inv = 1.0f / l;
            int qq = nt * 16 + l15;
            int hc0 = w * 16 + 4 * g;
            *(unsigned long long*)(ob + (size_t)(n0 + qq) * kHID + nh * kHC + hc0) =
                pk4(oacc[nt][0] * inv, oacc[nt][1] * inv, oacc[nt][2] * inv, oacc[nt][3] * inv);
        }
    }
}

// ---------------------------------------------------------------------------
// Depthwise 3x3 (standalone, for the res-branch).
// ---------------------------------------------------------------------------
__global__ void dwconv_pm_kernel(const unsigned short* __restrict__ in,
                                 unsigned short* __restrict__ out,
                                 const float* __restrict__ wt, const float* __restrict__ bias)
{
    dwconv_body(blockIdx.x * 256 + threadIdx.x, in, out, wt, bias);
}

// ---------------------------------------------------------------------------
// Instance-norm stats (bf16 input) via per-chunk atomics.
// ---------------------------------------------------------------------------
__global__ void istats_bf16_kernel(const unsigned short* __restrict__ in, float* __restrict__ acc)
{
    int n0 = blockIdx.x * 64;
    int b = n0 >> 14;
    int c = threadIdx.x;
    float s = 0.f, ss = 0.f;
    for (int p = 0; p < 64; ++p) {
        float v = bf2f(in[(size_t)(n0 + p) * kC + c]);
        s += v; ss += v * v;
    }
    atomicAdd(&acc[(size_t)(b * kC + c) * 2],     s);
    atomicAdd(&acc[(size_t)(b * kC + c) * 2 + 1], ss);
}

__device__ inline void inorm_ms(const float* acc, int b, int c, float& m, float& rs)
{
    float s  = acc[(size_t)(b * kC + c) * 2];
    float ss = acc[(size_t)(b * kC + c) * 2 + 1];
    m = s * (1.0f / kHW);
    float var = ss * (1.0f / kHW) - m * m;
    rs = rsqrtf(var + kEPS);
}

// MODE 0: gelu(inorm(in)) -> bf16.  MODE 1: gelu(inorm(in)) + add -> bf16.
template<int MODE>
__global__ void apply_pm_kernel(const unsigned short* __restrict__ in, const float* __restrict__ acc,
                                unsigned short* __restrict__ out, const unsigned short* __restrict__ addsrc)
{
    int idx = blockIdx.x * 256 + threadIdx.x;      // kN*48
    int n = idx / 48;
    int c0 = (idx - n * 48) * 4;
    int b = n >> 14;
    f32x4 v = ubf4(*(const unsigned long long*)(in + (size_t)n * kC + c0));
    f32x4 r;
#pragma unroll
    for (int j = 0; j < 4; ++j) {
        float m, rs;
        inorm_ms(acc, b, c0 + j, m, rs);
        float x = (v[j] - m) * rs;
        r[j] = gelu_f(x);
    }
    if (MODE == 1)
        r += ubf4(*(const unsigned long long*)(addsrc + (size_t)n * kC + c0));
    *(unsigned long long*)(out + (size_t)n * kC + c0) = pk4(r[0], r[1], r[2], r[3]);
}

// ---------------------------------------------------------------------------
// Final inorm via LDS transpose: bf16 pixel-major in -> NCHW fp32 d_out.
// ---------------------------------------------------------------------------
__global__ __launch_bounds__(256) void final_kernel(const unsigned short* __restrict__ in,
                                                    const float* __restrict__ acc,
                                                    float* __restrict__ out)
{
    __shared__ unsigned short tile[192][68];
    int n0 = blockIdx.x * 64;
    int b = n0 >> 14;
    int hw0 = n0 & (kHW - 1);
    int tid = threadIdx.x;
    for (int i = tid; i < 64 * 48; i += 256) {
        int p = i / 48, cq = i - p * 48;
        unsigned long long u = *(const unsigned long long*)(in + (size_t)(n0 + p) * kC + cq * 4);
        tile[cq * 4 + 0][p] = (unsigned short)u;
        tile[cq * 4 + 1][p] = (unsigned short)(u >> 16);
        tile[cq * 4 + 2][p] = (unsigned short)(u >> 32);
        tile[cq * 4 + 3][p] = (unsigned short)(u >> 48);
    }
    __syncthreads();
    for (int i = tid; i < 192 * 16; i += 256) {
        int c = i >> 4, grp = i & 15;
        float m, rs;
        inorm_ms(acc, b, c, m, rs);
        f32x4 o;
#pragma unroll
        for (int j = 0; j < 4; ++j)
            o[j] = (bf2f(tile[c][grp * 4 + j]) - m) * rs;
        *(f32x4*)(out + (size_t)(b * kC + c) * kHW + hw0 + grp * 4) = o;
    }
}

// ---------------------------------------------------------------------------
extern "C" void kernel_launch(void* const* d_in, const int* in_sizes, int n_in,
                              void* d_out, int out_size, void* d_ws, size_t ws_size,
                              hipStream_t stream)
{
    const float* x     = (const float*)d_in[0];
    const float* ln1_g = (const float*)d_in[1];
    const float* ln1_b = (const float*)d_in[2];
    const float* wq    = (const float*)d_in[3];
    const float* wk    = (const float*)d_in[4];
    const float* wv    = (const float*)d_in[5];
    const float* wo    = (const float*)d_in[6];
    const float* bo    = (const float*)d_in[7];
    const float* dw_w  = (const float*)d_in[8];
    const float* dw_b  = (const float*)d_in[9];
    const float* mlp_w = (const float*)d_in[10];
    const float* mlp_b = (const float*)d_in[11];
    const float* ln2_g = (const float*)d_in[12];
    const float* ln2_b = (const float*)d_in[13];
    const float* c1_w  = (const float*)d_in[14];
    const float* c1_b  = (const float*)d_in[15];
    const float* res_w = (const float*)d_in[16];
    const float* res_b = (const float*)d_in[17];
    const float* c2_w  = (const float*)d_in[18];
    const float* c2_b  = (const float*)d_in[19];

    char* base = (char*)d_ws;
    unsigned short* XPb = (unsigned short*)(base);               // bf16 [n][192] raw x
    unsigned short* XNb = (unsigned short*)(base + 25165824);    // bf16 [n][192] xn / Y1
    unsigned short* QPb = (unsigned short*)(base + 37748736);    // bf16 [n][512]; later T2
    unsigned short* T2  = QPb;
    unsigned short* KPb = (unsigned short*)(base + 71303168);    // bf16 [n][512]; OB alias; later Y2
    unsigned short* OB  = KPb;
    unsigned short* Y2  = KPb;
    unsigned short* LB  = (unsigned short*)(base + 104857600);   // bf16 [n][192] local; later Y3
    unsigned short* Y3  = LB;
    unsigned short* T1  = (unsigned short*)(base + 117440512);   // bf16 [n][192]; later R
    unsigned short* R   = T1;
    char* sm = base + 130023424;
    float* qpart  = (float*)(sm);                 sm += 524288;   // [16][128][64]
    float* ksum_h = (float*)(sm);                 sm += 524288;
    float* ksum_w = (float*)(sm);                 sm += 524288;
    float* acc0   = (float*)(sm);                 sm += 3072;     // zero block (2304 floats)
    float* acc1   = (float*)(sm);                 sm += 3072;
    float* acc2   = (float*)(sm);                 sm += 3072;
    unsigned short* kf   = (unsigned short*)(sm); sm += 524288;
    unsigned short* vfT  = (unsigned short*)(sm); sm += 524288;
    unsigned short* wqb  = (unsigned short*)(sm); sm += 196608;
    unsigned short* wkb  = (unsigned short*)(sm); sm += 196608;
    unsigned short* mlpb1= (unsigned short*)(sm); sm += 73728;
    unsigned short* c1b  = (unsigned short*)(sm); sm += 73728;
    unsigned short* c2b  = (unsigned short*)(sm); sm += 73728;
    unsigned short* w2pb = (unsigned short*)(sm); sm += 196608;
    float* bp2 = (float*)(sm);                    sm += 1024;
    int* hidx = (int*)(sm);                       sm += 1024;
    int* widx = (int*)(sm);

    // 1. prep
    prep_kernel<<<1593, 256, 0, stream>>>(acc0, wq, wk, mlp_w, c1_w, c2_w,
                                          wo, mlp_b, bo,
                                          wqb, wkb, mlpb1, c1b, c2b, w2pb, bp2);
    // 2. transpose + ln1
    txln_kernel<<<dim3(kHW / 64, kB), 256, 0, stream>>>(x, XPb, XNb, ln1_g, ln1_b);
    // 3. merged q/k projections + local dwconv
    qkdw_kernel<<<8192, 256, 0, stream>>>(wqb, wkb, XNb, XPb, QPb, KPb,
                                          qpart, ksum_h, LB, dw_w, dw_b);
    // 4. ksum_w
    sum_h_kernel<<<dim3(kW, 16), 256, 0, stream>>>(KPb, ksum_w);
    // 5. scores + top-16
    score_topk_kernel<<<16, 128, 0, stream>>>(qpart, ksum_h, ksum_w, hidx, widx);
    // 6. gather: kf copy + lazy vfT
    gather_kv_kernel<<<dim3(kP, 16), 256, 0, stream>>>(KPb, XNb, wv, hidx, widx, kf, vfT);
    // 7. attention (QBLK=128; OB overwrites KPb)
    attn_kernel<<<dim3(kHW / 128, 16), 256, 0, stream>>>(QPb, OB, kf, vfT);
    // 8. fused mlp + ln2 -> Y1 (XNb); F never materialized
    mgemm_mlp_ln_kernel<<<kN / 128, 384, 0, stream>>>(mlpb1, LB, w2pb, OB, XNb, bp2, XPb,
                                                      ln2_g, ln2_b);
    // 9. c1 GEMM + istats(acc0)
    mgemm_is_kernel<<<dim3(kN / 128, kC / 64), 256, 0, stream>>>(c1b, XNb, T1, c1_b, acc0);
    // 10. Y2 = gelu(inorm(T1))  (OB region dead)
    apply_pm_kernel<0><<<(kN * 48) / 256, 256, 0, stream>>>(T1, acc0, Y2, nullptr);
    // 11. res dwconv: R = dwconv(Y2)  (overwrites T1)
    dwconv_pm_kernel<<<(kN * 48) / 256, 256, 0, stream>>>(Y2, R, res_w, res_b);
    // 12. istats(R) -> acc1
    istats_bf16_kernel<<<kN / 64, 192, 0, stream>>>(R, acc1);
    // 13. Y3 = gelu(inorm(R)) + Y2
    apply_pm_kernel<1><<<(kN * 48) / 256, 256, 0, stream>>>(R, acc1, Y3, Y2);
    // 14. c2 GEMM + istats(acc2)
    mgemm_is_kernel<<<dim3(kN / 128, kC / 64), 256, 0, stream>>>(c2b, Y3, T2, c2_b, acc2);
    // 15. final inorm -> d_out
    final_kernel<<<kN / 64, 256, 0, stream>>>(T2, acc2, (float*)d_out);
}

// Round 14
// 449.078 us; speedup vs baseline: 1.5506x; 1.0060x over previous
//
#include <hip/hip_runtime.h>
#include <math.h>

constexpr int kC   = 192;
constexpr int kNH  = 8;
constexpr int kHC  = 64;
constexpr int kHID = 512;
constexpr int kP   = 16;
constexpr int kB   = 2;
constexpr int kH   = 128;
constexpr int kW   = 128;
constexpr int kHW  = kH * kW;      // 16384
constexpr int kN   = kB * kHW;     // 32768
constexpr float kEPS = 1e-5f;

typedef __attribute__((ext_vector_type(8))) short bf16x8;
typedef __attribute__((ext_vector_type(4))) float f32x4;

__device__ inline unsigned short f2bf(float f) {
    unsigned int u = __builtin_bit_cast(unsigned int, f);
    unsigned int r = (u + 0x7FFFu + ((u >> 16) & 1u)) >> 16;   // RNE
    return (unsigned short)r;
}
__device__ inline float bf2f(unsigned short u) {
    return __builtin_bit_cast(float, (unsigned int)u << 16);
}
__device__ inline unsigned int cvtpk(float lo, float hi) {
    unsigned int r;
    asm("v_cvt_pk_bf16_f32 %0, %1, %2" : "=v"(r) : "v"(lo), "v"(hi));
    return r;
}
__device__ inline unsigned long long pk4(float a, float b, float c, float d) {
    return (unsigned long long)cvtpk(a, b) | ((unsigned long long)cvtpk(c, d) << 32);
}
__device__ inline f32x4 ubf4(unsigned long long u) {
    f32x4 r;
    r[0] = bf2f((unsigned short)u);
    r[1] = bf2f((unsigned short)(u >> 16));
    r[2] = bf2f((unsigned short)(u >> 32));
    r[3] = bf2f((unsigned short)(u >> 48));
    return r;
}
__device__ inline float gelu_f(float x) {
    return 0.5f * x * (1.0f + erff(x * 0.70710678118654752f));
}

// ---------------------------------------------------------------------------
// Prep: zero acc0..2 + bf16 weight cvts + fused W2' weight.
// ---------------------------------------------------------------------------
__global__ void prep_kernel(float* __restrict__ zbase,
                            const float* wq, const float* wk, const float* wm,
                            const float* c1, const float* c2,
                            const float* wo, const float* mlp_b, const float* bo,
                            unsigned short* wqb, unsigned short* wkb,
                            unsigned short* mlpb1, unsigned short* c1b, unsigned short* c2b,
                            unsigned short* w2pb, float* bp2)
{
    int i = blockIdx.x * 256 + threadIdx.x;
    if (i < 2304) { zbase[i] = 0.f; return; }            // acc0..2
    i -= 2304;
    if (i < 98304) { wqb[i] = f2bf(wq[i]); return; }
    i -= 98304;
    if (i < 98304) { wkb[i] = f2bf(wk[i]); return; }
    i -= 98304;
    if (i < 36864) { int o = i / 192, k = i - o * 192; mlpb1[i] = f2bf(wm[o * 384 + k]); return; }
    i -= 36864;
    if (i < 36864) { c1b[i] = f2bf(c1[i]); return; }
    i -= 36864;
    if (i < 36864) { c2b[i] = f2bf(c2[i]); return; }
    i -= 36864;
    if (i < 98304) {
        int o = i >> 9, j = i & 511;
        const float* a = wm + o * 384 + 192;
        float s = 0.f;
        for (int c = 0; c < 192; ++c) s += a[c] * wo[c * 512 + j];
        w2pb[o * 512 + j] = f2bf(s);
        if (j == 0) {
            float t = mlp_b[o];
            for (int c = 0; c < 192; ++c) t += a[c] * bo[c];
            bp2[o] = t;
        }
    }
}

// ---------------------------------------------------------------------------
// Fused transpose + ln1: x NCHW fp32 -> XPb raw bf16 [n][192] + XNb bf16.
// ---------------------------------------------------------------------------
__global__ __launch_bounds__(256) void txln_kernel(const float* __restrict__ x,
                                                   unsigned short* __restrict__ xpb,
                                                   unsigned short* __restrict__ xnb,
                                                   const float* __restrict__ g,
                                                   const float* __restrict__ bb)
{
    __shared__ float tile[192][65];
    __shared__ float red[2][4][64];
    __shared__ float pms[64], prs[64];
    int hw0 = blockIdx.x * 64;
    int b   = blockIdx.y;
    int tid = threadIdx.x;
    for (int i = tid; i < 192 * 64; i += 256) {
        int c = i >> 6, p = i & 63;
        tile[c][p] = x[(size_t)(b * kC + c) * kHW + hw0 + p];
    }
    __syncthreads();
    {
        int p = tid & 63, qt = tid >> 6;
        float s = 0.f, ss = 0.f;
        for (int c = qt * 48; c < qt * 48 + 48; ++c) {
            float v = tile[c][p]; s += v; ss += v * v;
        }
        red[0][qt][p] = s; red[1][qt][p] = ss;
    }
    __syncthreads();
    if (tid < 64) {
        float s  = red[0][0][tid] + red[0][1][tid] + red[0][2][tid] + red[0][3][tid];
        float ss = red[1][0][tid] + red[1][1][tid] + red[1][2][tid] + red[1][3][tid];
        float m = s * (1.0f / kC);
        float var = ss * (1.0f / kC) - m * m;
        pms[tid] = m;
        prs[tid] = rsqrtf(var + kEPS);
    }
    __syncthreads();
    for (int i = tid; i < 64 * 192; i += 256) {
        int p = i / 192, c = i - p * 192;
        float raw = tile[c][p];
        size_t oi = (size_t)(b * kHW + hw0 + p) * kC + c;
        xpb[oi] = f2bf(raw);
        xnb[oi] = f2bf((raw - pms[p]) * prs[p] * g[c] + bb[c]);
    }
}

#define MGEMM_CORE(KVAL, APTR, BPTR)                                              \
    {                                                                             \
        const unsigned short* Ap = APTR;                                          \
        const unsigned short* Bp = BPTR;                                          \
        _Pragma("unroll 2")                                                       \
        for (int k = 0; k < KVAL; k += 32) {                                      \
            bf16x8 a0 = *(const bf16x8*)(Ap + k);                                 \
            bf16x8 a1 = *(const bf16x8*)(Ap + (size_t)16 * KVAL + k);             \
            bf16x8 b0 = *(const bf16x8*)(Bp + k);                                 \
            bf16x8 b1 = *(const bf16x8*)(Bp + (size_t)16 * KVAL + k);             \
            bf16x8 b2 = *(const bf16x8*)(Bp + (size_t)32 * KVAL + k);             \
            bf16x8 b3 = *(const bf16x8*)(Bp + (size_t)48 * KVAL + k);             \
            acc[0][0] = __builtin_amdgcn_mfma_f32_16x16x32_bf16(a0, b0, acc[0][0], 0, 0, 0); \
            acc[0][1] = __builtin_amdgcn_mfma_f32_16x16x32_bf16(a0, b1, acc[0][1], 0, 0, 0); \
            acc[0][2] = __builtin_amdgcn_mfma_f32_16x16x32_bf16(a0, b2, acc[0][2], 0, 0, 0); \
            acc[0][3] = __builtin_amdgcn_mfma_f32_16x16x32_bf16(a0, b3, acc[0][3], 0, 0, 0); \
            acc[1][0] = __builtin_amdgcn_mfma_f32_16x16x32_bf16(a1, b0, acc[1][0], 0, 0, 0); \
            acc[1][1] = __builtin_amdgcn_mfma_f32_16x16x32_bf16(a1, b1, acc[1][1], 0, 0, 0); \
            acc[1][2] = __builtin_amdgcn_mfma_f32_16x16x32_bf16(a1, b2, acc[1][2], 0, 0, 0); \
            acc[1][3] = __builtin_amdgcn_mfma_f32_16x16x32_bf16(a1, b3, acc[1][3], 0, 0, 0); \
        }                                                                         \
    }

// ---------------------------------------------------------------------------
// q/k projection GEMM, BM=128 (2 heads), 4 waves each owning one full
// (head x 64n) tile. Per-head L2 norm intra-wave. Fused row-sum.
// Grid: (256 nblk, 4 headpair, 2 q/k).
// ---------------------------------------------------------------------------
__global__ __launch_bounds__(256) void qk_proj_kernel(
    const unsigned short* __restrict__ wqb, const unsigned short* __restrict__ wkb,
    const unsigned short* __restrict__ xnb,
    unsigned short* __restrict__ qpb, unsigned short* __restrict__ kpb,
    float* __restrict__ qpart, float* __restrict__ ksum_h)
{
    __shared__ float rbuf[2][2][4][4][4];   // [wm][wn][g][mt][r]
    int nB = blockIdx.x * 128;
    int hp = blockIdx.y;
    const unsigned short* A = blockIdx.z ? wkb : wqb;
    unsigned short* out = blockIdx.z ? kpb : qpb;
    float* red_out = blockIdx.z ? ksum_h : qpart;

    int w = threadIdx.x >> 6, lane = threadIdx.x & 63;
    int l15 = lane & 15, g = lane >> 4;
    int wm = w & 1, wn = w >> 1;
    int oB = hp * 128;

    const unsigned short* Ap = A + (size_t)(oB + wm * 64 + l15) * 192 + 8 * g;
    const unsigned short* Bp = xnb + (size_t)(nB + wn * 64 + l15) * 192 + 8 * g;

    f32x4 acc[4][4];
#pragma unroll
    for (int mt = 0; mt < 4; ++mt)
#pragma unroll
        for (int nt = 0; nt < 4; ++nt) acc[mt][nt] = (f32x4){0.f,0.f,0.f,0.f};

#pragma unroll 2
    for (int k = 0; k < 192; k += 32) {
        bf16x8 a[4], bb[4];
#pragma unroll
        for (int mt = 0; mt < 4; ++mt) a[mt] = *(const bf16x8*)(Ap + (size_t)mt * 16 * 192 + k);
#pragma unroll
        for (int nt = 0; nt < 4; ++nt) bb[nt] = *(const bf16x8*)(Bp + (size_t)nt * 16 * 192 + k);
#pragma unroll
        for (int mt = 0; mt < 4; ++mt)
#pragma unroll
            for (int nt = 0; nt < 4; ++nt)
                acc[mt][nt] = __builtin_amdgcn_mfma_f32_16x16x32_bf16(a[mt], bb[nt], acc[mt][nt], 0, 0, 0);
    }

    float sc[4];
#pragma unroll
    for (int nt = 0; nt < 4; ++nt) {
        float s = 0.f;
#pragma unroll
        for (int mt = 0; mt < 4; ++mt) {
            f32x4 a = acc[mt][nt];
            s += (a[0]*a[0] + a[1]*a[1]) + (a[2]*a[2] + a[3]*a[3]);
        }
        s += __shfl_xor(s, 16);
        s += __shfl_xor(s, 32);
        sc[nt] = 1.0f / fmaxf(sqrtf(s), 1e-12f);
    }

#pragma unroll
    for (int nt = 0; nt < 4; ++nt) {
        int n = nB + wn * 64 + nt * 16 + l15;
#pragma unroll
        for (int mt = 0; mt < 4; ++mt) {
            int o = oB + wm * 64 + mt * 16 + 4 * g;
            f32x4 v = acc[mt][nt];
            *(unsigned long long*)(out + (size_t)n * kHID + o) =
                pk4(v[0]*sc[nt], v[1]*sc[nt], v[2]*sc[nt], v[3]*sc[nt]);
        }
    }

    float sred[4][4] = {};
#pragma unroll
    for (int nt = 0; nt < 4; ++nt)
#pragma unroll
        for (int mt = 0; mt < 4; ++mt) {
            f32x4 a = acc[mt][nt];
            sred[mt][0] += a[0] * sc[nt];
            sred[mt][1] += a[1] * sc[nt];
            sred[mt][2] += a[2] * sc[nt];
            sred[mt][3] += a[3] * sc[nt];
        }
#pragma unroll
    for (int off = 1; off < 16; off <<= 1)
#pragma unroll
        for (int mt = 0; mt < 4; ++mt)
#pragma unroll
            for (int r = 0; r < 4; ++r)
                sred[mt][r] += __shfl_xor(sred[mt][r], off);
    if (l15 == 0)
#pragma unroll
        for (int mt = 0; mt < 4; ++mt)
#pragma unroll
            for (int r = 0; r < 4; ++r)
                rbuf[wm][wn][g][mt][r] = sred[mt][r];
    __syncthreads();
    if (threadIdx.x < 128) {
        int wm2 = threadIdx.x >> 6;
        int o = threadIdx.x & 63;
        int mt2 = o >> 4, g2 = (o >> 2) & 3, r2 = o & 3;
        float v = rbuf[wm2][0][g2][mt2][r2] + rbuf[wm2][1][g2][mt2][r2];
        int row = (nB & (kHW - 1)) >> 7;
        int b = nB >> 14;
        int bh = b * 8 + hp * 2 + wm2;
        red_out[((size_t)(bh * 128 + row)) * 64 + o] = v;
    }
}

// ---------------------------------------------------------------------------
// Depthwise 3x3 SAME conv, pixel-major bf16 in -> bf16 out [n][192].
// ---------------------------------------------------------------------------
__global__ void dwconv_pm_kernel(const unsigned short* __restrict__ in,
                                 unsigned short* __restrict__ out,
                                 const float* __restrict__ wt, const float* __restrict__ bias)
{
    int idx = blockIdx.x * 256 + threadIdx.x;      // kN*48
    int n = idx / 48;
    int c0 = (idx - n * 48) * 4;
    int hw = n & (kHW - 1);
    int h = hw >> 7, ww = hw & 127;
    f32x4 s = *(const f32x4*)(bias + c0);
#pragma unroll
    for (int dy = -1; dy <= 1; ++dy) {
        int hh = h + dy;
        if (hh < 0 || hh >= kH) continue;
#pragma unroll
        for (int dx = -1; dx <= 1; ++dx) {
            int wx = ww + dx;
            if (wx < 0 || wx >= kW) continue;
            f32x4 v = ubf4(*(const unsigned long long*)(in + (size_t)(n + dy * kW + dx) * kC + c0));
            int t = (dy + 1) * 3 + (dx + 1);
            s[0] += v[0] * wt[(c0 + 0) * 9 + t];
            s[1] += v[1] * wt[(c0 + 1) * 9 + t];
            s[2] += v[2] * wt[(c0 + 2) * 9 + t];
            s[3] += v[3] * wt[(c0 + 3) * 9 + t];
        }
    }
    *(unsigned long long*)(out + (size_t)n * kC + c0) = pk4(s[0], s[1], s[2], s[3]);
}

// ksum_w[bh][w][hc] = sum_h k.  256 threads: 4 h-segments of 32 + LDS reduce.
__global__ void sum_h_kernel(const unsigned short* __restrict__ buf, float* __restrict__ out)
{
    __shared__ float red[4][64];
    int w = blockIdx.x, bh = blockIdx.y;
    int hc = threadIdx.x & 63, seg = threadIdx.x >> 6;
    int b = bh >> 3, nh = bh & 7;
    const unsigned short* p = buf + (size_t)(b * kHW + seg * 32 * kW + w) * kHID + nh * kHC + hc;
    float s = 0.f;
    for (int h = 0; h < 32; ++h) s += bf2f(p[(size_t)h * kW * kHID]);
    red[seg][hc] = s;
    __syncthreads();
    if (threadIdx.x < 64)
        out[((size_t)bh * kW + w) * kHC + threadIdx.x] =
            red[0][threadIdx.x] + red[1][threadIdx.x] + red[2][threadIdx.x] + red[3][threadIdx.x];
}

// ---------------------------------------------------------------------------
// c1/c2 GEMM: bf16 out [n][192] + bias + fused instance-norm partial stats.
// ---------------------------------------------------------------------------
__global__ __launch_bounds__(256) void mgemm_is_kernel(
    const unsigned short* __restrict__ A, const unsigned short* __restrict__ B,
    unsigned short* __restrict__ out, const float* __restrict__ bias,
    float* __restrict__ accp)
{
    __shared__ float sa[2][64], qa[2][64];
    int nB = blockIdx.x * 128, oB = blockIdx.y * 64;
    int w = threadIdx.x >> 6, lane = threadIdx.x & 63;
    int l15 = lane & 15, g = lane >> 4;
    int wm = w & 1, wn = w >> 1;

    f32x4 acc[2][4];
#pragma unroll
    for (int mt = 0; mt < 2; ++mt)
#pragma unroll
        for (int nt = 0; nt < 4; ++nt) acc[mt][nt] = (f32x4){0.f,0.f,0.f,0.f};

    MGEMM_CORE(192, A + (size_t)(oB + wm * 32 + l15) * 192 + 8 * g,
                    B + (size_t)(nB + wn * 64 + l15) * 192 + 8 * g);

    f32x4 vv[2][4];
#pragma unroll
    for (int mt = 0; mt < 2; ++mt)
#pragma unroll
        for (int nt = 0; nt < 4; ++nt) {
            int o = oB + wm * 32 + mt * 16 + 4 * g;
            int n = nB + wn * 64 + nt * 16 + l15;
            f32x4 v = acc[mt][nt] + *(const f32x4*)(bias + o);
            vv[mt][nt] = v;
            *(unsigned long long*)(out + (size_t)n * kC + o) = pk4(v[0], v[1], v[2], v[3]);
        }
    float s2[2][4] = {}, q2[2][4] = {};
#pragma unroll
    for (int mt = 0; mt < 2; ++mt)
#pragma unroll
        for (int nt = 0; nt < 4; ++nt)
#pragma unroll
            for (int r = 0; r < 4; ++r) {
                float v = vv[mt][nt][r];
                s2[mt][r] += v; q2[mt][r] += v * v;
            }
#pragma unroll
    for (int off = 1; off < 16; off <<= 1)
#pragma unroll
        for (int mt = 0; mt < 2; ++mt)
#pragma unroll
            for (int r = 0; r < 4; ++r) {
                s2[mt][r] += __shfl_xor(s2[mt][r], off);
                q2[mt][r] += __shfl_xor(q2[mt][r], off);
            }
    if (l15 == 0)
#pragma unroll
        for (int mt = 0; mt < 2; ++mt)
#pragma unroll
            for (int r = 0; r < 4; ++r) {
                int ol = wm * 32 + mt * 16 + 4 * g + r;
                sa[wn][ol] = s2[mt][r];
                qa[wn][ol] = q2[mt][r];
            }
    __syncthreads();
    if (threadIdx.x < 128) {
        int ol = threadIdx.x & 63, st = threadIdx.x >> 6;
        float v = st ? (qa[0][ol] + qa[1][ol]) : (sa[0][ol] + sa[1][ol]);
        int b = nB >> 14;
        atomicAdd(&accp[(size_t)(b * kC + oB + ol) * 2 + st], v);
    }
}

// ---------------------------------------------------------------------------
// Fused MLP + ln2: BM=192 (all channels) x BN=128, 6 waves. F never
// materialized; per-pixel LN via intra-wave reduce + LDS over 3 o-waves;
// writes Y1 (bf16 [n][192]) directly.
// ---------------------------------------------------------------------------
__global__ __launch_bounds__(384) void mgemm_mlp_ln_kernel(
    const unsigned short* __restrict__ A1, const unsigned short* __restrict__ B1,
    const unsigned short* __restrict__ A2, const unsigned short* __restrict__ B2,
    unsigned short* __restrict__ out, const float* __restrict__ bp2,
    const unsigned short* __restrict__ res,
    const float* __restrict__ lng, const float* __restrict__ lnb)
{
    __shared__ float lnS[3][2][4][16], lnQ[3][2][4][16];
    int nB = blockIdx.x * 128;
    int w = threadIdx.x >> 6, lane = threadIdx.x & 63;
    int l15 = lane & 15, g = lane >> 4;
    int om = w >> 1, on = w & 1;
    int oB = om * 64;

    f32x4 acc[4][4];
#pragma unroll
    for (int mt = 0; mt < 4; ++mt)
#pragma unroll
        for (int nt = 0; nt < 4; ++nt) acc[mt][nt] = (f32x4){0.f,0.f,0.f,0.f};

    {
        const unsigned short* Ap = A1 + (size_t)(oB + l15) * 192 + 8 * g;
        const unsigned short* Bp = B1 + (size_t)(nB + on * 64 + l15) * 192 + 8 * g;
#pragma unroll 2
        for (int k = 0; k < 192; k += 32) {
            bf16x8 a[4], bb[4];
#pragma unroll
            for (int mt = 0; mt < 4; ++mt) a[mt] = *(const bf16x8*)(Ap + (size_t)mt * 16 * 192 + k);
#pragma unroll
            for (int nt = 0; nt < 4; ++nt) bb[nt] = *(const bf16x8*)(Bp + (size_t)nt * 16 * 192 + k);
#pragma unroll
            for (int mt = 0; mt < 4; ++mt)
#pragma unroll
                for (int nt = 0; nt < 4; ++nt)
                    acc[mt][nt] = __builtin_amdgcn_mfma_f32_16x16x32_bf16(a[mt], bb[nt], acc[mt][nt], 0, 0, 0);
        }
    }
    {
        const unsigned short* Ap = A2 + (size_t)(oB + l15) * 512 + 8 * g;
        const unsigned short* Bp = B2 + (size_t)(nB + on * 64 + l15) * 512 + 8 * g;
#pragma unroll 2
        for (int k = 0; k < 512; k += 32) {
            bf16x8 a[4], bb[4];
#pragma unroll
            for (int mt = 0; mt < 4; ++mt) a[mt] = *(const bf16x8*)(Ap + (size_t)mt * 16 * 512 + k);
#pragma unroll
            for (int nt = 0; nt < 4; ++nt) bb[nt] = *(const bf16x8*)(Bp + (size_t)nt * 16 * 512 + k);
#pragma unroll
            for (int mt = 0; mt < 4; ++mt)
#pragma unroll
                for (int nt = 0; nt < 4; ++nt)
                    acc[mt][nt] = __builtin_amdgcn_mfma_f32_16x16x32_bf16(a[mt], bb[nt], acc[mt][nt], 0, 0, 0);
        }
    }

    float sp[4] = {}, sq[4] = {};
#pragma unroll
    for (int nt = 0; nt < 4; ++nt) {
        int n = nB + on * 64 + nt * 16 + l15;
#pragma unroll
        for (int mt = 0; mt < 4; ++mt) {
            int o = oB + mt * 16 + 4 * g;
            f32x4 v = acc[mt][nt];
            v[0] += bp2[o]; v[1] += bp2[o+1]; v[2] += bp2[o+2]; v[3] += bp2[o+3];
            v += ubf4(*(const unsigned long long*)(res + (size_t)n * kC + o));
            acc[mt][nt] = v;
            sp[nt] += (v[0] + v[1]) + (v[2] + v[3]);
            sq[nt] += (v[0]*v[0] + v[1]*v[1]) + (v[2]*v[2] + v[3]*v[3]);
        }
    }
#pragma unroll
    for (int nt = 0; nt < 4; ++nt) {
        sp[nt] += __shfl_xor(sp[nt], 16);
        sp[nt] += __shfl_xor(sp[nt], 32);
        sq[nt] += __shfl_xor(sq[nt], 16);
        sq[nt] += __shfl_xor(sq[nt], 32);
    }
    if (g == 0)
#pragma unroll
        for (int nt = 0; nt < 4; ++nt) {
            lnS[om][on][nt][l15] = sp[nt];
            lnQ[om][on][nt][l15] = sq[nt];
        }
    __syncthreads();

#pragma unroll
    for (int nt = 0; nt < 4; ++nt) {
        float S = lnS[0][on][nt][l15] + lnS[1][on][nt][l15] + lnS[2][on][nt][l15];
        float Q = lnQ[0][on][nt][l15] + lnQ[1][on][nt][l15] + lnQ[2][on][nt][l15];
        float m = S * (1.0f / kC);
        float var = Q * (1.0f / kC) - m * m;
        float rs = rsqrtf(var + kEPS);
        int n = nB + on * 64 + nt * 16 + l15;
#pragma unroll
        for (int mt = 0; mt < 4; ++mt) {
            int o = oB + mt * 16 + 4 * g;
            f32x4 v = acc[mt][nt];
            f32x4 gg = *(const f32x4*)(lng + o);
            f32x4 bv = *(const f32x4*)(lnb + o);
            *(unsigned long long*)(out + (size_t)n * kC + o) =
                pk4((v[0]-m)*rs*gg[0] + bv[0], (v[1]-m)*rs*gg[1] + bv[1],
                    (v[2]-m)*rs*gg[2] + bv[2], (v[3]-m)*rs*gg[3] + bv[3]);
        }
    }
}

// ---------------------------------------------------------------------------
// Fused qs-reduce + scores + top-16 (tie -> lower index).
// ---------------------------------------------------------------------------
__global__ void score_topk_kernel(const float* __restrict__ qpart,
                                  const float* __restrict__ ksum_h,
                                  const float* __restrict__ ksum_w,
                                  int* __restrict__ hidx, int* __restrict__ widx)
{
    __shared__ float qsl[2][64];
    __shared__ float hs[128], ws[128];
    int bh = blockIdx.x;
    int tid = threadIdx.x;               // 128
    int hc = tid & 63, grp = tid >> 6;
    {
        const float* qp = qpart + ((size_t)bh * 128 + grp * 64) * 64 + hc;
        float s = 0.f;
        for (int i = 0; i < 64; ++i) s += qp[(size_t)i * 64];
        qsl[grp][hc] = s;
    }
    __syncthreads();
    if (tid < 64) qsl[0][tid] += qsl[1][tid];
    __syncthreads();
    {
        const float* kh = ksum_h + ((size_t)bh * 128 + tid) * 64;
        const float* kw = ksum_w + ((size_t)bh * 128 + tid) * 64;
        float sh = 0.f, sw = 0.f;
        for (int c = 0; c < 64; ++c) {
            float q = qsl[0][c];
            sh += q * kh[c];
            sw += q * kw[c];
        }
        hs[tid] = sh; ws[tid] = sw;
    }
    __syncthreads();
    int sel = tid >> 6;
    const float* sc = sel ? ws : hs;
    int* out = (sel ? widx : hidx) + bh * kP;
    int lane = tid & 63;
    float v0 = sc[lane], v1 = sc[lane + 64];
    int i0 = lane, i1 = lane + 64;
    for (int p = 0; p < kP; ++p) {
        float bv; int bi;
        if (v1 > v0) { bv = v1; bi = i1; } else { bv = v0; bi = i0; }
#pragma unroll
        for (int off = 1; off < 64; off <<= 1) {
            float ov = __shfl_xor(bv, off);
            int   oi = __shfl_xor(bi, off);
            if (ov > bv || (ov == bv && oi < bi)) { bv = ov; bi = oi; }
        }
        if (lane == 0) out[p] = bi;
        if (i0 == bi) v0 = -INFINITY;
        if (i1 == bi) v1 = -INFINITY;
    }
}

// ---------------------------------------------------------------------------
// Gather kf from dense KPb; lazy-project vfT.
// ---------------------------------------------------------------------------
__global__ void gather_kv_kernel(const unsigned short* __restrict__ kpb,
                                 const unsigned short* __restrict__ xnb,
                                 const float* __restrict__ wv,
                                 const int* __restrict__ hidx, const int* __restrict__ widx,
                                 unsigned short* __restrict__ kf, unsigned short* __restrict__ vfT)
{
    int bh = blockIdx.y, p1 = blockIdx.x;
    int b = bh >> 3, nh = bh & 7;
    int hc = threadIdx.x & 63, pg = threadIdx.x >> 6;
    int hrow = hidx[bh * kP + p1];
    int o = nh * kHC + hc;
    const float* wvp = wv + (size_t)o * kC;
    for (int p2 = pg; p2 < kP; p2 += 4) {
        int wcol = widx[bh * kP + p2];
        int n = b * kHW + hrow * kW + wcol;
        int kidx = p1 * kP + p2;
        kf[((size_t)bh * 256 + kidx) * 64 + hc] = kpb[(size_t)n * kHID + nh * kHC + hc];
        const unsigned int* xr = (const unsigned int*)(xnb + (size_t)n * kC);
        float s = 0.f;
        for (int c2 = 0; c2 < kC / 2; ++c2) {
            unsigned int u = xr[c2];
            s += wvp[c2 * 2]     * bf2f((unsigned short)(u & 0xffff));
            s += wvp[c2 * 2 + 1] * bf2f((unsigned short)(u >> 16));
        }
        vfT[((size_t)bh * 64 + hc) * 256 + kidx] = f2bf(s);
    }
}

// ---------------------------------------------------------------------------
// MFMA attention, QBLK=128: kf fragments loaded once, reused for 2 q-subtiles.
// P in LDS stride-256 + XOR swizzle (conflict-free).
// ---------------------------------------------------------------------------
__global__ __launch_bounds__(256) void attn_kernel(
    const unsigned short* __restrict__ qpb, unsigned short* __restrict__ ob,
    const unsigned short* __restrict__ kf, const unsigned short* __restrict__ vfT)
{
    __shared__ unsigned short pls[64 * 256];
    __shared__ float lred[4][4][16];

    int bh = blockIdx.y; int b = bh >> 3, nh = bh & 7;
    int nbase = b * kHW + blockIdx.x * 128;
    int tid = threadIdx.x;
    int w = tid >> 6, lane = tid & 63, l15 = lane & 15, g = lane >> 4;

    const unsigned short* kfb = kf + (size_t)bh * 256 * 64;
    bf16x8 ak[4][2];
#pragma unroll
    for (int mt = 0; mt < 4; ++mt)
#pragma unroll
        for (int kt = 0; kt < 2; ++kt)
            ak[mt][kt] = *(const bf16x8*)&kfb[(size_t)(w * 64 + mt * 16 + l15) * 64 + kt * 32 + 8 * g];

    const unsigned short* vfb = vfT + (size_t)bh * 64 * 256;

#pragma unroll
    for (int sub = 0; sub < 2; ++sub) {
        int n0 = nbase + sub * 64;
        bf16x8 bq[4][2];
#pragma unroll
        for (int nt = 0; nt < 4; ++nt)
#pragma unroll
            for (int kt = 0; kt < 2; ++kt)
                bq[nt][kt] = *(const bf16x8*)(qpb + (size_t)(n0 + nt * 16 + l15) * kHID
                                              + nh * kHC + kt * 32 + 8 * g);

        f32x4 acc[4][4];
#pragma unroll
        for (int mt = 0; mt < 4; ++mt)
#pragma unroll
            for (int nt = 0; nt < 4; ++nt) acc[mt][nt] = (f32x4){0.f,0.f,0.f,0.f};

#pragma unroll
        for (int kt = 0; kt < 2; ++kt)
#pragma unroll
            for (int mt = 0; mt < 4; ++mt)
#pragma unroll
                for (int nt = 0; nt < 4; ++nt)
                    acc[mt][nt] = __builtin_amdgcn_mfma_f32_16x16x32_bf16(
                        ak[mt][kt], bq[nt][kt], acc[mt][nt], 0, 0, 0);

        if (sub) __syncthreads();

        float lpart[4] = {0.f, 0.f, 0.f, 0.f};
#pragma unroll
        for (int mt = 0; mt < 4; ++mt)
#pragma unroll
            for (int nt = 0; nt < 4; ++nt) {
                float e0 = __expf(acc[mt][nt][0]);
                float e1 = __expf(acc[mt][nt][1]);
                float e2 = __expf(acc[mt][nt][2]);
                float e3 = __expf(acc[mt][nt][3]);
                lpart[nt] += (e0 + e1) + (e2 + e3);
                int qq = nt * 16 + l15;
                int k0 = w * 64 + mt * 16 + 4 * g;
                int kx = k0 ^ ((qq & 7) << 3);
                *(unsigned long long*)&pls[qq * 256 + kx] = pk4(e0, e1, e2, e3);
            }
#pragma unroll
        for (int nt = 0; nt < 4; ++nt) {
            lpart[nt] += __shfl_xor(lpart[nt], 16);
            lpart[nt] += __shfl_xor(lpart[nt], 32);
        }
        if (g == 0)
#pragma unroll
            for (int nt = 0; nt < 4; ++nt) lred[w][nt][l15] = lpart[nt];
        __syncthreads();

        f32x4 oacc[4];
#pragma unroll
        for (int nt = 0; nt < 4; ++nt) oacc[nt] = (f32x4){0.f,0.f,0.f,0.f};

#pragma unroll
        for (int ks = 0; ks < 8; ++ks) {
            bf16x8 av = *(const bf16x8*)&vfb[(size_t)(w * 16 + l15) * 256 + ks * 32 + 8 * g];
#pragma unroll
            for (int nt = 0; nt < 4; ++nt) {
                int qq = nt * 16 + l15;
                int kx = (ks * 32 + 8 * g) ^ ((qq & 7) << 3);
                bf16x8 bp = *(const bf16x8*)&pls[qq * 256 + kx];
                oacc[nt] = __builtin_amdgcn_mfma_f32_16x16x32_bf16(av, bp, oacc[nt], 0, 0, 0);
            }
        }

#pragma unroll
        for (int nt = 0; nt < 4; ++nt) {
            float l = lred[0][nt][l15] + lred[1][nt][l15] + lred[2][nt][l15] + lred[3][nt][l15];
            float inv = 1.0f / l;
            int qq = nt * 16 + l15;
            int hc0 = w * 16 + 4 * g;
            *(unsigned long long*)(ob + (size_t)(n0 + qq) * kHID + nh * kHC + hc0) =
                pk4(oacc[nt][0] * inv, oacc[nt][1] * inv, oacc[nt][2] * inv, oacc[nt][3] * inv);
        }
    }
}

// ---------------------------------------------------------------------------
// Instance-norm stats (bf16 input) via per-chunk atomics.
// ---------------------------------------------------------------------------
__global__ void istats_bf16_kernel(const unsigned short* __restrict__ in, float* __restrict__ acc)
{
    int n0 = blockIdx.x * 64;
    int b = n0 >> 14;
    int c = threadIdx.x;
    float s = 0.f, ss = 0.f;
    for (int p = 0; p < 64; ++p) {
        float v = bf2f(in[(size_t)(n0 + p) * kC + c]);
        s += v; ss += v * v;
    }
    atomicAdd(&acc[(size_t)(b * kC + c) * 2],     s);
    atomicAdd(&acc[(size_t)(b * kC + c) * 2 + 1], ss);
}

__device__ inline void inorm_ms(const float* acc, int b, int c, float& m, float& rs)
{
    float s  = acc[(size_t)(b * kC + c) * 2];
    float ss = acc[(size_t)(b * kC + c) * 2 + 1];
    m = s * (1.0f / kHW);
    float var = ss * (1.0f / kHW) - m * m;
    rs = rsqrtf(var + kEPS);
}

// MODE 0: gelu(inorm(in)) -> bf16.  MODE 1: gelu(inorm(in)) + add -> bf16.
template<int MODE>
__global__ void apply_pm_kernel(const unsigned short* __restrict__ in, const float* __restrict__ acc,
                                unsigned short* __restrict__ out, const unsigned short* __restrict__ addsrc)
{
    int idx = blockIdx.x * 256 + threadIdx.x;      // kN*48
    int n = idx / 48;
    int c0 = (idx - n * 48) * 4;
    int b = n >> 14;
    f32x4 v = ubf4(*(const unsigned long long*)(in + (size_t)n * kC + c0));
    f32x4 r;
#pragma unroll
    for (int j = 0; j < 4; ++j) {
        float m, rs;
        inorm_ms(acc, b, c0 + j, m, rs);
        float x = (v[j] - m) * rs;
        r[j] = gelu_f(x);
    }
    if (MODE == 1)
        r += ubf4(*(const unsigned long long*)(addsrc + (size_t)n * kC + c0));
    *(unsigned long long*)(out + (size_t)n * kC + c0) = pk4(r[0], r[1], r[2], r[3]);
}

// ---------------------------------------------------------------------------
// Final inorm via LDS transpose: bf16 pixel-major in -> NCHW fp32 d_out.
// ---------------------------------------------------------------------------
__global__ __launch_bounds__(256) void final_kernel(const unsigned short* __restrict__ in,
                                                    const float* __restrict__ acc,
                                                    float* __restrict__ out)
{
    __shared__ unsigned short tile[192][68];
    int n0 = blockIdx.x * 64;
    int b = n0 >> 14;
    int hw0 = n0 & (kHW - 1);
    int tid = threadIdx.x;
    for (int i = tid; i < 64 * 48; i += 256) {
        int p = i / 48, cq = i - p * 48;
        unsigned long long u = *(const unsigned long long*)(in + (size_t)(n0 + p) * kC + cq * 4);
        tile[cq * 4 + 0][p] = (unsigned short)u;
        tile[cq * 4 + 1][p] = (unsigned short)(u >> 16);
        tile[cq * 4 + 2][p] = (unsigned short)(u >> 32);
        tile[cq * 4 + 3][p] = (unsigned short)(u >> 48);
    }
    __syncthreads();
    for (int i = tid; i < 192 * 16; i += 256) {
        int c = i >> 4, grp = i & 15;
        float m, rs;
        inorm_ms(acc, b, c, m, rs);
        f32x4 o;
#pragma unroll
        for (int j = 0; j < 4; ++j)
            o[j] = (bf2f(tile[c][grp * 4 + j]) - m) * rs;
        *(f32x4*)(out + (size_t)(b * kC + c) * kHW + hw0 + grp * 4) = o;
    }
}

// ---------------------------------------------------------------------------
extern "C" void kernel_launch(void* const* d_in, const int* in_sizes, int n_in,
                              void* d_out, int out_size, void* d_ws, size_t ws_size,
                              hipStream_t stream)
{
    const float* x     = (const float*)d_in[0];
    const float* ln1_g = (const float*)d_in[1];
    const float* ln1_b = (const float*)d_in[2];
    const float* wq    = (const float*)d_in[3];
    const float* wk    = (const float*)d_in[4];
    const float* wv    = (const float*)d_in[5];
    const float* wo    = (const float*)d_in[6];
    const float* bo    = (const float*)d_in[7];
    const float* dw_w  = (const float*)d_in[8];
    const float* dw_b  = (const float*)d_in[9];
    const float* mlp_w = (const float*)d_in[10];
    const float* mlp_b = (const float*)d_in[11];
    const float* ln2_g = (const float*)d_in[12];
    const float* ln2_b = (const float*)d_in[13];
    const float* c1_w  = (const float*)d_in[14];
    const float* c1_b  = (const float*)d_in[15];
    const float* res_w = (const float*)d_in[16];
    const float* res_b = (const float*)d_in[17];
    const float* c2_w  = (const float*)d_in[18];
    const float* c2_b  = (const float*)d_in[19];

    char* base = (char*)d_ws;
    unsigned short* XPb = (unsigned short*)(base);               // bf16 [n][192] raw x
    unsigned short* XNb = (unsigned short*)(base + 25165824);    // bf16 [n][192] xn / Y1
    unsigned short* QPb = (unsigned short*)(base + 37748736);    // bf16 [n][512]; later T2
    unsigned short* T2  = QPb;
    unsigned short* KPb = (unsigned short*)(base + 71303168);    // bf16 [n][512]; OB alias; later Y2
    unsigned short* OB  = KPb;
    unsigned short* Y2  = KPb;
    unsigned short* LB  = (unsigned short*)(base + 104857600);   // bf16 [n][192] local; later Y3
    unsigned short* Y3  = LB;
    unsigned short* T1  = (unsigned short*)(base + 117440512);   // bf16 [n][192]; later R
    unsigned short* R   = T1;
    char* sm = base + 130023424;
    float* qpart  = (float*)(sm);                 sm += 524288;   // [16][128][64]
    float* ksum_h = (float*)(sm);                 sm += 524288;
    float* ksum_w = (float*)(sm);                 sm += 524288;
    float* acc0   = (float*)(sm);                 sm += 3072;     // zero block (2304 floats)
    float* acc1   = (float*)(sm);                 sm += 3072;
    float* acc2   = (float*)(sm);                 sm += 3072;
    unsigned short* kf   = (unsigned short*)(sm); sm += 524288;
    unsigned short* vfT  = (unsigned short*)(sm); sm += 524288;
    unsigned short* wqb  = (unsigned short*)(sm); sm += 196608;
    unsigned short* wkb  = (unsigned short*)(sm); sm += 196608;
    unsigned short* mlpb1= (unsigned short*)(sm); sm += 73728;
    unsigned short* c1b  = (unsigned short*)(sm); sm += 73728;
    unsigned short* c2b  = (unsigned short*)(sm); sm += 73728;
    unsigned short* w2pb = (unsigned short*)(sm); sm += 196608;
    float* bp2 = (float*)(sm);                    sm += 1024;
    int* hidx = (int*)(sm);                       sm += 1024;
    int* widx = (int*)(sm);

    // 1. prep
    prep_kernel<<<1593, 256, 0, stream>>>(acc0, wq, wk, mlp_w, c1_w, c2_w,
                                          wo, mlp_b, bo,
                                          wqb, wkb, mlpb1, c1b, c2b, w2pb, bp2);
    // 2. transpose + ln1
    txln_kernel<<<dim3(kHW / 64, kB), 256, 0, stream>>>(x, XPb, XNb, ln1_g, ln1_b);
    // 3. q/k projections (separate; merging with dwconv regressed twice)
    qk_proj_kernel<<<dim3(kN / 128, 4, 2), 256, 0, stream>>>(wqb, wkb, XNb, QPb, KPb,
                                                             qpart, ksum_h);
    // 4. local dwconv
    dwconv_pm_kernel<<<(kN * 48) / 256, 256, 0, stream>>>(XPb, LB, dw_w, dw_b);
    // 5. ksum_w
    sum_h_kernel<<<dim3(kW, 16), 256, 0, stream>>>(KPb, ksum_w);
    // 6. scores + top-16
    score_topk_kernel<<<16, 128, 0, stream>>>(qpart, ksum_h, ksum_w, hidx, widx);
    // 7. gather: kf copy + lazy vfT
    gather_kv_kernel<<<dim3(kP, 16), 256, 0, stream>>>(KPb, XNb, wv, hidx, widx, kf, vfT);
    // 8. attention (QBLK=128; OB overwrites KPb)
    attn_kernel<<<dim3(kHW / 128, 16), 256, 0, stream>>>(QPb, OB, kf, vfT);
    // 9. fused mlp + ln2 -> Y1 (XNb); F never materialized
    mgemm_mlp_ln_kernel<<<kN / 128, 384, 0, stream>>>(mlpb1, LB, w2pb, OB, XNb, bp2, XPb,
                                                      ln2_g, ln2_b);
    // 10. c1 GEMM + istats(acc0)
    mgemm_is_kernel<<<dim3(kN / 128, kC / 64), 256, 0, stream>>>(c1b, XNb, T1, c1_b, acc0);
    // 11. Y2 = gelu(inorm(T1))  (OB region dead)
    apply_pm_kernel<0><<<(kN * 48) / 256, 256, 0, stream>>>(T1, acc0, Y2, nullptr);
    // 12. res dwconv: R = dwconv(Y2)  (overwrites T1)
    dwconv_pm_kernel<<<(kN * 48) / 256, 256, 0, stream>>>(Y2, R, res_w, res_b);
    // 13. istats(R) -> acc1
    istats_bf16_kernel<<<kN / 64, 192, 0, stream>>>(R, acc1);
    // 14. Y3 = gelu(inorm(R)) + Y2
    apply_pm_kernel<1><<<(kN * 48) / 256, 256, 0, stream>>>(R, acc1, Y3, Y2);
    // 15. c2 GEMM + istats(acc2)
    mgemm_is_kernel<<<dim3(kN / 128, kC / 64), 256, 0, stream>>>(c2b, Y3, T2, c2_b, acc2);
    // 16. final inorm -> d_out
    final_kernel<<<kN / 64, 256, 0, stream>>>(T2, acc2, (float*)d_out);
}

// Round 15
// 447.437 us; speedup vs baseline: 1.5563x; 1.0037x over previous
//
#include <hip/hip_runtime.h>
#include <math.h>

constexpr int kC   = 192;
constexpr int kNH  = 8;
constexpr int kHC  = 64;
constexpr int kHID = 512;
constexpr int kP   = 16;
constexpr int kB   = 2;
constexpr int kH   = 128;
constexpr int kW   = 128;
constexpr int kHW  = kH * kW;      // 16384
constexpr int kN   = kB * kHW;     // 32768
constexpr float kEPS = 1e-5f;

typedef __attribute__((ext_vector_type(8))) short bf16x8;
typedef __attribute__((ext_vector_type(4))) float f32x4;

__device__ inline unsigned short f2bf(float f) {
    unsigned int u = __builtin_bit_cast(unsigned int, f);
    unsigned int r = (u + 0x7FFFu + ((u >> 16) & 1u)) >> 16;   // RNE
    return (unsigned short)r;
}
__device__ inline float bf2f(unsigned short u) {
    return __builtin_bit_cast(float, (unsigned int)u << 16);
}
__device__ inline unsigned int cvtpk(float lo, float hi) {
    unsigned int r;
    asm("v_cvt_pk_bf16_f32 %0, %1, %2" : "=v"(r) : "v"(lo), "v"(hi));
    return r;
}
__device__ inline unsigned long long pk4(float a, float b, float c, float d) {
    return (unsigned long long)cvtpk(a, b) | ((unsigned long long)cvtpk(c, d) << 32);
}
__device__ inline f32x4 ubf4(unsigned long long u) {
    f32x4 r;
    r[0] = bf2f((unsigned short)u);
    r[1] = bf2f((unsigned short)(u >> 16));
    r[2] = bf2f((unsigned short)(u >> 32));
    r[3] = bf2f((unsigned short)(u >> 48));
    return r;
}
__device__ inline float gelu_f(float x) {
    return 0.5f * x * (1.0f + erff(x * 0.70710678118654752f));
}

// ---------------------------------------------------------------------------
// Prep: zero acc0..2 + bf16 weight cvts + fused W2' weight.
// ---------------------------------------------------------------------------
__global__ void prep_kernel(float* __restrict__ zbase,
                            const float* wq, const float* wk, const float* wm,
                            const float* c1, const float* c2,
                            const float* wo, const float* mlp_b, const float* bo,
                            unsigned short* wqb, unsigned short* wkb,
                            unsigned short* mlpb1, unsigned short* c1b, unsigned short* c2b,
                            unsigned short* w2pb, float* bp2)
{
    int i = blockIdx.x * 256 + threadIdx.x;
    if (i < 2304) { zbase[i] = 0.f; return; }            // acc0..2
    i -= 2304;
    if (i < 98304) { wqb[i] = f2bf(wq[i]); return; }
    i -= 98304;
    if (i < 98304) { wkb[i] = f2bf(wk[i]); return; }
    i -= 98304;
    if (i < 36864) { int o = i / 192, k = i - o * 192; mlpb1[i] = f2bf(wm[o * 384 + k]); return; }
    i -= 36864;
    if (i < 36864) { c1b[i] = f2bf(c1[i]); return; }
    i -= 36864;
    if (i < 36864) { c2b[i] = f2bf(c2[i]); return; }
    i -= 36864;
    if (i < 98304) {
        int o = i >> 9, j = i & 511;
        const float* a = wm + o * 384 + 192;
        float s = 0.f;
        for (int c = 0; c < 192; ++c) s += a[c] * wo[c * 512 + j];
        w2pb[o * 512 + j] = f2bf(s);
        if (j == 0) {
            float t = mlp_b[o];
            for (int c = 0; c < 192; ++c) t += a[c] * bo[c];
            bp2[o] = t;
        }
    }
}

// ---------------------------------------------------------------------------
// Fused transpose + ln1: x NCHW fp32 -> XPb raw bf16 [n][192] + XNb bf16.
// ---------------------------------------------------------------------------
__global__ __launch_bounds__(256) void txln_kernel(const float* __restrict__ x,
                                                   unsigned short* __restrict__ xpb,
                                                   unsigned short* __restrict__ xnb,
                                                   const float* __restrict__ g,
                                                   const float* __restrict__ bb)
{
    __shared__ float tile[192][65];
    __shared__ float red[2][4][64];
    __shared__ float pms[64], prs[64];
    int hw0 = blockIdx.x * 64;
    int b   = blockIdx.y;
    int tid = threadIdx.x;
    for (int i = tid; i < 192 * 64; i += 256) {
        int c = i >> 6, p = i & 63;
        tile[c][p] = x[(size_t)(b * kC + c) * kHW + hw0 + p];
    }
    __syncthreads();
    {
        int p = tid & 63, qt = tid >> 6;
        float s = 0.f, ss = 0.f;
        for (int c = qt * 48; c < qt * 48 + 48; ++c) {
            float v = tile[c][p]; s += v; ss += v * v;
        }
        red[0][qt][p] = s; red[1][qt][p] = ss;
    }
    __syncthreads();
    if (tid < 64) {
        float s  = red[0][0][tid] + red[0][1][tid] + red[0][2][tid] + red[0][3][tid];
        float ss = red[1][0][tid] + red[1][1][tid] + red[1][2][tid] + red[1][3][tid];
        float m = s * (1.0f / kC);
        float var = ss * (1.0f / kC) - m * m;
        pms[tid] = m;
        prs[tid] = rsqrtf(var + kEPS);
    }
    __syncthreads();
    for (int i = tid; i < 64 * 192; i += 256) {
        int p = i / 192, c = i - p * 192;
        float raw = tile[c][p];
        size_t oi = (size_t)(b * kHW + hw0 + p) * kC + c;
        xpb[oi] = f2bf(raw);
        xnb[oi] = f2bf((raw - pms[p]) * prs[p] * g[c] + bb[c]);
    }
}

#define MGEMM_CORE(KVAL, APTR, BPTR)                                              \
    {                                                                             \
        const unsigned short* Ap = APTR;                                          \
        const unsigned short* Bp = BPTR;                                          \
        _Pragma("unroll 2")                                                       \
        for (int k = 0; k < KVAL; k += 32) {                                      \
            bf16x8 a0 = *(const bf16x8*)(Ap + k);                                 \
            bf16x8 a1 = *(const bf16x8*)(Ap + (size_t)16 * KVAL + k);             \
            bf16x8 b0 = *(const bf16x8*)(Bp + k);                                 \
            bf16x8 b1 = *(const bf16x8*)(Bp + (size_t)16 * KVAL + k);             \
            bf16x8 b2 = *(const bf16x8*)(Bp + (size_t)32 * KVAL + k);             \
            bf16x8 b3 = *(const bf16x8*)(Bp + (size_t)48 * KVAL + k);             \
            acc[0][0] = __builtin_amdgcn_mfma_f32_16x16x32_bf16(a0, b0, acc[0][0], 0, 0, 0); \
            acc[0][1] = __builtin_amdgcn_mfma_f32_16x16x32_bf16(a0, b1, acc[0][1], 0, 0, 0); \
            acc[0][2] = __builtin_amdgcn_mfma_f32_16x16x32_bf16(a0, b2, acc[0][2], 0, 0, 0); \
            acc[0][3] = __builtin_amdgcn_mfma_f32_16x16x32_bf16(a0, b3, acc[0][3], 0, 0, 0); \
            acc[1][0] = __builtin_amdgcn_mfma_f32_16x16x32_bf16(a1, b0, acc[1][0], 0, 0, 0); \
            acc[1][1] = __builtin_amdgcn_mfma_f32_16x16x32_bf16(a1, b1, acc[1][1], 0, 0, 0); \
            acc[1][2] = __builtin_amdgcn_mfma_f32_16x16x32_bf16(a1, b2, acc[1][2], 0, 0, 0); \
            acc[1][3] = __builtin_amdgcn_mfma_f32_16x16x32_bf16(a1, b3, acc[1][3], 0, 0, 0); \
        }                                                                         \
    }

// ---------------------------------------------------------------------------
// q/k projection GEMM, BM=128 (2 heads), 4 waves each owning one full
// (head x 64n) tile. Per-head L2 norm intra-wave. Fused row-sum.
// Flat grid 2048 with XCD swizzle: each XCD gets a contiguous 32-nblk slice
// of XNb (1.57 MB, L2-resident) for all (hp, q/k) -> B re-reads hit local L2.
// ---------------------------------------------------------------------------
__global__ __launch_bounds__(256) void qk_proj_kernel(
    const unsigned short* __restrict__ wqb, const unsigned short* __restrict__ wkb,
    const unsigned short* __restrict__ xnb,
    unsigned short* __restrict__ qpb, unsigned short* __restrict__ kpb,
    float* __restrict__ qpart, float* __restrict__ ksum_h)
{
    __shared__ float rbuf[2][2][4][4][4];   // [wm][wn][g][mt][r]
    int bid = blockIdx.x;
    int xcd = bid & 7;
    int idx = bid >> 3;                      // 0..255 within XCD
    int nblk = xcd * 32 + (idx & 31);
    int hpz  = idx >> 5;                     // 0..7
    int hp = hpz & 3, isK = hpz >> 2;

    int nB = nblk * 128;
    const unsigned short* A = isK ? wkb : wqb;
    unsigned short* out = isK ? kpb : qpb;
    float* red_out = isK ? ksum_h : qpart;

    int w = threadIdx.x >> 6, lane = threadIdx.x & 63;
    int l15 = lane & 15, g = lane >> 4;
    int wm = w & 1, wn = w >> 1;
    int oB = hp * 128;

    const unsigned short* Ap = A + (size_t)(oB + wm * 64 + l15) * 192 + 8 * g;
    const unsigned short* Bp = xnb + (size_t)(nB + wn * 64 + l15) * 192 + 8 * g;

    f32x4 acc[4][4];
#pragma unroll
    for (int mt = 0; mt < 4; ++mt)
#pragma unroll
        for (int nt = 0; nt < 4; ++nt) acc[mt][nt] = (f32x4){0.f,0.f,0.f,0.f};

#pragma unroll 2
    for (int k = 0; k < 192; k += 32) {
        bf16x8 a[4], bb[4];
#pragma unroll
        for (int mt = 0; mt < 4; ++mt) a[mt] = *(const bf16x8*)(Ap + (size_t)mt * 16 * 192 + k);
#pragma unroll
        for (int nt = 0; nt < 4; ++nt) bb[nt] = *(const bf16x8*)(Bp + (size_t)nt * 16 * 192 + k);
#pragma unroll
        for (int mt = 0; mt < 4; ++mt)
#pragma unroll
            for (int nt = 0; nt < 4; ++nt)
                acc[mt][nt] = __builtin_amdgcn_mfma_f32_16x16x32_bf16(a[mt], bb[nt], acc[mt][nt], 0, 0, 0);
    }

    float sc[4];
#pragma unroll
    for (int nt = 0; nt < 4; ++nt) {
        float s = 0.f;
#pragma unroll
        for (int mt = 0; mt < 4; ++mt) {
            f32x4 a = acc[mt][nt];
            s += (a[0]*a[0] + a[1]*a[1]) + (a[2]*a[2] + a[3]*a[3]);
        }
        s += __shfl_xor(s, 16);
        s += __shfl_xor(s, 32);
        sc[nt] = 1.0f / fmaxf(sqrtf(s), 1e-12f);
    }

#pragma unroll
    for (int nt = 0; nt < 4; ++nt) {
        int n = nB + wn * 64 + nt * 16 + l15;
#pragma unroll
        for (int mt = 0; mt < 4; ++mt) {
            int o = oB + wm * 64 + mt * 16 + 4 * g;
            f32x4 v = acc[mt][nt];
            *(unsigned long long*)(out + (size_t)n * kHID + o) =
                pk4(v[0]*sc[nt], v[1]*sc[nt], v[2]*sc[nt], v[3]*sc[nt]);
        }
    }

    float sred[4][4] = {};
#pragma unroll
    for (int nt = 0; nt < 4; ++nt)
#pragma unroll
        for (int mt = 0; mt < 4; ++mt) {
            f32x4 a = acc[mt][nt];
            sred[mt][0] += a[0] * sc[nt];
            sred[mt][1] += a[1] * sc[nt];
            sred[mt][2] += a[2] * sc[nt];
            sred[mt][3] += a[3] * sc[nt];
        }
#pragma unroll
    for (int off = 1; off < 16; off <<= 1)
#pragma unroll
        for (int mt = 0; mt < 4; ++mt)
#pragma unroll
            for (int r = 0; r < 4; ++r)
                sred[mt][r] += __shfl_xor(sred[mt][r], off);
    if (l15 == 0)
#pragma unroll
        for (int mt = 0; mt < 4; ++mt)
#pragma unroll
            for (int r = 0; r < 4; ++r)
                rbuf[wm][wn][g][mt][r] = sred[mt][r];
    __syncthreads();
    if (threadIdx.x < 128) {
        int wm2 = threadIdx.x >> 6;
        int o = threadIdx.x & 63;
        int mt2 = o >> 4, g2 = (o >> 2) & 3, r2 = o & 3;
        float v = rbuf[wm2][0][g2][mt2][r2] + rbuf[wm2][1][g2][mt2][r2];
        int row = (nB & (kHW - 1)) >> 7;
        int b = nB >> 14;
        int bh = b * 8 + hp * 2 + wm2;
        red_out[((size_t)(bh * 128 + row)) * 64 + o] = v;
    }
}

// ---------------------------------------------------------------------------
// Depthwise 3x3 SAME conv, pixel-major bf16 in -> bf16 out [n][192].
// ---------------------------------------------------------------------------
__global__ void dwconv_pm_kernel(const unsigned short* __restrict__ in,
                                 unsigned short* __restrict__ out,
                                 const float* __restrict__ wt, const float* __restrict__ bias)
{
    int idx = blockIdx.x * 256 + threadIdx.x;      // kN*48
    int n = idx / 48;
    int c0 = (idx - n * 48) * 4;
    int hw = n & (kHW - 1);
    int h = hw >> 7, ww = hw & 127;
    f32x4 s = *(const f32x4*)(bias + c0);
#pragma unroll
    for (int dy = -1; dy <= 1; ++dy) {
        int hh = h + dy;
        if (hh < 0 || hh >= kH) continue;
#pragma unroll
        for (int dx = -1; dx <= 1; ++dx) {
            int wx = ww + dx;
            if (wx < 0 || wx >= kW) continue;
            f32x4 v = ubf4(*(const unsigned long long*)(in + (size_t)(n + dy * kW + dx) * kC + c0));
            int t = (dy + 1) * 3 + (dx + 1);
            s[0] += v[0] * wt[(c0 + 0) * 9 + t];
            s[1] += v[1] * wt[(c0 + 1) * 9 + t];
            s[2] += v[2] * wt[(c0 + 2) * 9 + t];
            s[3] += v[3] * wt[(c0 + 3) * 9 + t];
        }
    }
    *(unsigned long long*)(out + (size_t)n * kC + c0) = pk4(s[0], s[1], s[2], s[3]);
}

// ksum_w[bh][w][hc] = sum_h k.  256 threads: 4 h-segments of 32 + LDS reduce.
__global__ void sum_h_kernel(const unsigned short* __restrict__ buf, float* __restrict__ out)
{
    __shared__ float red[4][64];
    int w = blockIdx.x, bh = blockIdx.y;
    int hc = threadIdx.x & 63, seg = threadIdx.x >> 6;
    int b = bh >> 3, nh = bh & 7;
    const unsigned short* p = buf + (size_t)(b * kHW + seg * 32 * kW + w) * kHID + nh * kHC + hc;
    float s = 0.f;
    for (int h = 0; h < 32; ++h) s += bf2f(p[(size_t)h * kW * kHID]);
    red[seg][hc] = s;
    __syncthreads();
    if (threadIdx.x < 64)
        out[((size_t)bh * kW + w) * kHC + threadIdx.x] =
            red[0][threadIdx.x] + red[1][threadIdx.x] + red[2][threadIdx.x] + red[3][threadIdx.x];
}

// ---------------------------------------------------------------------------
// c1/c2 GEMM: bf16 out [n][192] + bias + fused istats. Flat grid 768 with
// XCD swizzle (32-nblk slice per XCD, all 3 o-blocks).
// ---------------------------------------------------------------------------
__global__ __launch_bounds__(256) void mgemm_is_kernel(
    const unsigned short* __restrict__ A, const unsigned short* __restrict__ B,
    unsigned short* __restrict__ out, const float* __restrict__ bias,
    float* __restrict__ accp)
{
    __shared__ float sa[2][64], qa[2][64];
    int bid = blockIdx.x;
    int xcd = bid & 7;
    int idx = bid >> 3;                      // 0..95
    int nB = (xcd * 32 + (idx & 31)) * 128;
    int oB = (idx >> 5) * 64;
    int w = threadIdx.x >> 6, lane = threadIdx.x & 63;
    int l15 = lane & 15, g = lane >> 4;
    int wm = w & 1, wn = w >> 1;

    f32x4 acc[2][4];
#pragma unroll
    for (int mt = 0; mt < 2; ++mt)
#pragma unroll
        for (int nt = 0; nt < 4; ++nt) acc[mt][nt] = (f32x4){0.f,0.f,0.f,0.f};

    MGEMM_CORE(192, A + (size_t)(oB + wm * 32 + l15) * 192 + 8 * g,
                    B + (size_t)(nB + wn * 64 + l15) * 192 + 8 * g);

    f32x4 vv[2][4];
#pragma unroll
    for (int mt = 0; mt < 2; ++mt)
#pragma unroll
        for (int nt = 0; nt < 4; ++nt) {
            int o = oB + wm * 32 + mt * 16 + 4 * g;
            int n = nB + wn * 64 + nt * 16 + l15;
            f32x4 v = acc[mt][nt] + *(const f32x4*)(bias + o);
            vv[mt][nt] = v;
            *(unsigned long long*)(out + (size_t)n * kC + o) = pk4(v[0], v[1], v[2], v[3]);
        }
    float s2[2][4] = {}, q2[2][4] = {};
#pragma unroll
    for (int mt = 0; mt < 2; ++mt)
#pragma unroll
        for (int nt = 0; nt < 4; ++nt)
#pragma unroll
            for (int r = 0; r < 4; ++r) {
                float v = vv[mt][nt][r];
                s2[mt][r] += v; q2[mt][r] += v * v;
            }
#pragma unroll
    for (int off = 1; off < 16; off <<= 1)
#pragma unroll
        for (int mt = 0; mt < 2; ++mt)
#pragma unroll
            for (int r = 0; r < 4; ++r) {
                s2[mt][r] += __shfl_xor(s2[mt][r], off);
                q2[mt][r] += __shfl_xor(q2[mt][r], off);
            }
    if (l15 == 0)
#pragma unroll
        for (int mt = 0; mt < 2; ++mt)
#pragma unroll
            for (int r = 0; r < 4; ++r) {
                int ol = wm * 32 + mt * 16 + 4 * g + r;
                sa[wn][ol] = s2[mt][r];
                qa[wn][ol] = q2[mt][r];
            }
    __syncthreads();
    if (threadIdx.x < 128) {
        int ol = threadIdx.x & 63, st = threadIdx.x >> 6;
        float v = st ? (qa[0][ol] + qa[1][ol]) : (sa[0][ol] + sa[1][ol]);
        int b = nB >> 14;
        atomicAdd(&accp[(size_t)(b * kC + oB + ol) * 2 + st], v);
    }
}

// ---------------------------------------------------------------------------
// Fused MLP + ln2: BM=192 x BN=128, 6 waves; XCD-swizzled nblk. Writes Y1.
// ---------------------------------------------------------------------------
__global__ __launch_bounds__(384) void mgemm_mlp_ln_kernel(
    const unsigned short* __restrict__ A1, const unsigned short* __restrict__ B1,
    const unsigned short* __restrict__ A2, const unsigned short* __restrict__ B2,
    unsigned short* __restrict__ out, const float* __restrict__ bp2,
    const unsigned short* __restrict__ res,
    const float* __restrict__ lng, const float* __restrict__ lnb)
{
    __shared__ float lnS[3][2][4][16], lnQ[3][2][4][16];
    int bid = blockIdx.x;
    int nB = ((bid & 7) * 32 + (bid >> 3)) * 128;
    int w = threadIdx.x >> 6, lane = threadIdx.x & 63;
    int l15 = lane & 15, g = lane >> 4;
    int om = w >> 1, on = w & 1;
    int oB = om * 64;

    f32x4 acc[4][4];
#pragma unroll
    for (int mt = 0; mt < 4; ++mt)
#pragma unroll
        for (int nt = 0; nt < 4; ++nt) acc[mt][nt] = (f32x4){0.f,0.f,0.f,0.f};

    {
        const unsigned short* Ap = A1 + (size_t)(oB + l15) * 192 + 8 * g;
        const unsigned short* Bp = B1 + (size_t)(nB + on * 64 + l15) * 192 + 8 * g;
#pragma unroll 2
        for (int k = 0; k < 192; k += 32) {
            bf16x8 a[4], bb[4];
#pragma unroll
            for (int mt = 0; mt < 4; ++mt) a[mt] = *(const bf16x8*)(Ap + (size_t)mt * 16 * 192 + k);
#pragma unroll
            for (int nt = 0; nt < 4; ++nt) bb[nt] = *(const bf16x8*)(Bp + (size_t)nt * 16 * 192 + k);
#pragma unroll
            for (int mt = 0; mt < 4; ++mt)
#pragma unroll
                for (int nt = 0; nt < 4; ++nt)
                    acc[mt][nt] = __builtin_amdgcn_mfma_f32_16x16x32_bf16(a[mt], bb[nt], acc[mt][nt], 0, 0, 0);
        }
    }
    {
        const unsigned short* Ap = A2 + (size_t)(oB + l15) * 512 + 8 * g;
        const unsigned short* Bp = B2 + (size_t)(nB + on * 64 + l15) * 512 + 8 * g;
#pragma unroll 2
        for (int k = 0; k < 512; k += 32) {
            bf16x8 a[4], bb[4];
#pragma unroll
            for (int mt = 0; mt < 4; ++mt) a[mt] = *(const bf16x8*)(Ap + (size_t)mt * 16 * 512 + k);
#pragma unroll
            for (int nt = 0; nt < 4; ++nt) bb[nt] = *(const bf16x8*)(Bp + (size_t)nt * 16 * 512 + k);
#pragma unroll
            for (int mt = 0; mt < 4; ++mt)
#pragma unroll
                for (int nt = 0; nt < 4; ++nt)
                    acc[mt][nt] = __builtin_amdgcn_mfma_f32_16x16x32_bf16(a[mt], bb[nt], acc[mt][nt], 0, 0, 0);
        }
    }

    float sp[4] = {}, sq[4] = {};
#pragma unroll
    for (int nt = 0; nt < 4; ++nt) {
        int n = nB + on * 64 + nt * 16 + l15;
#pragma unroll
        for (int mt = 0; mt < 4; ++mt) {
            int o = oB + mt * 16 + 4 * g;
            f32x4 v = acc[mt][nt];
            v[0] += bp2[o]; v[1] += bp2[o+1]; v[2] += bp2[o+2]; v[3] += bp2[o+3];
            v += ubf4(*(const unsigned long long*)(res + (size_t)n * kC + o));
            acc[mt][nt] = v;
            sp[nt] += (v[0] + v[1]) + (v[2] + v[3]);
            sq[nt] += (v[0]*v[0] + v[1]*v[1]) + (v[2]*v[2] + v[3]*v[3]);
        }
    }
#pragma unroll
    for (int nt = 0; nt < 4; ++nt) {
        sp[nt] += __shfl_xor(sp[nt], 16);
        sp[nt] += __shfl_xor(sp[nt], 32);
        sq[nt] += __shfl_xor(sq[nt], 16);
        sq[nt] += __shfl_xor(sq[nt], 32);
    }
    if (g == 0)
#pragma unroll
        for (int nt = 0; nt < 4; ++nt) {
            lnS[om][on][nt][l15] = sp[nt];
            lnQ[om][on][nt][l15] = sq[nt];
        }
    __syncthreads();

#pragma unroll
    for (int nt = 0; nt < 4; ++nt) {
        float S = lnS[0][on][nt][l15] + lnS[1][on][nt][l15] + lnS[2][on][nt][l15];
        float Q = lnQ[0][on][nt][l15] + lnQ[1][on][nt][l15] + lnQ[2][on][nt][l15];
        float m = S * (1.0f / kC);
        float var = Q * (1.0f / kC) - m * m;
        float rs = rsqrtf(var + kEPS);
        int n = nB + on * 64 + nt * 16 + l15;
#pragma unroll
        for (int mt = 0; mt < 4; ++mt) {
            int o = oB + mt * 16 + 4 * g;
            f32x4 v = acc[mt][nt];
            f32x4 gg = *(const f32x4*)(lng + o);
            f32x4 bv = *(const f32x4*)(lnb + o);
            *(unsigned long long*)(out + (size_t)n * kC + o) =
                pk4((v[0]-m)*rs*gg[0] + bv[0], (v[1]-m)*rs*gg[1] + bv[1],
                    (v[2]-m)*rs*gg[2] + bv[2], (v[3]-m)*rs*gg[3] + bv[3]);
        }
    }
}

// ---------------------------------------------------------------------------
// Fused qs-reduce + scores + top-16 (tie -> lower index).
// ---------------------------------------------------------------------------
__global__ void score_topk_kernel(const float* __restrict__ qpart,
                                  const float* __restrict__ ksum_h,
                                  const float* __restrict__ ksum_w,
                                  int* __restrict__ hidx, int* __restrict__ widx)
{
    __shared__ float qsl[2][64];
    __shared__ float hs[128], ws[128];
    int bh = blockIdx.x;
    int tid = threadIdx.x;               // 128
    int hc = tid & 63, grp = tid >> 6;
    {
        const float* qp = qpart + ((size_t)bh * 128 + grp * 64) * 64 + hc;
        float s = 0.f;
        for (int i = 0; i < 64; ++i) s += qp[(size_t)i * 64];
        qsl[grp][hc] = s;
    }
    __syncthreads();
    if (tid < 64) qsl[0][tid] += qsl[1][tid];
    __syncthreads();
    {
        const float* kh = ksum_h + ((size_t)bh * 128 + tid) * 64;
        const float* kw = ksum_w + ((size_t)bh * 128 + tid) * 64;
        float sh = 0.f, sw = 0.f;
        for (int c = 0; c < 64; ++c) {
            float q = qsl[0][c];
            sh += q * kh[c];
            sw += q * kw[c];
        }
        hs[tid] = sh; ws[tid] = sw;
    }
    __syncthreads();
    int sel = tid >> 6;
    const float* sc = sel ? ws : hs;
    int* out = (sel ? widx : hidx) + bh * kP;
    int lane = tid & 63;
    float v0 = sc[lane], v1 = sc[lane + 64];
    int i0 = lane, i1 = lane + 64;
    for (int p = 0; p < kP; ++p) {
        float bv; int bi;
        if (v1 > v0) { bv = v1; bi = i1; } else { bv = v0; bi = i0; }
#pragma unroll
        for (int off = 1; off < 64; off <<= 1) {
            float ov = __shfl_xor(bv, off);
            int   oi = __shfl_xor(bi, off);
            if (ov > bv || (ov == bv && oi < bi)) { bv = ov; bi = oi; }
        }
        if (lane == 0) out[p] = bi;
        if (i0 == bi) v0 = -INFINITY;
        if (i1 == bi) v1 = -INFINITY;
    }
}

// ---------------------------------------------------------------------------
// Gather kf from dense KPb; lazy-project vfT.
// ---------------------------------------------------------------------------
__global__ void gather_kv_kernel(const unsigned short* __restrict__ kpb,
                                 const unsigned short* __restrict__ xnb,
                                 const float* __restrict__ wv,
                                 const int* __restrict__ hidx, const int* __restrict__ widx,
                                 unsigned short* __restrict__ kf, unsigned short* __restrict__ vfT)
{
    int bh = blockIdx.y, p1 = blockIdx.x;
    int b = bh >> 3, nh = bh & 7;
    int hc = threadIdx.x & 63, pg = threadIdx.x >> 6;
    int hrow = hidx[bh * kP + p1];
    int o = nh * kHC + hc;
    const float* wvp = wv + (size_t)o * kC;
    for (int p2 = pg; p2 < kP; p2 += 4) {
        int wcol = widx[bh * kP + p2];
        int n = b * kHW + hrow * kW + wcol;
        int kidx = p1 * kP + p2;
        kf[((size_t)bh * 256 + kidx) * 64 + hc] = kpb[(size_t)n * kHID + nh * kHC + hc];
        const unsigned int* xr = (const unsigned int*)(xnb + (size_t)n * kC);
        float s = 0.f;
        for (int c2 = 0; c2 < kC / 2; ++c2) {
            unsigned int u = xr[c2];
            s += wvp[c2 * 2]     * bf2f((unsigned short)(u & 0xffff));
            s += wvp[c2 * 2 + 1] * bf2f((unsigned short)(u >> 16));
        }
        vfT[((size_t)bh * 64 + hc) * 256 + kidx] = f2bf(s);
    }
}

// ---------------------------------------------------------------------------
// MFMA attention, QBLK=128, flat grid 2048 with XCD swizzle (each XCD owns
// 2 bh values -> kf/vfT L2-resident). P in LDS stride-256 + XOR swizzle.
// ---------------------------------------------------------------------------
__global__ __launch_bounds__(256) void attn_kernel(
    const unsigned short* __restrict__ qpb, unsigned short* __restrict__ ob,
    const unsigned short* __restrict__ kf, const unsigned short* __restrict__ vfT)
{
    __shared__ unsigned short pls[64 * 256];
    __shared__ float lred[4][4][16];

    int bid = blockIdx.x;
    int xcd = bid & 7;
    int idx = bid >> 3;                      // 0..255
    int bh = xcd * 2 + (idx >> 7);
    int qblk = idx & 127;
    int b = bh >> 3, nh = bh & 7;
    int nbase = b * kHW + qblk * 128;
    int tid = threadIdx.x;
    int w = tid >> 6, lane = tid & 63, l15 = lane & 15, g = lane >> 4;

    const unsigned short* kfb = kf + (size_t)bh * 256 * 64;
    bf16x8 ak[4][2];
#pragma unroll
    for (int mt = 0; mt < 4; ++mt)
#pragma unroll
        for (int kt = 0; kt < 2; ++kt)
            ak[mt][kt] = *(const bf16x8*)&kfb[(size_t)(w * 64 + mt * 16 + l15) * 64 + kt * 32 + 8 * g];

    const unsigned short* vfb = vfT + (size_t)bh * 64 * 256;

#pragma unroll
    for (int sub = 0; sub < 2; ++sub) {
        int n0 = nbase + sub * 64;
        bf16x8 bq[4][2];
#pragma unroll
        for (int nt = 0; nt < 4; ++nt)
#pragma unroll
            for (int kt = 0; kt < 2; ++kt)
                bq[nt][kt] = *(const bf16x8*)(qpb + (size_t)(n0 + nt * 16 + l15) * kHID
                                              + nh * kHC + kt * 32 + 8 * g);

        f32x4 acc[4][4];
#pragma unroll
        for (int mt = 0; mt < 4; ++mt)
#pragma unroll
            for (int nt = 0; nt < 4; ++nt) acc[mt][nt] = (f32x4){0.f,0.f,0.f,0.f};

#pragma unroll
        for (int kt = 0; kt < 2; ++kt)
#pragma unroll
            for (int mt = 0; mt < 4; ++mt)
#pragma unroll
                for (int nt = 0; nt < 4; ++nt)
                    acc[mt][nt] = __builtin_amdgcn_mfma_f32_16x16x32_bf16(
                        ak[mt][kt], bq[nt][kt], acc[mt][nt], 0, 0, 0);

        if (sub) __syncthreads();

        float lpart[4] = {0.f, 0.f, 0.f, 0.f};
#pragma unroll
        for (int mt = 0; mt < 4; ++mt)
#pragma unroll
            for (int nt = 0; nt < 4; ++nt) {
                float e0 = __expf(acc[mt][nt][0]);
                float e1 = __expf(acc[mt][nt][1]);
                float e2 = __expf(acc[mt][nt][2]);
                float e3 = __expf(acc[mt][nt][3]);
                lpart[nt] += (e0 + e1) + (e2 + e3);
                int qq = nt * 16 + l15;
                int k0 = w * 64 + mt * 16 + 4 * g;
                int kx = k0 ^ ((qq & 7) << 3);
                *(unsigned long long*)&pls[qq * 256 + kx] = pk4(e0, e1, e2, e3);
            }
#pragma unroll
        for (int nt = 0; nt < 4; ++nt) {
            lpart[nt] += __shfl_xor(lpart[nt], 16);
            lpart[nt] += __shfl_xor(lpart[nt], 32);
        }
        if (g == 0)
#pragma unroll
            for (int nt = 0; nt < 4; ++nt) lred[w][nt][l15] = lpart[nt];
        __syncthreads();

        f32x4 oacc[4];
#pragma unroll
        for (int nt = 0; nt < 4; ++nt) oacc[nt] = (f32x4){0.f,0.f,0.f,0.f};

#pragma unroll
        for (int ks = 0; ks < 8; ++ks) {
            bf16x8 av = *(const bf16x8*)&vfb[(size_t)(w * 16 + l15) * 256 + ks * 32 + 8 * g];
#pragma unroll
            for (int nt = 0; nt < 4; ++nt) {
                int qq = nt * 16 + l15;
                int kx = (ks * 32 + 8 * g) ^ ((qq & 7) << 3);
                bf16x8 bp = *(const bf16x8*)&pls[qq * 256 + kx];
                oacc[nt] = __builtin_amdgcn_mfma_f32_16x16x32_bf16(av, bp, oacc[nt], 0, 0, 0);
            }
        }

#pragma unroll
        for (int nt = 0; nt < 4; ++nt) {
            float l = lred[0][nt][l15] + lred[1][nt][l15] + lred[2][nt][l15] + lred[3][nt][l15];
            float inv = 1.0f / l;
            int qq = nt * 16 + l15;
            int hc0 = w * 16 + 4 * g;
            *(unsigned long long*)(ob + (size_t)(n0 + qq) * kHID + nh * kHC + hc0) =
                pk4(oacc[nt][0] * inv, oacc[nt][1] * inv, oacc[nt][2] * inv, oacc[nt][3] * inv);
        }
    }
}

// ---------------------------------------------------------------------------
// Instance-norm stats (bf16 input) via per-chunk atomics.
// ---------------------------------------------------------------------------
__global__ void istats_bf16_kernel(const unsigned short* __restrict__ in, float* __restrict__ acc)
{
    int n0 = blockIdx.x * 64;
    int b = n0 >> 14;
    int c = threadIdx.x;
    float s = 0.f, ss = 0.f;
    for (int p = 0; p < 64; ++p) {
        float v = bf2f(in[(size_t)(n0 + p) * kC + c]);
        s += v; ss += v * v;
    }
    atomicAdd(&acc[(size_t)(b * kC + c) * 2],     s);
    atomicAdd(&acc[(size_t)(b * kC + c) * 2 + 1], ss);
}

__device__ inline void inorm_ms(const float* acc, int b, int c, float& m, float& rs)
{
    float s  = acc[(size_t)(b * kC + c) * 2];
    float ss = acc[(size_t)(b * kC + c) * 2 + 1];
    m = s * (1.0f / kHW);
    float var = ss * (1.0f / kHW) - m * m;
    rs = rsqrtf(var + kEPS);
}

// MODE 0: gelu(inorm(in)) -> bf16.  MODE 1: gelu(inorm(in)) + add -> bf16.
template<int MODE>
__global__ void apply_pm_kernel(const unsigned short* __restrict__ in, const float* __restrict__ acc,
                                unsigned short* __restrict__ out, const unsigned short* __restrict__ addsrc)
{
    int idx = blockIdx.x * 256 + threadIdx.x;      // kN*48
    int n = idx / 48;
    int c0 = (idx - n * 48) * 4;
    int b = n >> 14;
    f32x4 v = ubf4(*(const unsigned long long*)(in + (size_t)n * kC + c0));
    f32x4 r;
#pragma unroll
    for (int j = 0; j < 4; ++j) {
        float m, rs;
        inorm_ms(acc, b, c0 + j, m, rs);
        float x = (v[j] - m) * rs;
        r[j] = gelu_f(x);
    }
    if (MODE == 1)
        r += ubf4(*(const unsigned long long*)(addsrc + (size_t)n * kC + c0));
    *(unsigned long long*)(out + (size_t)n * kC + c0) = pk4(r[0], r[1], r[2], r[3]);
}

// ---------------------------------------------------------------------------
// Final inorm via LDS transpose: bf16 pixel-major in -> NCHW fp32 d_out.
// ---------------------------------------------------------------------------
__global__ __launch_bounds__(256) void final_kernel(const unsigned short* __restrict__ in,
                                                    const float* __restrict__ acc,
                                                    float* __restrict__ out)
{
    __shared__ unsigned short tile[192][68];
    int n0 = blockIdx.x * 64;
    int b = n0 >> 14;
    int hw0 = n0 & (kHW - 1);
    int tid = threadIdx.x;
    for (int i = tid; i < 64 * 48; i += 256) {
        int p = i / 48, cq = i - p * 48;
        unsigned long long u = *(const unsigned long long*)(in + (size_t)(n0 + p) * kC + cq * 4);
        tile[cq * 4 + 0][p] = (unsigned short)u;
        tile[cq * 4 + 1][p] = (unsigned short)(u >> 16);
        tile[cq * 4 + 2][p] = (unsigned short)(u >> 32);
        tile[cq * 4 + 3][p] = (unsigned short)(u >> 48);
    }
    __syncthreads();
    for (int i = tid; i < 192 * 16; i += 256) {
        int c = i >> 4, grp = i & 15;
        float m, rs;
        inorm_ms(acc, b, c, m, rs);
        f32x4 o;
#pragma unroll
        for (int j = 0; j < 4; ++j)
            o[j] = (bf2f(tile[c][grp * 4 + j]) - m) * rs;
        *(f32x4*)(out + (size_t)(b * kC + c) * kHW + hw0 + grp * 4) = o;
    }
}

// ---------------------------------------------------------------------------
extern "C" void kernel_launch(void* const* d_in, const int* in_sizes, int n_in,
                              void* d_out, int out_size, void* d_ws, size_t ws_size,
                              hipStream_t stream)
{
    const float* x     = (const float*)d_in[0];
    const float* ln1_g = (const float*)d_in[1];
    const float* ln1_b = (const float*)d_in[2];
    const float* wq    = (const float*)d_in[3];
    const float* wk    = (const float*)d_in[4];
    const float* wv    = (const float*)d_in[5];
    const float* wo    = (const float*)d_in[6];
    const float* bo    = (const float*)d_in[7];
    const float* dw_w  = (const float*)d_in[8];
    const float* dw_b  = (const float*)d_in[9];
    const float* mlp_w = (const float*)d_in[10];
    const float* mlp_b = (const float*)d_in[11];
    const float* ln2_g = (const float*)d_in[12];
    const float* ln2_b = (const float*)d_in[13];
    const float* c1_w  = (const float*)d_in[14];
    const float* c1_b  = (const float*)d_in[15];
    const float* res_w = (const float*)d_in[16];
    const float* res_b = (const float*)d_in[17];
    const float* c2_w  = (const float*)d_in[18];
    const float* c2_b  = (const float*)d_in[19];

    char* base = (char*)d_ws;
    unsigned short* XPb = (unsigned short*)(base);               // bf16 [n][192] raw x
    unsigned short* XNb = (unsigned short*)(base + 25165824);    // bf16 [n][192] xn / Y1
    unsigned short* QPb = (unsigned short*)(base + 37748736);    // bf16 [n][512]; later T2
    unsigned short* T2  = QPb;
    unsigned short* KPb = (unsigned short*)(base + 71303168);    // bf16 [n][512]; OB alias; later Y2
    unsigned short* OB  = KPb;
    unsigned short* Y2  = KPb;
    unsigned short* LB  = (unsigned short*)(base + 104857600);   // bf16 [n][192] local; later Y3
    unsigned short* Y3  = LB;
    unsigned short* T1  = (unsigned short*)(base + 117440512);   // bf16 [n][192]; later R
    unsigned short* R   = T1;
    char* sm = base + 130023424;
    float* qpart  = (float*)(sm);                 sm += 524288;   // [16][128][64]
    float* ksum_h = (float*)(sm);                 sm += 524288;
    float* ksum_w = (float*)(sm);                 sm += 524288;
    float* acc0   = (float*)(sm);                 sm += 3072;     // zero block (2304 floats)
    float* acc1   = (float*)(sm);                 sm += 3072;
    float* acc2   = (float*)(sm);                 sm += 3072;
    unsigned short* kf   = (unsigned short*)(sm); sm += 524288;
    unsigned short* vfT  = (unsigned short*)(sm); sm += 524288;
    unsigned short* wqb  = (unsigned short*)(sm); sm += 196608;
    unsigned short* wkb  = (unsigned short*)(sm); sm += 196608;
    unsigned short* mlpb1= (unsigned short*)(sm); sm += 73728;
    unsigned short* c1b  = (unsigned short*)(sm); sm += 73728;
    unsigned short* c2b  = (unsigned short*)(sm); sm += 73728;
    unsigned short* w2pb = (unsigned short*)(sm); sm += 196608;
    float* bp2 = (float*)(sm);                    sm += 1024;
    int* hidx = (int*)(sm);                       sm += 1024;
    int* widx = (int*)(sm);

    // 1. prep
    prep_kernel<<<1593, 256, 0, stream>>>(acc0, wq, wk, mlp_w, c1_w, c2_w,
                                          wo, mlp_b, bo,
                                          wqb, wkb, mlpb1, c1b, c2b, w2pb, bp2);
    // 2. transpose + ln1
    txln_kernel<<<dim3(kHW / 64, kB), 256, 0, stream>>>(x, XPb, XNb, ln1_g, ln1_b);
    // 3. q/k projections (XCD-swizzled flat grid)
    qk_proj_kernel<<<2048, 256, 0, stream>>>(wqb, wkb, XNb, QPb, KPb, qpart, ksum_h);
    // 4. local dwconv
    dwconv_pm_kernel<<<(kN * 48) / 256, 256, 0, stream>>>(XPb, LB, dw_w, dw_b);
    // 5. ksum_w
    sum_h_kernel<<<dim3(kW, 16), 256, 0, stream>>>(KPb, ksum_w);
    // 6. scores + top-16
    score_topk_kernel<<<16, 128, 0, stream>>>(qpart, ksum_h, ksum_w, hidx, widx);
    // 7. gather: kf copy + lazy vfT
    gather_kv_kernel<<<dim3(kP, 16), 256, 0, stream>>>(KPb, XNb, wv, hidx, widx, kf, vfT);
    // 8. attention (QBLK=128, XCD-swizzled; OB overwrites KPb)
    attn_kernel<<<2048, 256, 0, stream>>>(QPb, OB, kf, vfT);
    // 9. fused mlp + ln2 -> Y1 (XNb)
    mgemm_mlp_ln_kernel<<<kN / 128, 384, 0, stream>>>(mlpb1, LB, w2pb, OB, XNb, bp2, XPb,
                                                      ln2_g, ln2_b);
    // 10. c1 GEMM + istats(acc0)  (XCD-swizzled flat grid)
    mgemm_is_kernel<<<768, 256, 0, stream>>>(c1b, XNb, T1, c1_b, acc0);
    // 11. Y2 = gelu(inorm(T1))
    apply_pm_kernel<0><<<(kN * 48) / 256, 256, 0, stream>>>(T1, acc0, Y2, nullptr);
    // 12. res dwconv: R = dwconv(Y2)
    dwconv_pm_kernel<<<(kN * 48) / 256, 256, 0, stream>>>(Y2, R, res_w, res_b);
    // 13. istats(R) -> acc1
    istats_bf16_kernel<<<kN / 64, 192, 0, stream>>>(R, acc1);
    // 14. Y3 = gelu(inorm(R)) + Y2
    apply_pm_kernel<1><<<(kN * 48) / 256, 256, 0, stream>>>(R, acc1, Y3, Y2);
    // 15. c2 GEMM + istats(acc2)
    mgemm_is_kernel<<<768, 256, 0, stream>>>(c2b, Y3, T2, c2_b, acc2);
    // 16. final inorm -> d_out
    final_kernel<<<kN / 64, 256, 0, stream>>>(T2, acc2, (float*)d_out);
}